// Round 7
// baseline (701.038 us; speedup 1.0000x reference)
//
#include <hip/hip_runtime.h>
#include <math.h>

#define NN 50000
#define NE 800000
#define EMB 128
#define GH 64
#define BB 64
#define TT 200
#define HH 128
#define G4 512
#define IND 134
#define PM 128
#define PO 128

__device__ __forceinline__ float sigf(float x) { return 1.0f / (1.0f + __expf(-x)); }
__device__ __forceinline__ float tanhf_(float x) { return 1.0f - 2.0f / (__expf(2.0f * x) + 1.0f); }
__device__ __forceinline__ void fma4(float4& a, float s, const float4 w) {
    a.x += s * w.x; a.y += s * w.y; a.z += s * w.z; a.w += s * w.w;
}

// ---------------- CSR build ----------------
__global__ void hist_kernel(const int* __restrict__ ei, const float* __restrict__ ew,
                            int* __restrict__ cnt, float* __restrict__ degw) {
    int e = blockIdx.x * 256 + threadIdx.x;
    if (e >= NE) return;
    int d = ei[NE + e];
    atomicAdd(&cnt[d], 1);
    atomicAdd(&degw[d], ew[e]);
}

__global__ void dinv_kernel(const float* __restrict__ degw, float* __restrict__ dinv) {
    int n = blockIdx.x * 256 + threadIdx.x;
    if (n >= NN) return;
    dinv[n] = rsqrtf(degw[n] + 1.0f);   // +1 self loop
}

__global__ __launch_bounds__(1024) void scan1_kernel(const int* __restrict__ cnt,
                                                     int* __restrict__ rs, int* __restrict__ partials) {
    __shared__ int s[1024];
    int gid = blockIdx.x * 1024 + threadIdx.x;
    int v = (gid < NN) ? cnt[gid] : 0;
    s[threadIdx.x] = v;
    __syncthreads();
    for (int off = 1; off < 1024; off <<= 1) {
        int add = (threadIdx.x >= (unsigned)off) ? s[threadIdx.x - off] : 0;
        __syncthreads();
        s[threadIdx.x] += add;
        __syncthreads();
    }
    if (gid < NN) rs[gid] = s[threadIdx.x] - v;  // exclusive
    if (threadIdx.x == 1023) partials[blockIdx.x] = s[1023];
}

__global__ void scan2_kernel(int* __restrict__ partials, int nblk) {
    if (threadIdx.x == 0) {
        int acc = 0;
        for (int i = 0; i < nblk; ++i) { int v = partials[i]; partials[i] = acc; acc += v; }
    }
}

__global__ __launch_bounds__(1024) void scan3_kernel(const int* __restrict__ partials,
                                                     int* __restrict__ rs, int* __restrict__ cursor) {
    int gid = blockIdx.x * 1024 + threadIdx.x;
    if (gid < NN) {
        int v = rs[gid] + partials[gid >> 10];
        rs[gid] = v;
        cursor[gid] = v;
    }
    if (gid == 0) rs[NN] = NE;
}

__global__ void fill_kernel(const int* __restrict__ ei, const float* __restrict__ ew,
                            const float* __restrict__ dinv, int* __restrict__ cursor,
                            int* __restrict__ ssrc, float* __restrict__ sw) {
    int e = blockIdx.x * 256 + threadIdx.x;
    if (e >= NE) return;
    int s = ei[e], d = ei[NE + e];
    int pos = atomicAdd(&cursor[d], 1);
    ssrc[pos] = s;
    sw[pos] = ew[e] * dinv[s] * dinv[d];
}

// ---------------- GCN layer 1 GEMM (fused concat, 134 -> 64) ----------------
__global__ __launch_bounds__(256) void gemm1_kernel(const float* __restrict__ coords,
                                                    const float* __restrict__ temporal,
                                                    const float* __restrict__ emb,
                                                    const float* __restrict__ W1,
                                                    float* __restrict__ h1) {
    __shared__ __align__(16) float wl[IND][GH];
    for (int i = threadIdx.x; i < IND * GH / 4; i += 256)
        ((float4*)wl)[i] = ((const float4*)W1)[i];
    __syncthreads();
    int n = blockIdx.x * 256 + threadIdx.x;
    if (n >= NN) return;
    float4 acc[16];
    float c0 = coords[2 * n], c1 = coords[2 * n + 1];
#pragma unroll
    for (int j = 0; j < 16; ++j) {
        float4 wa = *(const float4*)&wl[0][j * 4];
        float4 wb = *(const float4*)&wl[1][j * 4];
        float4 a;
        a.x = c0 * wa.x + c1 * wb.x; a.y = c0 * wa.y + c1 * wb.y;
        a.z = c0 * wa.z + c1 * wb.z; a.w = c0 * wa.w + c1 * wb.w;
        acc[j] = a;
    }
    const float4* er = (const float4*)(emb + (size_t)n * EMB);
#pragma unroll 2
    for (int k4 = 0; k4 < 32; ++k4) {
        float4 v = er[k4];
        int k = 2 + k4 * 4;
#pragma unroll
        for (int j = 0; j < 16; ++j) {
            fma4(acc[j], v.x, *(const float4*)&wl[k][j * 4]);
            fma4(acc[j], v.y, *(const float4*)&wl[k + 1][j * 4]);
            fma4(acc[j], v.z, *(const float4*)&wl[k + 2][j * 4]);
            fma4(acc[j], v.w, *(const float4*)&wl[k + 3][j * 4]);
        }
    }
    float t0 = temporal[4 * n], t1 = temporal[4 * n + 1], t2 = temporal[4 * n + 2], t3 = temporal[4 * n + 3];
#pragma unroll
    for (int j = 0; j < 16; ++j) {
        fma4(acc[j], t0, *(const float4*)&wl[130][j * 4]);
        fma4(acc[j], t1, *(const float4*)&wl[131][j * 4]);
        fma4(acc[j], t2, *(const float4*)&wl[132][j * 4]);
        fma4(acc[j], t3, *(const float4*)&wl[133][j * 4]);
        *(float4*)&h1[(size_t)n * GH + j * 4] = acc[j];
    }
}

// ---------------- symmetric-norm aggregation (64 features, CSR) ----------------
__global__ __launch_bounds__(256) void agg_kernel(const float* __restrict__ hin,
                                                  const int* __restrict__ rs,
                                                  const int* __restrict__ ssrc,
                                                  const float* __restrict__ sw,
                                                  const float* __restrict__ dinv,
                                                  const float* __restrict__ bias, int relu,
                                                  float* __restrict__ hout) {
    int lane = threadIdx.x & 63;
    int wid = threadIdx.x >> 6;
    int n = blockIdx.x * 4 + wid;
    if (n >= NN) return;
    float dv = dinv[n];
    float acc = hin[(size_t)n * GH + lane] * (dv * dv);  // self loop
    int i = rs[n], e1 = rs[n + 1];
    for (; i + 3 < e1; i += 4) {
        int s0 = ssrc[i], s1 = ssrc[i + 1], s2 = ssrc[i + 2], s3 = ssrc[i + 3];
        float w0 = sw[i], w1 = sw[i + 1], w2 = sw[i + 2], w3 = sw[i + 3];
        float a0 = hin[(size_t)s0 * GH + lane];
        float a1 = hin[(size_t)s1 * GH + lane];
        float a2 = hin[(size_t)s2 * GH + lane];
        float a3 = hin[(size_t)s3 * GH + lane];
        acc += a0 * w0 + a1 * w1 + a2 * w2 + a3 * w3;
    }
    for (; i < e1; ++i) acc += hin[(size_t)ssrc[i] * GH + lane] * sw[i];
    if (bias) acc += bias[lane];
    if (relu) acc = fmaxf(acc, 0.0f);
    hout[(size_t)n * GH + lane] = acc;
}

// ---------------- W2 transpose (64x128 -> 128x64), one-time tiny kernel ----------------
__global__ void w2t_kernel(const float* __restrict__ W2, float* __restrict__ w2t) {
    int i = blockIdx.x * 256 + threadIdx.x;
    if (i >= GH * EMB) return;
    int o = i >> 6, k = i & 63;
    w2t[i] = W2[(size_t)k * EMB + o];
}

// ---------------- GCN layer 2 GEMM v2 (64 -> 128), register-tiled ----------------
// Old version: 1024 LDS b128 broadcasts/thread (FMA:LDS 1:1). v2: tile 128m x
// 64o, thread = 4m x 8o (acc 32), XOR-swizzled LDS -> 192 conflict-free LDS
// instr/thread (10.7 FMA per LDS read). W2 pre-transposed so staging is
// coalesced.
__global__ __launch_bounds__(256) void gemm2_kernel(const float* __restrict__ a2,
                                                    const float* __restrict__ w2t,
                                                    const float* __restrict__ b2,
                                                    float* __restrict__ z2) {
    int m0 = blockIdx.x * 128, o0 = blockIdx.y * 64;
    __shared__ __align__(16) float xs[128][64];
    __shared__ __align__(16) float wt[64][64];
    __shared__ float bsh[64];
    int tid = threadIdx.x;
#pragma unroll
    for (int i = 0; i < 8; ++i) {            // stage a2 rows (swizzled)
        int idx = i * 256 + tid;
        int r = idx >> 4, c4 = idx & 15;
        int m = m0 + r;
        float4 v = (m < NN) ? *(const float4*)&a2[(size_t)m * GH + c4 * 4]
                            : make_float4(0.f, 0.f, 0.f, 0.f);
        *(float4*)&xs[r][(c4 ^ ((r >> 2) & 3)) * 4] = v;
    }
#pragma unroll
    for (int i = 0; i < 4; ++i) {            // stage w2t rows (swizzled)
        int idx = i * 256 + tid;
        int r = idx >> 4, c4 = idx & 15;
        float4 v = *(const float4*)&w2t[(size_t)(o0 + r) * GH + c4 * 4];
        *(float4*)&wt[r][(c4 ^ ((r >> 3) & 7)) * 4] = v;
    }
    if (tid < 64) bsh[tid] = b2[o0 + tid];
    __syncthreads();
    int mt = tid >> 3, ot = tid & 7;        // mt 0..31 (4 m each), ot 0..7 (8 o each)
    float acc[4][8];
#pragma unroll
    for (int mi = 0; mi < 4; ++mi)
#pragma unroll
        for (int oi = 0; oi < 8; ++oi) acc[mi][oi] = 0.0f;
    for (int k4 = 0; k4 < 16; ++k4) {
        int xc = (k4 ^ (mt & 3)) * 4;
        int wc = (k4 ^ (ot & 7)) * 4;
        float4 xv[4], wv[8];
#pragma unroll
        for (int mi = 0; mi < 4; ++mi) xv[mi] = *(const float4*)&xs[mt * 4 + mi][xc];
#pragma unroll
        for (int oi = 0; oi < 8; ++oi) wv[oi] = *(const float4*)&wt[ot * 8 + oi][wc];
#pragma unroll
        for (int mi = 0; mi < 4; ++mi)
#pragma unroll
            for (int oi = 0; oi < 8; ++oi)
                acc[mi][oi] += xv[mi].x * wv[oi].x + xv[mi].y * wv[oi].y
                             + xv[mi].z * wv[oi].z + xv[mi].w * wv[oi].w;
    }
#pragma unroll
    for (int mi = 0; mi < 4; ++mi) {
        int m = m0 + mt * 4 + mi;
        if (m >= NN) continue;
        int ob = ot * 8;
        float4 oa = make_float4(acc[mi][0] + bsh[ob + 0], acc[mi][1] + bsh[ob + 1],
                                acc[mi][2] + bsh[ob + 2], acc[mi][3] + bsh[ob + 3]);
        float4 obv = make_float4(acc[mi][4] + bsh[ob + 4], acc[mi][5] + bsh[ob + 5],
                                 acc[mi][6] + bsh[ob + 6], acc[mi][7] + bsh[ob + 7]);
        *(float4*)&z2[(size_t)m * EMB + o0 + ob] = oa;
        *(float4*)&z2[(size_t)m * EMB + o0 + ob + 4] = obv;
    }
}

// ---------------- gather sequence embeddings ----------------
__global__ void gather_kernel(const int* __restrict__ seq, const float* __restrict__ z2,
                              float* __restrict__ se) {
    int idx = blockIdx.x * 256 + threadIdx.x;
    if (idx >= BB * TT * 32) return;
    int r = idx >> 5, q = idx & 31;
    int node = seq[r];
    ((float4*)se)[(size_t)r * 32 + q] = ((const float4*)z2)[(size_t)node * 32 + q];
}

// ---------------- pre-GEMM v3: tiled GEMM [12800 x 128] @ [128 x 512]^T ----------------
__global__ __launch_bounds__(256) void pregemm_kernel(const float* __restrict__ se,
                                                      const float* __restrict__ w_ih_f,
                                                      const float* __restrict__ w_ih_b,
                                                      const float* __restrict__ b_ih_f,
                                                      const float* __restrict__ b_hh_f,
                                                      const float* __restrict__ b_ih_b,
                                                      const float* __restrict__ b_hh_b,
                                                      const int* __restrict__ lengths,
                                                      float* __restrict__ xpf,
                                                      float* __restrict__ xpb) {
    int dir = blockIdx.z;
    const float* w_ih = dir ? w_ih_b : w_ih_f;
    int o0 = blockIdx.y * PO;
    int m0 = blockIdx.x * PM;
    __shared__ __align__(16) float xs[PM][EMB];
    __shared__ __align__(16) float ws[PO][EMB];
    __shared__ float bsh[PO];
    int tid = threadIdx.x;
#pragma unroll
    for (int i = 0; i < 16; ++i) {          // stage W (swizzled)
        int idx = i * 256 + tid;
        int row = idx >> 5, c4 = idx & 31;
        float4 v = *(const float4*)&w_ih[(size_t)(o0 + row) * EMB + c4 * 4];
        *(float4*)&ws[row][(c4 ^ ((row >> 3) & 7)) * 4] = v;
    }
    if (tid < PO) bsh[tid] = dir ? (b_ih_b[o0 + tid] + b_hh_b[o0 + tid])
                                 : (b_ih_f[o0 + tid] + b_hh_f[o0 + tid]);
#pragma unroll
    for (int i = 0; i < 16; ++i) {          // stage x (swizzled)
        int idx = i * 256 + tid;
        int r = idx >> 5, c4 = idx & 31;
        int m = m0 + r;
        int t = m >> 6, b = m & 63;
        int tsrc = t;
        if (dir) { int len = lengths[b]; tsrc = (t < len) ? (len - 1 - t) : t; }
        float4 v = *(const float4*)&se[((size_t)b * TT + tsrc) * EMB + c4 * 4];
        *(float4*)&xs[r][(c4 ^ ((r >> 3) & 3)) * 4] = v;
    }
    __syncthreads();
    int mt = tid >> 4, ot = tid & 15;   // each 0..15
    int mswz = mt & 3, oswz = ot & 7;
    float acc[8][8];
#pragma unroll
    for (int mi = 0; mi < 8; ++mi)
#pragma unroll
        for (int oi = 0; oi < 8; ++oi) acc[mi][oi] = 0.0f;
    for (int k4 = 0; k4 < 32; ++k4) {
        int xk = (k4 ^ mswz) * 4;
        int wk = (k4 ^ oswz) * 4;
        float4 xv[8], wv[8];
#pragma unroll
        for (int mi = 0; mi < 8; ++mi) xv[mi] = *(const float4*)&xs[mt * 8 + mi][xk];
#pragma unroll
        for (int oi = 0; oi < 8; ++oi) wv[oi] = *(const float4*)&ws[ot * 8 + oi][wk];
#pragma unroll
        for (int mi = 0; mi < 8; ++mi)
#pragma unroll
            for (int oi = 0; oi < 8; ++oi)
                acc[mi][oi] += xv[mi].x * wv[oi].x + xv[mi].y * wv[oi].y
                             + xv[mi].z * wv[oi].z + xv[mi].w * wv[oi].w;
    }
    float* xp = dir ? xpb : xpf;
#pragma unroll
    for (int mi = 0; mi < 8; ++mi) {
        int m = m0 + mt * 8 + mi;
        int ob = ot * 8;
        float4 oa = make_float4(acc[mi][0] + bsh[ob + 0], acc[mi][1] + bsh[ob + 1],
                                acc[mi][2] + bsh[ob + 2], acc[mi][3] + bsh[ob + 3]);
        float4 obv = make_float4(acc[mi][4] + bsh[ob + 4], acc[mi][5] + bsh[ob + 5],
                                 acc[mi][6] + bsh[ob + 6], acc[mi][7] + bsh[ob + 7]);
        *(float4*)&xp[(size_t)m * G4 + o0 + ob] = oa;
        *(float4*)&xp[(size_t)m * G4 + o0 + ob + 4] = obv;
    }
}

// ---------------- LSTM recurrence v4: in-wave shfl reduction ----------------
// R6 post-mortem: part[] LDS round trip + 2 barriers + serial 2-wave phase B
// = 2100 cyc/step. v4: lane = uu*8 + kq (8 units x 8 k-slices per wave), so
// the kq-reduction is 12 shfl_xor in-wave (no LDS), activations run on 128
// lanes across all 16 waves, ONE barrier/step via double-buffered h. h stored
// as [8][20] (pad 20 floats): chunk kq starts at bank 20*kq mod 32 -> the 8
// chunks hit disjoint bank-quads -> conflict-free ds_read_b128 with 8-way
// broadcast. W/thread = 64 floats (static idx).
__global__ __launch_bounds__(1024, 4) void lstm_kernel(const float* __restrict__ xpf,
                                                       const float* __restrict__ xpb,
                                                       const float* __restrict__ w_hh_f,
                                                       const float* __restrict__ w_hh_b,
                                                       const int* __restrict__ lengths,
                                                       float* __restrict__ hfo,
                                                       float* __restrict__ hbo) {
    int chain = blockIdx.x;
    int dir = chain & 1, b = chain >> 1;
    const float* w_hh = dir ? w_hh_b : w_hh_f;
    const float* xp = dir ? xpb : xpf;
    float* ho = dir ? hbo : hfo;
    int tid = threadIdx.x;
    int wv = tid >> 6, lane = tid & 63;
    int uu = lane >> 3, kq = lane & 7;
    int u = wv * 8 + uu;      // unit 0..127
    int len = lengths[b];

    float4 W[4][4];
#pragma unroll
    for (int g = 0; g < 4; ++g)
#pragma unroll
        for (int j4 = 0; j4 < 4; ++j4)
            W[g][j4] = *(const float4*)&w_hh[(size_t)(g * HH + u) * HH + kq * 16 + j4 * 4];

    __shared__ __align__(16) float hl[2][8][20];   // [buf][kq][16 + pad4]
    if (tid < 320) ((float*)hl)[tid] = 0.0f;
    __syncthreads();

    bool act = (kq == 0);
    const float* xb = xp + (size_t)b * G4 + u;
    float cst = 0.0f;
    float x0 = 0.f, x1 = 0.f, x2 = 0.f, x3 = 0.f;
    if (act && len > 0) { x0 = xb[0]; x1 = xb[HH]; x2 = xb[2 * HH]; x3 = xb[3 * HH]; }
    for (int t = 0; t < len; ++t) {
        const float4* h4 = (const float4*)&hl[t & 1][kq][0];
        float a0 = 0.f, a1 = 0.f, a2 = 0.f, a3 = 0.f;
#pragma unroll
        for (int j4 = 0; j4 < 4; ++j4) {
            float4 hv = h4[j4];
            a0 += W[0][j4].x * hv.x + W[0][j4].y * hv.y + W[0][j4].z * hv.z + W[0][j4].w * hv.w;
            a1 += W[1][j4].x * hv.x + W[1][j4].y * hv.y + W[1][j4].z * hv.z + W[1][j4].w * hv.w;
            a2 += W[2][j4].x * hv.x + W[2][j4].y * hv.y + W[2][j4].z * hv.z + W[2][j4].w * hv.w;
            a3 += W[3][j4].x * hv.x + W[3][j4].y * hv.y + W[3][j4].z * hv.z + W[3][j4].w * hv.w;
        }
#pragma unroll
        for (int m = 1; m < 8; m <<= 1) {   // reduce over kq (low 3 lane bits)
            a0 += __shfl_xor(a0, m, 64);
            a1 += __shfl_xor(a1, m, 64);
            a2 += __shfl_xor(a2, m, 64);
            a3 += __shfl_xor(a3, m, 64);
        }
        if (act) {
            float n0 = 0.f, n1 = 0.f, n2 = 0.f, n3 = 0.f;
            if (t + 1 < len) {
                const float* xn = xb + (size_t)(t + 1) * (BB * G4);
                n0 = xn[0]; n1 = xn[HH]; n2 = xn[2 * HH]; n3 = xn[3 * HH];
            }
            float gi = sigf(a0 + x0), gf = sigf(a1 + x1);
            float gg = tanhf_(a2 + x2), go = sigf(a3 + x3);
            cst = gf * cst + gi * gg;
            float h = go * tanhf_(cst);
            hl[(t + 1) & 1][u >> 4][u & 15] = h;
            int tt = dir ? (len - 1 - t) : t;
            ho[((size_t)b * TT + tt) * HH + u] = h;
            x0 = n0; x1 = n1; x2 = n2; x3 = n3;
        }
        __syncthreads();
    }
}

// ---------------- masked attention pooling ----------------
__global__ __launch_bounds__(256) void attn_kernel(const float* __restrict__ hf,
                                                   const float* __restrict__ hb,
                                                   const float* __restrict__ attn_w,
                                                   const float* __restrict__ attn_b,
                                                   const int* __restrict__ lengths,
                                                   float* __restrict__ ctx) {
    int b = blockIdx.x;
    int tid = threadIdx.x;
    int len = lengths[b];
    __shared__ __align__(16) float wl[256];
    __shared__ float pl[256];
    __shared__ float red[256];
    wl[tid] = attn_w[tid];
    __syncthreads();
    float sc = -3.0e38f;
    if (tid < len) {
        const float4* rf = (const float4*)(hf + ((size_t)b * TT + tid) * HH);
        const float4* rb = (const float4*)(hb + ((size_t)b * TT + tid) * HH);
        const float4* w4 = (const float4*)wl;
        float s = attn_b[0];
        for (int k4 = 0; k4 < 32; ++k4) {
            float4 a = rf[k4], ww = w4[k4];
            s += a.x * ww.x + a.y * ww.y + a.z * ww.z + a.w * ww.w;
        }
        for (int k4 = 0; k4 < 32; ++k4) {
            float4 a = rb[k4], ww = w4[32 + k4];
            s += a.x * ww.x + a.y * ww.y + a.z * ww.z + a.w * ww.w;
        }
        sc = s;
    }
    red[tid] = sc;
    __syncthreads();
    for (int off = 128; off > 0; off >>= 1) {
        if (tid < off) red[tid] = fmaxf(red[tid], red[tid + off]);
        __syncthreads();
    }
    float mx = red[0];
    __syncthreads();
    float e = (tid < len) ? __expf(sc - mx) : 0.0f;
    red[tid] = e;
    __syncthreads();
    for (int off = 128; off > 0; off >>= 1) {
        if (tid < off) red[tid] += red[tid + off];
        __syncthreads();
    }
    float inv = 1.0f / red[0];
    pl[tid] = e * inv;
    __syncthreads();
    float acc = 0.0f;
    const float* basep = (tid < HH) ? (hf + (size_t)b * TT * HH + tid)
                                    : (hb + (size_t)b * TT * HH + (tid - HH));
#pragma unroll 4
    for (int t = 0; t < len; ++t) acc += pl[t] * basep[(size_t)t * HH];
    ctx[(size_t)b * 256 + tid] = acc;
}

// ---------------- final FC: [64,256] @ [256,N] + b ----------------
__global__ __launch_bounds__(256) void fc_kernel(const float* __restrict__ ctx,
                                                 const float* __restrict__ fc_w,
                                                 const float* __restrict__ fc_b,
                                                 float* __restrict__ out) {
    __shared__ __align__(16) float cl[64][256];
    for (int i = threadIdx.x; i < 64 * 256 / 4; i += 256)
        ((float4*)cl)[i] = ((const float4*)ctx)[i];
    __syncthreads();
    int nb = threadIdx.x & 63;
    int bq = threadIdx.x >> 6;
    int n = blockIdx.x * 64 + nb;
    if (n >= NN) return;
    float acc[16];
#pragma unroll
    for (int i = 0; i < 16; ++i) acc[i] = 0.0f;
#pragma unroll 2
    for (int k4 = 0; k4 < 64; ++k4) {
        int k = k4 * 4;
        float w0 = fc_w[(size_t)k * NN + n];
        float w1 = fc_w[(size_t)(k + 1) * NN + n];
        float w2 = fc_w[(size_t)(k + 2) * NN + n];
        float w3 = fc_w[(size_t)(k + 3) * NN + n];
#pragma unroll
        for (int i = 0; i < 16; ++i) {
            float4 cv = *(const float4*)&cl[bq * 16 + i][k];
            acc[i] += cv.x * w0 + cv.y * w1 + cv.z * w2 + cv.w * w3;
        }
    }
    float fb = fc_b[n];
#pragma unroll
    for (int i = 0; i < 16; ++i)
        out[(size_t)(bq * 16 + i) * NN + n] = acc[i] + fb;
}

// ---------------- host launcher ----------------
extern "C" void kernel_launch(void* const* d_in, const int* in_sizes, int n_in,
                              void* d_out, int out_size, void* d_ws, size_t ws_size,
                              hipStream_t stream) {
    const float* x_coords   = (const float*)d_in[0];
    const float* temporal   = (const float*)d_in[1];
    const int*   edge_index = (const int*)d_in[2];
    const float* edge_w     = (const float*)d_in[3];
    const int*   seq        = (const int*)d_in[4];
    const int*   lengths    = (const int*)d_in[5];
    const float* node_emb   = (const float*)d_in[6];
    const float* gcn1_w     = (const float*)d_in[7];
    const float* gcn1_b     = (const float*)d_in[8];
    const float* gcn2_w     = (const float*)d_in[9];
    const float* gcn2_b     = (const float*)d_in[10];
    const float* w_ih_f     = (const float*)d_in[11];
    const float* w_hh_f     = (const float*)d_in[12];
    const float* b_ih_f     = (const float*)d_in[13];
    const float* b_hh_f     = (const float*)d_in[14];
    const float* w_ih_b     = (const float*)d_in[15];
    const float* w_hh_b     = (const float*)d_in[16];
    const float* b_ih_b     = (const float*)d_in[17];
    const float* b_hh_b     = (const float*)d_in[18];
    const float* attn_w     = (const float*)d_in[19];
    const float* attn_b     = (const float*)d_in[20];
    const float* fc_w       = (const float*)d_in[21];
    const float* fc_b       = (const float*)d_in[22];
    float* out = (float*)d_out;

    char* base = (char*)d_ws;
    size_t off = 0;
    auto alloc = [&](size_t nbytes) -> void* {
        void* p = base + off;
        off = (off + nbytes + 255) & ~(size_t)255;
        return p;
    };
    int*   cnt     = (int*)alloc((size_t)2 * NN * 4);  // cnt + degw contiguous (one memset)
    float* degw    = (float*)(cnt + NN);
    float* dinv    = (float*)alloc((size_t)NN * 4);
    int*   rs      = (int*)alloc(((size_t)NN + 1) * 4);
    int*   cursor  = (int*)alloc((size_t)NN * 4);
    int*   partials= (int*)alloc(64 * 4);
    int*   ssrc    = (int*)alloc((size_t)NE * 4);
    float* sw      = (float*)alloc((size_t)NE * 4);
    float* h1      = (float*)alloc((size_t)NN * GH * 4);
    float* z1      = (float*)alloc((size_t)NN * GH * 4);
    float* a2      = h1;  // h1 dead after agg1
    float* w2t     = (float*)alloc((size_t)GH * EMB * 4);
    float* z2      = (float*)alloc((size_t)NN * EMB * 4);
    float* se      = (float*)alloc((size_t)BB * TT * EMB * 4);
    float* xpf     = (float*)alloc((size_t)TT * BB * G4 * 4);
    float* xpb     = (float*)alloc((size_t)TT * BB * G4 * 4);
    float* hfo     = (float*)alloc((size_t)BB * TT * HH * 4);
    float* hbo     = (float*)alloc((size_t)BB * TT * HH * 4);
    float* ctx     = (float*)alloc((size_t)BB * 256 * 4);
    (void)ws_size; (void)in_sizes; (void)n_in; (void)out_size;

    hipMemsetAsync(cnt, 0, (size_t)2 * NN * 4, stream);

    hist_kernel<<<(NE + 255) / 256, 256, 0, stream>>>(edge_index, edge_w, cnt, degw);
    dinv_kernel<<<(NN + 255) / 256, 256, 0, stream>>>(degw, dinv);
    const int nblk = (NN + 1023) / 1024;  // 49
    scan1_kernel<<<nblk, 1024, 0, stream>>>(cnt, rs, partials);
    scan2_kernel<<<1, 64, 0, stream>>>(partials, nblk);
    scan3_kernel<<<nblk, 1024, 0, stream>>>(partials, rs, cursor);
    fill_kernel<<<(NE + 255) / 256, 256, 0, stream>>>(edge_index, edge_w, dinv, cursor, ssrc, sw);
    w2t_kernel<<<(GH * EMB + 255) / 256, 256, 0, stream>>>(gcn2_w, w2t);

    gemm1_kernel<<<(NN + 255) / 256, 256, 0, stream>>>(x_coords, temporal, node_emb, gcn1_w, h1);
    agg_kernel<<<(NN + 3) / 4, 256, 0, stream>>>(h1, rs, ssrc, sw, dinv, gcn1_b, 1, z1);
    agg_kernel<<<(NN + 3) / 4, 256, 0, stream>>>(z1, rs, ssrc, sw, dinv, (const float*)nullptr, 0, a2);
    gemm2_kernel<<<dim3((NN + 127) / 128, 2), 256, 0, stream>>>(a2, w2t, gcn2_b, z2);

    gather_kernel<<<(BB * TT * 32 + 255) / 256, 256, 0, stream>>>(seq, z2, se);
    pregemm_kernel<<<dim3(TT * BB / PM, G4 / PO, 2), 256, 0, stream>>>(
        se, w_ih_f, w_ih_b, b_ih_f, b_hh_f, b_ih_b, b_hh_b, lengths, xpf, xpb);
    lstm_kernel<<<BB * 2, 1024, 0, stream>>>(xpf, xpb, w_hh_f, w_hh_b, lengths, hfo, hbo);
    attn_kernel<<<BB, 256, 0, stream>>>(hfo, hbo, attn_w, attn_b, lengths, ctx);
    fc_kernel<<<(NN + 63) / 64, 256, 0, stream>>>(ctx, fc_w, fc_b, out);
}

// Round 8
// 673.587 us; speedup vs baseline: 1.0408x; 1.0408x over previous
//
#include <hip/hip_runtime.h>
#include <math.h>

#define NN 50000
#define NE 800000
#define EMB 128
#define GH 64
#define BB 64
#define TT 200
#define HH 128
#define G4 512
#define IND 134
#define PM 128
#define PO 128

__device__ __forceinline__ float sigf(float x) { return 1.0f / (1.0f + __expf(-x)); }
__device__ __forceinline__ float tanhf_(float x) { return 1.0f - 2.0f / (__expf(2.0f * x) + 1.0f); }
__device__ __forceinline__ void fma4(float4& a, float s, const float4 w) {
    a.x += s * w.x; a.y += s * w.y; a.z += s * w.z; a.w += s * w.w;
}

// ---------------- CSR build ----------------
__global__ void hist_kernel(const int* __restrict__ ei, const float* __restrict__ ew,
                            int* __restrict__ cnt, float* __restrict__ degw) {
    int e = blockIdx.x * 256 + threadIdx.x;
    if (e >= NE) return;
    int d = ei[NE + e];
    atomicAdd(&cnt[d], 1);
    atomicAdd(&degw[d], ew[e]);
}

__global__ void dinv_kernel(const float* __restrict__ degw, float* __restrict__ dinv) {
    int n = blockIdx.x * 256 + threadIdx.x;
    if (n >= NN) return;
    dinv[n] = rsqrtf(degw[n] + 1.0f);   // +1 self loop
}

__global__ __launch_bounds__(1024) void scan1_kernel(const int* __restrict__ cnt,
                                                     int* __restrict__ rs, int* __restrict__ partials) {
    __shared__ int s[1024];
    int gid = blockIdx.x * 1024 + threadIdx.x;
    int v = (gid < NN) ? cnt[gid] : 0;
    s[threadIdx.x] = v;
    __syncthreads();
    for (int off = 1; off < 1024; off <<= 1) {
        int add = (threadIdx.x >= (unsigned)off) ? s[threadIdx.x - off] : 0;
        __syncthreads();
        s[threadIdx.x] += add;
        __syncthreads();
    }
    if (gid < NN) rs[gid] = s[threadIdx.x] - v;  // exclusive
    if (threadIdx.x == 1023) partials[blockIdx.x] = s[1023];
}

__global__ void scan2_kernel(int* __restrict__ partials, int nblk) {
    if (threadIdx.x == 0) {
        int acc = 0;
        for (int i = 0; i < nblk; ++i) { int v = partials[i]; partials[i] = acc; acc += v; }
    }
}

__global__ __launch_bounds__(1024) void scan3_kernel(const int* __restrict__ partials,
                                                     int* __restrict__ rs, int* __restrict__ cursor) {
    int gid = blockIdx.x * 1024 + threadIdx.x;
    if (gid < NN) {
        int v = rs[gid] + partials[gid >> 10];
        rs[gid] = v;
        cursor[gid] = v;
    }
    if (gid == 0) rs[NN] = NE;
}

__global__ void fill_kernel(const int* __restrict__ ei, const float* __restrict__ ew,
                            const float* __restrict__ dinv, int* __restrict__ cursor,
                            int* __restrict__ ssrc, float* __restrict__ sw) {
    int e = blockIdx.x * 256 + threadIdx.x;
    if (e >= NE) return;
    int s = ei[e], d = ei[NE + e];
    int pos = atomicAdd(&cursor[d], 1);
    ssrc[pos] = s;
    sw[pos] = ew[e] * dinv[s] * dinv[d];
}

// ---------------- W1 transpose+reorder: w1t[o][j], j: 0..127=emb rows(2..129),
// 128..129=coords rows(0..1), 130..133=temporal rows, 134..135=zero pad ----------------
__global__ void w1t_kernel(const float* __restrict__ W1, float* __restrict__ w1t) {
    int i = blockIdx.x * 256 + threadIdx.x;
    if (i >= 64 * 136) return;
    int o = i / 136, j = i - (i / 136) * 136;
    float v = 0.0f;
    if (j < 128) v = W1[(size_t)(j + 2) * GH + o];
    else if (j < 130) v = W1[(size_t)(j - 128) * GH + o];
    else if (j < 134) v = W1[(size_t)j * GH + o];
    w1t[i] = v;
}

// ---------------- GCN layer 1 GEMM v2 (134 -> 64), register-tiled ----------------
// Old: 2144 ds_read_b128 broadcasts/wave (LDS-bound ~40us). v2: 128m x 64o
// tile, both operands LDS-staged, thread = 4m x 8o (acc 32), XOR swizzle
// word = k4 ^ (mt&7) / (ot&7) spreads the 8 per-wave rows across all 8
// bank-quads -> conflict-free. 12 b128 per k4 for 128 MAC (10.7 MAC/LDS).
__global__ __launch_bounds__(256) void gemm1_kernel(const float* __restrict__ coords,
                                                    const float* __restrict__ temporal,
                                                    const float* __restrict__ emb,
                                                    const float* __restrict__ w1t,
                                                    float* __restrict__ h1) {
    __shared__ __align__(16) float xs[128][136];
    __shared__ __align__(16) float wt[64][136];
    int tid = threadIdx.x;
    int m0 = blockIdx.x * 128;
    for (int i = tid; i < 64 * 34; i += 256) {           // stage W^T (swizzled words 0..31)
        int rr = i / 34, w = i - rr * 34;
        float4 v = *(const float4*)&w1t[(size_t)rr * 136 + w * 4];
        int ws = (w < 32) ? (w ^ ((rr >> 3) & 7)) : w;
        *(float4*)&wt[rr][ws * 4] = v;
    }
    for (int i = tid; i < 128 * 32; i += 256) {          // stage emb words 0..31 (swizzled)
        int r = i >> 5, c4 = i & 31;
        int m = m0 + r;
        float4 v = make_float4(0.f, 0.f, 0.f, 0.f);
        if (m < NN) v = *(const float4*)&emb[(size_t)m * EMB + c4 * 4];
        *(float4*)&xs[r][(c4 ^ ((r >> 2) & 7)) * 4] = v;
    }
    for (int i = tid; i < 128 * 8; i += 256) {           // words 32..33: coords+temporal+pad
        int r = i >> 3, c = i & 7;
        int m = m0 + r;
        float v = 0.0f;
        if (m < NN) {
            if (c < 2) v = coords[2 * m + c];
            else if (c < 6) v = temporal[4 * m + (c - 2)];
        }
        xs[r][128 + c] = v;
    }
    __syncthreads();
    int mt = tid >> 3, ot = tid & 7;
    int xswz = mt & 7, wswz = ot & 7;
    float acc[4][8];
#pragma unroll
    for (int mi = 0; mi < 4; ++mi)
#pragma unroll
        for (int oi = 0; oi < 8; ++oi) acc[mi][oi] = 0.0f;
    for (int k4 = 0; k4 < 34; ++k4) {
        int xk = (k4 < 32) ? (k4 ^ xswz) : k4;
        int wk = (k4 < 32) ? (k4 ^ wswz) : k4;
        float4 xv[4], wv[8];
#pragma unroll
        for (int mi = 0; mi < 4; ++mi) xv[mi] = *(const float4*)&xs[mt * 4 + mi][xk * 4];
#pragma unroll
        for (int oi = 0; oi < 8; ++oi) wv[oi] = *(const float4*)&wt[ot * 8 + oi][wk * 4];
#pragma unroll
        for (int mi = 0; mi < 4; ++mi)
#pragma unroll
            for (int oi = 0; oi < 8; ++oi)
                acc[mi][oi] += xv[mi].x * wv[oi].x + xv[mi].y * wv[oi].y
                             + xv[mi].z * wv[oi].z + xv[mi].w * wv[oi].w;
    }
#pragma unroll
    for (int mi = 0; mi < 4; ++mi) {
        int m = m0 + mt * 4 + mi;
        if (m >= NN) continue;
        int ob = ot * 8;
        float4 oa = make_float4(acc[mi][0], acc[mi][1], acc[mi][2], acc[mi][3]);
        float4 obv = make_float4(acc[mi][4], acc[mi][5], acc[mi][6], acc[mi][7]);
        *(float4*)&h1[(size_t)m * GH + ob] = oa;
        *(float4*)&h1[(size_t)m * GH + ob + 4] = obv;
    }
}

// ---------------- symmetric-norm aggregation (64 features, CSR) ----------------
__global__ __launch_bounds__(256) void agg_kernel(const float* __restrict__ hin,
                                                  const int* __restrict__ rs,
                                                  const int* __restrict__ ssrc,
                                                  const float* __restrict__ sw,
                                                  const float* __restrict__ dinv,
                                                  const float* __restrict__ bias, int relu,
                                                  float* __restrict__ hout) {
    int lane = threadIdx.x & 63;
    int wid = threadIdx.x >> 6;
    int n = blockIdx.x * 4 + wid;
    if (n >= NN) return;
    float dv = dinv[n];
    float acc = hin[(size_t)n * GH + lane] * (dv * dv);  // self loop
    int i = rs[n], e1 = rs[n + 1];
    for (; i + 3 < e1; i += 4) {
        int s0 = ssrc[i], s1 = ssrc[i + 1], s2 = ssrc[i + 2], s3 = ssrc[i + 3];
        float w0 = sw[i], w1 = sw[i + 1], w2 = sw[i + 2], w3 = sw[i + 3];
        float a0 = hin[(size_t)s0 * GH + lane];
        float a1 = hin[(size_t)s1 * GH + lane];
        float a2 = hin[(size_t)s2 * GH + lane];
        float a3 = hin[(size_t)s3 * GH + lane];
        acc += a0 * w0 + a1 * w1 + a2 * w2 + a3 * w3;
    }
    for (; i < e1; ++i) acc += hin[(size_t)ssrc[i] * GH + lane] * sw[i];
    if (bias) acc += bias[lane];
    if (relu) acc = fmaxf(acc, 0.0f);
    hout[(size_t)n * GH + lane] = acc;
}

// ---------------- W2 transpose (64x128 -> 128x64) ----------------
__global__ void w2t_kernel(const float* __restrict__ W2, float* __restrict__ w2t) {
    int i = blockIdx.x * 256 + threadIdx.x;
    if (i >= GH * EMB) return;
    int o = i >> 6, k = i & 63;
    w2t[i] = W2[(size_t)k * EMB + o];
}

// ---------------- GCN layer 2 GEMM v2 (64 -> 128), register-tiled ----------------
__global__ __launch_bounds__(256) void gemm2_kernel(const float* __restrict__ a2,
                                                    const float* __restrict__ w2t,
                                                    const float* __restrict__ b2,
                                                    float* __restrict__ z2) {
    int m0 = blockIdx.x * 128, o0 = blockIdx.y * 64;
    __shared__ __align__(16) float xs[128][64];
    __shared__ __align__(16) float wt[64][64];
    __shared__ float bsh[64];
    int tid = threadIdx.x;
#pragma unroll
    for (int i = 0; i < 8; ++i) {            // stage a2 rows (swizzled)
        int idx = i * 256 + tid;
        int r = idx >> 4, c4 = idx & 15;
        int m = m0 + r;
        float4 v = (m < NN) ? *(const float4*)&a2[(size_t)m * GH + c4 * 4]
                            : make_float4(0.f, 0.f, 0.f, 0.f);
        *(float4*)&xs[r][(c4 ^ ((r >> 2) & 3)) * 4] = v;
    }
#pragma unroll
    for (int i = 0; i < 4; ++i) {            // stage w2t rows (swizzled)
        int idx = i * 256 + tid;
        int r = idx >> 4, c4 = idx & 15;
        float4 v = *(const float4*)&w2t[(size_t)(o0 + r) * GH + c4 * 4];
        *(float4*)&wt[r][(c4 ^ ((r >> 3) & 7)) * 4] = v;
    }
    if (tid < 64) bsh[tid] = b2[o0 + tid];
    __syncthreads();
    int mt = tid >> 3, ot = tid & 7;        // mt 0..31 (4 m each), ot 0..7 (8 o each)
    float acc[4][8];
#pragma unroll
    for (int mi = 0; mi < 4; ++mi)
#pragma unroll
        for (int oi = 0; oi < 8; ++oi) acc[mi][oi] = 0.0f;
    for (int k4 = 0; k4 < 16; ++k4) {
        int xc = (k4 ^ (mt & 3)) * 4;
        int wc = (k4 ^ (ot & 7)) * 4;
        float4 xv[4], wv[8];
#pragma unroll
        for (int mi = 0; mi < 4; ++mi) xv[mi] = *(const float4*)&xs[mt * 4 + mi][xc];
#pragma unroll
        for (int oi = 0; oi < 8; ++oi) wv[oi] = *(const float4*)&wt[ot * 8 + oi][wc];
#pragma unroll
        for (int mi = 0; mi < 4; ++mi)
#pragma unroll
            for (int oi = 0; oi < 8; ++oi)
                acc[mi][oi] += xv[mi].x * wv[oi].x + xv[mi].y * wv[oi].y
                             + xv[mi].z * wv[oi].z + xv[mi].w * wv[oi].w;
    }
#pragma unroll
    for (int mi = 0; mi < 4; ++mi) {
        int m = m0 + mt * 4 + mi;
        if (m >= NN) continue;
        int ob = ot * 8;
        float4 oa = make_float4(acc[mi][0] + bsh[ob + 0], acc[mi][1] + bsh[ob + 1],
                                acc[mi][2] + bsh[ob + 2], acc[mi][3] + bsh[ob + 3]);
        float4 obv = make_float4(acc[mi][4] + bsh[ob + 4], acc[mi][5] + bsh[ob + 5],
                                 acc[mi][6] + bsh[ob + 6], acc[mi][7] + bsh[ob + 7]);
        *(float4*)&z2[(size_t)m * EMB + o0 + ob] = oa;
        *(float4*)&z2[(size_t)m * EMB + o0 + ob + 4] = obv;
    }
}

// ---------------- gather sequence embeddings ----------------
__global__ void gather_kernel(const int* __restrict__ seq, const float* __restrict__ z2,
                              float* __restrict__ se) {
    int idx = blockIdx.x * 256 + threadIdx.x;
    if (idx >= BB * TT * 32) return;
    int r = idx >> 5, q = idx & 31;
    int node = seq[r];
    ((float4*)se)[(size_t)r * 32 + q] = ((const float4*)z2)[(size_t)node * 32 + q];
}

// ---------------- pre-GEMM v3: tiled GEMM [12800 x 128] @ [128 x 512]^T ----------------
__global__ __launch_bounds__(256) void pregemm_kernel(const float* __restrict__ se,
                                                      const float* __restrict__ w_ih_f,
                                                      const float* __restrict__ w_ih_b,
                                                      const float* __restrict__ b_ih_f,
                                                      const float* __restrict__ b_hh_f,
                                                      const float* __restrict__ b_ih_b,
                                                      const float* __restrict__ b_hh_b,
                                                      const int* __restrict__ lengths,
                                                      float* __restrict__ xpf,
                                                      float* __restrict__ xpb) {
    int dir = blockIdx.z;
    const float* w_ih = dir ? w_ih_b : w_ih_f;
    int o0 = blockIdx.y * PO;
    int m0 = blockIdx.x * PM;
    __shared__ __align__(16) float xs[PM][EMB];
    __shared__ __align__(16) float ws[PO][EMB];
    __shared__ float bsh[PO];
    int tid = threadIdx.x;
#pragma unroll
    for (int i = 0; i < 16; ++i) {          // stage W (swizzled)
        int idx = i * 256 + tid;
        int row = idx >> 5, c4 = idx & 31;
        float4 v = *(const float4*)&w_ih[(size_t)(o0 + row) * EMB + c4 * 4];
        *(float4*)&ws[row][(c4 ^ ((row >> 3) & 7)) * 4] = v;
    }
    if (tid < PO) bsh[tid] = dir ? (b_ih_b[o0 + tid] + b_hh_b[o0 + tid])
                                 : (b_ih_f[o0 + tid] + b_hh_f[o0 + tid]);
#pragma unroll
    for (int i = 0; i < 16; ++i) {          // stage x (swizzled)
        int idx = i * 256 + tid;
        int r = idx >> 5, c4 = idx & 31;
        int m = m0 + r;
        int t = m >> 6, b = m & 63;
        int tsrc = t;
        if (dir) { int len = lengths[b]; tsrc = (t < len) ? (len - 1 - t) : t; }
        float4 v = *(const float4*)&se[((size_t)b * TT + tsrc) * EMB + c4 * 4];
        *(float4*)&xs[r][(c4 ^ ((r >> 3) & 3)) * 4] = v;
    }
    __syncthreads();
    int mt = tid >> 4, ot = tid & 15;   // each 0..15
    int mswz = mt & 3, oswz = ot & 7;
    float acc[8][8];
#pragma unroll
    for (int mi = 0; mi < 8; ++mi)
#pragma unroll
        for (int oi = 0; oi < 8; ++oi) acc[mi][oi] = 0.0f;
    for (int k4 = 0; k4 < 32; ++k4) {
        int xk = (k4 ^ mswz) * 4;
        int wk = (k4 ^ oswz) * 4;
        float4 xv[8], wv[8];
#pragma unroll
        for (int mi = 0; mi < 8; ++mi) xv[mi] = *(const float4*)&xs[mt * 8 + mi][xk];
#pragma unroll
        for (int oi = 0; oi < 8; ++oi) wv[oi] = *(const float4*)&ws[ot * 8 + oi][wk];
#pragma unroll
        for (int mi = 0; mi < 8; ++mi)
#pragma unroll
            for (int oi = 0; oi < 8; ++oi)
                acc[mi][oi] += xv[mi].x * wv[oi].x + xv[mi].y * wv[oi].y
                             + xv[mi].z * wv[oi].z + xv[mi].w * wv[oi].w;
    }
    float* xp = dir ? xpb : xpf;
#pragma unroll
    for (int mi = 0; mi < 8; ++mi) {
        int m = m0 + mt * 8 + mi;
        int ob = ot * 8;
        float4 oa = make_float4(acc[mi][0] + bsh[ob + 0], acc[mi][1] + bsh[ob + 1],
                                acc[mi][2] + bsh[ob + 2], acc[mi][3] + bsh[ob + 3]);
        float4 obv = make_float4(acc[mi][4] + bsh[ob + 4], acc[mi][5] + bsh[ob + 5],
                                 acc[mi][6] + bsh[ob + 6], acc[mi][7] + bsh[ob + 7]);
        *(float4*)&xp[(size_t)m * G4 + o0 + ob] = oa;
        *(float4*)&xp[(size_t)m * G4 + o0 + ob + 4] = obv;
    }
}

// ---------------- LSTM recurrence (Structure Z, reverted from the shfl v4) ----------------
// R7 lesson: __shfl_xor on CDNA = ds_bpermute = LDS-PIPE instruction; the
// "in-wave" butterfly was 192 LDS instrs/step (vs ~90 here) -> 245us. This
// R6 structure measured 175us. Micro-opt: kq=0 lanes (== phase-B threads)
// keep their partial in-register: 7 part writes + 7 reads instead of 8+8.
__global__ __launch_bounds__(1024, 4) void lstm_kernel(const float* __restrict__ xpf,
                                                       const float* __restrict__ xpb,
                                                       const float* __restrict__ w_hh_f,
                                                       const float* __restrict__ w_hh_b,
                                                       const int* __restrict__ lengths,
                                                       float* __restrict__ hfo,
                                                       float* __restrict__ hbo) {
    int chain = blockIdx.x;
    int dir = chain & 1, b = chain >> 1;
    const float* w_hh = dir ? w_hh_b : w_hh_f;
    const float* xp = dir ? xpb : xpf;
    float* ho = dir ? hbo : hfo;
    int tid = threadIdx.x;
    int u = tid & 127;
    int kq = tid >> 7;    // 0..7
    int len = lengths[b];

    float4 W[4][4];
#pragma unroll
    for (int g = 0; g < 4; ++g)
#pragma unroll
        for (int j4 = 0; j4 < 4; ++j4)
            W[g][j4] = *(const float4*)&w_hh[(size_t)(g * HH + u) * HH + kq * 16 + j4 * 4];

    __shared__ __align__(16) float hl[HH];
    __shared__ __align__(16) float part[HH][9][4];   // [u][kq(pad 9)][gate]
    if (tid < HH) hl[tid] = 0.0f;
    __syncthreads();

    float cst = 0.0f;
    float x0 = 0.f, x1 = 0.f, x2 = 0.f, x3 = 0.f;
    const float* xpt = xp + (size_t)b * G4 + u;
    if (tid < HH && len > 0) {
        x0 = xpt[0]; x1 = xpt[HH]; x2 = xpt[2 * HH]; x3 = xpt[3 * HH];
    }
    for (int t = 0; t < len; ++t) {
        // phase A: all 16 waves; uniform h broadcast reads
        const float4* h4 = (const float4*)&hl[kq * 16];
        float a0 = 0.f, a1 = 0.f, a2 = 0.f, a3 = 0.f;
#pragma unroll
        for (int j4 = 0; j4 < 4; ++j4) {
            float4 hv = h4[j4];
            a0 += W[0][j4].x * hv.x + W[0][j4].y * hv.y + W[0][j4].z * hv.z + W[0][j4].w * hv.w;
            a1 += W[1][j4].x * hv.x + W[1][j4].y * hv.y + W[1][j4].z * hv.z + W[1][j4].w * hv.w;
            a2 += W[2][j4].x * hv.x + W[2][j4].y * hv.y + W[2][j4].z * hv.z + W[2][j4].w * hv.w;
            a3 += W[3][j4].x * hv.x + W[3][j4].y * hv.y + W[3][j4].z * hv.z + W[3][j4].w * hv.w;
        }
        if (kq) *(float4*)&part[u][kq][0] = make_float4(a0, a1, a2, a3);
        __syncthreads();
        // phase B: 2 waves (== the kq=0 threads) finish unit u
        if (tid < HH) {
            float n0 = 0.f, n1 = 0.f, n2 = 0.f, n3 = 0.f;
            if (t + 1 < len) {
                const float* xn = xpt + (size_t)(t + 1) * (BB * G4);
                n0 = xn[0]; n1 = xn[HH]; n2 = xn[2 * HH]; n3 = xn[3 * HH];
            }
            float s0 = x0 + a0, s1 = x1 + a1, s2 = x2 + a2, s3 = x3 + a3;
#pragma unroll
            for (int q = 1; q < 8; ++q) {
                float4 p = *(const float4*)&part[u][q][0];
                s0 += p.x; s1 += p.y; s2 += p.z; s3 += p.w;
            }
            float gi = sigf(s0), gf = sigf(s1), gg = tanhf_(s2), go = sigf(s3);
            cst = gf * cst + gi * gg;
            float h = go * tanhf_(cst);
            hl[u] = h;
            int tt = dir ? (len - 1 - t) : t;
            ho[((size_t)b * TT + tt) * HH + u] = h;
            x0 = n0; x1 = n1; x2 = n2; x3 = n3;
        }
        __syncthreads();
    }
}

// ---------------- masked attention pooling ----------------
__global__ __launch_bounds__(256) void attn_kernel(const float* __restrict__ hf,
                                                   const float* __restrict__ hb,
                                                   const float* __restrict__ attn_w,
                                                   const float* __restrict__ attn_b,
                                                   const int* __restrict__ lengths,
                                                   float* __restrict__ ctx) {
    int b = blockIdx.x;
    int tid = threadIdx.x;
    int len = lengths[b];
    __shared__ __align__(16) float wl[256];
    __shared__ float pl[256];
    __shared__ float red[256];
    wl[tid] = attn_w[tid];
    __syncthreads();
    float sc = -3.0e38f;
    if (tid < len) {
        const float4* rf = (const float4*)(hf + ((size_t)b * TT + tid) * HH);
        const float4* rb = (const float4*)(hb + ((size_t)b * TT + tid) * HH);
        const float4* w4 = (const float4*)wl;
        float s = attn_b[0];
        for (int k4 = 0; k4 < 32; ++k4) {
            float4 a = rf[k4], ww = w4[k4];
            s += a.x * ww.x + a.y * ww.y + a.z * ww.z + a.w * ww.w;
        }
        for (int k4 = 0; k4 < 32; ++k4) {
            float4 a = rb[k4], ww = w4[32 + k4];
            s += a.x * ww.x + a.y * ww.y + a.z * ww.z + a.w * ww.w;
        }
        sc = s;
    }
    red[tid] = sc;
    __syncthreads();
    for (int off = 128; off > 0; off >>= 1) {
        if (tid < off) red[tid] = fmaxf(red[tid], red[tid + off]);
        __syncthreads();
    }
    float mx = red[0];
    __syncthreads();
    float e = (tid < len) ? __expf(sc - mx) : 0.0f;
    red[tid] = e;
    __syncthreads();
    for (int off = 128; off > 0; off >>= 1) {
        if (tid < off) red[tid] += red[tid + off];
        __syncthreads();
    }
    float inv = 1.0f / red[0];
    pl[tid] = e * inv;
    __syncthreads();
    float acc = 0.0f;
    const float* basep = (tid < HH) ? (hf + (size_t)b * TT * HH + tid)
                                    : (hb + (size_t)b * TT * HH + (tid - HH));
#pragma unroll 4
    for (int t = 0; t < len; ++t) acc += pl[t] * basep[(size_t)t * HH];
    ctx[(size_t)b * 256 + tid] = acc;
}

// ---------------- final FC v2: [64,256] @ [256,N] + b, 4 n-cols/thread ----------------
// Old: 1024 LDS b128/wave x 12 waves/CU = LDS-bound ~60us. v2: thread owns
// 4 n columns (spaced 64) x 16 b rows -> waves 3128 -> 784, per-CU LDS
// 150K -> 37K cyc; HBM floor 8us (fc_w read exactly once).
__global__ __launch_bounds__(256) void fc_kernel(const float* __restrict__ ctx,
                                                 const float* __restrict__ fc_w,
                                                 const float* __restrict__ fc_b,
                                                 float* __restrict__ out) {
    __shared__ __align__(16) float cl[64][256];
    for (int i = threadIdx.x; i < 64 * 256 / 4; i += 256)
        ((float4*)cl)[i] = ((const float4*)ctx)[i];
    __syncthreads();
    int lane = threadIdx.x & 63;
    int bq = threadIdx.x >> 6;
    int nb = blockIdx.x * 256 + lane;
    float acc[16][4];
#pragma unroll
    for (int i = 0; i < 16; ++i)
#pragma unroll
        for (int c = 0; c < 4; ++c) acc[i][c] = 0.0f;
    for (int k4 = 0; k4 < 64; ++k4) {
        int k = k4 * 4;
        float w[4][4];   // [j = k sub][c = col group]
#pragma unroll
        for (int j = 0; j < 4; ++j)
#pragma unroll
            for (int c = 0; c < 4; ++c) {
                int n = nb + c * 64;
                w[j][c] = (n < NN) ? fc_w[(size_t)(k + j) * NN + n] : 0.0f;
            }
#pragma unroll
        for (int i = 0; i < 16; ++i) {
            float4 cv = *(const float4*)&cl[bq * 16 + i][k];
#pragma unroll
            for (int c = 0; c < 4; ++c)
                acc[i][c] += cv.x * w[0][c] + cv.y * w[1][c] + cv.z * w[2][c] + cv.w * w[3][c];
        }
    }
    float fb[4];
#pragma unroll
    for (int c = 0; c < 4; ++c) {
        int n = nb + c * 64;
        fb[c] = (n < NN) ? fc_b[n] : 0.0f;
    }
#pragma unroll
    for (int i = 0; i < 16; ++i)
#pragma unroll
        for (int c = 0; c < 4; ++c) {
            int n = nb + c * 64;
            if (n < NN) out[(size_t)(bq * 16 + i) * NN + n] = acc[i][c] + fb[c];
        }
}

// ---------------- host launcher ----------------
extern "C" void kernel_launch(void* const* d_in, const int* in_sizes, int n_in,
                              void* d_out, int out_size, void* d_ws, size_t ws_size,
                              hipStream_t stream) {
    const float* x_coords   = (const float*)d_in[0];
    const float* temporal   = (const float*)d_in[1];
    const int*   edge_index = (const int*)d_in[2];
    const float* edge_w     = (const float*)d_in[3];
    const int*   seq        = (const int*)d_in[4];
    const int*   lengths    = (const int*)d_in[5];
    const float* node_emb   = (const float*)d_in[6];
    const float* gcn1_w     = (const float*)d_in[7];
    const float* gcn1_b     = (const float*)d_in[8];
    const float* gcn2_w     = (const float*)d_in[9];
    const float* gcn2_b     = (const float*)d_in[10];
    const float* w_ih_f     = (const float*)d_in[11];
    const float* w_hh_f     = (const float*)d_in[12];
    const float* b_ih_f     = (const float*)d_in[13];
    const float* b_hh_f     = (const float*)d_in[14];
    const float* w_ih_b     = (const float*)d_in[15];
    const float* w_hh_b     = (const float*)d_in[16];
    const float* b_ih_b     = (const float*)d_in[17];
    const float* b_hh_b     = (const float*)d_in[18];
    const float* attn_w     = (const float*)d_in[19];
    const float* attn_b     = (const float*)d_in[20];
    const float* fc_w       = (const float*)d_in[21];
    const float* fc_b       = (const float*)d_in[22];
    float* out = (float*)d_out;

    char* base = (char*)d_ws;
    size_t off = 0;
    auto alloc = [&](size_t nbytes) -> void* {
        void* p = base + off;
        off = (off + nbytes + 255) & ~(size_t)255;
        return p;
    };
    int*   cnt     = (int*)alloc((size_t)2 * NN * 4);  // cnt + degw contiguous (one memset)
    float* degw    = (float*)(cnt + NN);
    float* dinv    = (float*)alloc((size_t)NN * 4);
    int*   rs      = (int*)alloc(((size_t)NN + 1) * 4);
    int*   cursor  = (int*)alloc((size_t)NN * 4);
    int*   partials= (int*)alloc(64 * 4);
    int*   ssrc    = (int*)alloc((size_t)NE * 4);
    float* sw      = (float*)alloc((size_t)NE * 4);
    float* h1      = (float*)alloc((size_t)NN * GH * 4);
    float* z1      = (float*)alloc((size_t)NN * GH * 4);
    float* a2      = h1;  // h1 dead after agg1
    float* w1t     = (float*)alloc((size_t)64 * 136 * 4);
    float* w2t     = (float*)alloc((size_t)GH * EMB * 4);
    float* z2      = (float*)alloc((size_t)NN * EMB * 4);
    float* se      = (float*)alloc((size_t)BB * TT * EMB * 4);
    float* xpf     = (float*)alloc((size_t)TT * BB * G4 * 4);
    float* xpb     = (float*)alloc((size_t)TT * BB * G4 * 4);
    float* hfo     = (float*)alloc((size_t)BB * TT * HH * 4);
    float* hbo     = (float*)alloc((size_t)BB * TT * HH * 4);
    float* ctx     = (float*)alloc((size_t)BB * 256 * 4);
    (void)ws_size; (void)in_sizes; (void)n_in; (void)out_size;

    hipMemsetAsync(cnt, 0, (size_t)2 * NN * 4, stream);

    hist_kernel<<<(NE + 255) / 256, 256, 0, stream>>>(edge_index, edge_w, cnt, degw);
    dinv_kernel<<<(NN + 255) / 256, 256, 0, stream>>>(degw, dinv);
    const int nblk = (NN + 1023) / 1024;  // 49
    scan1_kernel<<<nblk, 1024, 0, stream>>>(cnt, rs, partials);
    scan2_kernel<<<1, 64, 0, stream>>>(partials, nblk);
    scan3_kernel<<<nblk, 1024, 0, stream>>>(partials, rs, cursor);
    fill_kernel<<<(NE + 255) / 256, 256, 0, stream>>>(edge_index, edge_w, dinv, cursor, ssrc, sw);
    w1t_kernel<<<(64 * 136 + 255) / 256, 256, 0, stream>>>(gcn1_w, w1t);
    w2t_kernel<<<(GH * EMB + 255) / 256, 256, 0, stream>>>(gcn2_w, w2t);

    gemm1_kernel<<<(NN + 127) / 128, 256, 0, stream>>>(x_coords, temporal, node_emb, w1t, h1);
    agg_kernel<<<(NN + 3) / 4, 256, 0, stream>>>(h1, rs, ssrc, sw, dinv, gcn1_b, 1, z1);
    agg_kernel<<<(NN + 3) / 4, 256, 0, stream>>>(z1, rs, ssrc, sw, dinv, (const float*)nullptr, 0, a2);
    gemm2_kernel<<<dim3((NN + 127) / 128, 2), 256, 0, stream>>>(a2, w2t, gcn2_b, z2);

    gather_kernel<<<(BB * TT * 32 + 255) / 256, 256, 0, stream>>>(seq, z2, se);
    pregemm_kernel<<<dim3(TT * BB / PM, G4 / PO, 2), 256, 0, stream>>>(
        se, w_ih_f, w_ih_b, b_ih_f, b_hh_f, b_ih_b, b_hh_b, lengths, xpf, xpb);
    lstm_kernel<<<BB * 2, 1024, 0, stream>>>(xpf, xpb, w_hh_f, w_hh_b, lengths, hfo, hbo);
    attn_kernel<<<BB, 256, 0, stream>>>(hfo, hbo, attn_w, attn_b, lengths, ctx);
    fc_kernel<<<(NN + 255) / 256, 256, 0, stream>>>(ctx, fc_w, fc_b, out);
}

// Round 9
// 666.591 us; speedup vs baseline: 1.0517x; 1.0105x over previous
//
#include <hip/hip_runtime.h>
#include <math.h>

#define NN 50000
#define NE 800000
#define EMB 128
#define GH 64
#define BB 64
#define TT 200
#define HH 128
#define G4 512
#define IND 134
#define PM 128
#define PO 128

__device__ __forceinline__ float sigf(float x) { return 1.0f / (1.0f + __expf(-x)); }
__device__ __forceinline__ float tanhf_(float x) { return 1.0f - 2.0f / (__expf(2.0f * x) + 1.0f); }

// ---------------- CSR build ----------------
__global__ void hist_kernel(const int* __restrict__ ei, const float* __restrict__ ew,
                            int* __restrict__ cnt, float* __restrict__ degw) {
    int e = blockIdx.x * 256 + threadIdx.x;
    if (e >= NE) return;
    int d = ei[NE + e];
    atomicAdd(&cnt[d], 1);
    atomicAdd(&degw[d], ew[e]);
}

// scan1 + dinv fused (both depend only on hist)
__global__ __launch_bounds__(1024) void scan1_kernel(const int* __restrict__ cnt,
                                                     const float* __restrict__ degw,
                                                     float* __restrict__ dinv,
                                                     int* __restrict__ rs, int* __restrict__ partials) {
    __shared__ int s[1024];
    int gid = blockIdx.x * 1024 + threadIdx.x;
    int v = (gid < NN) ? cnt[gid] : 0;
    if (gid < NN) dinv[gid] = rsqrtf(degw[gid] + 1.0f);   // +1 self loop
    s[threadIdx.x] = v;
    __syncthreads();
    for (int off = 1; off < 1024; off <<= 1) {
        int add = (threadIdx.x >= (unsigned)off) ? s[threadIdx.x - off] : 0;
        __syncthreads();
        s[threadIdx.x] += add;
        __syncthreads();
    }
    if (gid < NN) rs[gid] = s[threadIdx.x] - v;  // exclusive
    if (threadIdx.x == 1023) partials[blockIdx.x] = s[1023];
}

// misc: block 0 = parallel scan of partials (was 1-thread, ~12us); blocks 1..34
// = W1 transpose+reorder; blocks 35..66 = W2 transpose.
__global__ void misc_kernel(int* __restrict__ partials, int nblk,
                            const float* __restrict__ W1, float* __restrict__ w1t,
                            const float* __restrict__ W2, float* __restrict__ w2t) {
    int blk = blockIdx.x;
    int tid = threadIdx.x;
    if (blk == 0) {
        __shared__ int s[64];
        int v = (tid < nblk) ? partials[tid] : 0;
        s[tid] = v;
        __syncthreads();
        for (int off = 1; off < 64; off <<= 1) {
            int add = (tid >= off) ? s[tid - off] : 0;
            __syncthreads();
            s[tid] += add;
            __syncthreads();
        }
        if (tid < nblk) partials[tid] = s[tid] - v;  // exclusive
    } else if (blk <= 34) {
        int i = (blk - 1) * 256 + tid;
        if (i < 64 * 136) {
            int o = i / 136, j = i - o * 136;
            float v = 0.0f;
            if (j < 128) v = W1[(size_t)(j + 2) * GH + o];
            else if (j < 130) v = W1[(size_t)(j - 128) * GH + o];
            else if (j < 134) v = W1[(size_t)j * GH + o];
            w1t[i] = v;
        }
    } else {
        int i = (blk - 35) * 256 + tid;
        if (i < GH * EMB) {
            int o = i >> 6, k = i & 63;
            w2t[i] = W2[(size_t)k * EMB + o];
        }
    }
}

__global__ __launch_bounds__(1024) void scan3_kernel(const int* __restrict__ partials,
                                                     int* __restrict__ rs, int* __restrict__ cursor) {
    int gid = blockIdx.x * 1024 + threadIdx.x;
    if (gid < NN) {
        int v = rs[gid] + partials[gid >> 10];
        rs[gid] = v;
        cursor[gid] = v;
    }
    if (gid == 0) rs[NN] = NE;
}

// fill: (src, weight) packed into int2 -> ONE random 8B scatter instead of two 4B
__global__ void fill_kernel(const int* __restrict__ ei, const float* __restrict__ ew,
                            const float* __restrict__ dinv, int* __restrict__ cursor,
                            int2* __restrict__ ssrcw) {
    int e = blockIdx.x * 256 + threadIdx.x;
    if (e >= NE) return;
    int s = ei[e], d = ei[NE + e];
    int pos = atomicAdd(&cursor[d], 1);
    ssrcw[pos] = make_int2(s, __float_as_int(ew[e] * dinv[s] * dinv[d]));
}

// ---------------- GCN layer 1 GEMM v2 (134 -> 64), register-tiled ----------------
__global__ __launch_bounds__(256) void gemm1_kernel(const float* __restrict__ coords,
                                                    const float* __restrict__ temporal,
                                                    const float* __restrict__ emb,
                                                    const float* __restrict__ w1t,
                                                    float* __restrict__ h1) {
    __shared__ __align__(16) float xs[128][136];
    __shared__ __align__(16) float wt[64][136];
    int tid = threadIdx.x;
    int m0 = blockIdx.x * 128;
    for (int i = tid; i < 64 * 34; i += 256) {           // stage W^T (swizzled words 0..31)
        int rr = i / 34, w = i - rr * 34;
        float4 v = *(const float4*)&w1t[(size_t)rr * 136 + w * 4];
        int ws = (w < 32) ? (w ^ ((rr >> 3) & 7)) : w;
        *(float4*)&wt[rr][ws * 4] = v;
    }
    for (int i = tid; i < 128 * 32; i += 256) {          // stage emb words 0..31 (swizzled)
        int r = i >> 5, c4 = i & 31;
        int m = m0 + r;
        float4 v = make_float4(0.f, 0.f, 0.f, 0.f);
        if (m < NN) v = *(const float4*)&emb[(size_t)m * EMB + c4 * 4];
        *(float4*)&xs[r][(c4 ^ ((r >> 2) & 7)) * 4] = v;
    }
    for (int i = tid; i < 128 * 8; i += 256) {           // words 32..33: coords+temporal+pad
        int r = i >> 3, c = i & 7;
        int m = m0 + r;
        float v = 0.0f;
        if (m < NN) {
            if (c < 2) v = coords[2 * m + c];
            else if (c < 6) v = temporal[4 * m + (c - 2)];
        }
        xs[r][128 + c] = v;
    }
    __syncthreads();
    int mt = tid >> 3, ot = tid & 7;
    int xswz = mt & 7, wswz = ot & 7;
    float acc[4][8];
#pragma unroll
    for (int mi = 0; mi < 4; ++mi)
#pragma unroll
        for (int oi = 0; oi < 8; ++oi) acc[mi][oi] = 0.0f;
    for (int k4 = 0; k4 < 34; ++k4) {
        int xk = (k4 < 32) ? (k4 ^ xswz) : k4;
        int wk = (k4 < 32) ? (k4 ^ wswz) : k4;
        float4 xv[4], wv[8];
#pragma unroll
        for (int mi = 0; mi < 4; ++mi) xv[mi] = *(const float4*)&xs[mt * 4 + mi][xk * 4];
#pragma unroll
        for (int oi = 0; oi < 8; ++oi) wv[oi] = *(const float4*)&wt[ot * 8 + oi][wk * 4];
#pragma unroll
        for (int mi = 0; mi < 4; ++mi)
#pragma unroll
            for (int oi = 0; oi < 8; ++oi)
                acc[mi][oi] += xv[mi].x * wv[oi].x + xv[mi].y * wv[oi].y
                             + xv[mi].z * wv[oi].z + xv[mi].w * wv[oi].w;
    }
#pragma unroll
    for (int mi = 0; mi < 4; ++mi) {
        int m = m0 + mt * 4 + mi;
        if (m >= NN) continue;
        int ob = ot * 8;
        *(float4*)&h1[(size_t)m * GH + ob] = make_float4(acc[mi][0], acc[mi][1], acc[mi][2], acc[mi][3]);
        *(float4*)&h1[(size_t)m * GH + ob + 4] = make_float4(acc[mi][4], acc[mi][5], acc[mi][6], acc[mi][7]);
    }
}

// ---------------- symmetric-norm aggregation (64 features, CSR, int2 edges) ----------------
__global__ __launch_bounds__(256) void agg_kernel(const float* __restrict__ hin,
                                                  const int* __restrict__ rs,
                                                  const int2* __restrict__ ssrcw,
                                                  const float* __restrict__ dinv,
                                                  const float* __restrict__ bias, int relu,
                                                  float* __restrict__ hout) {
    int lane = threadIdx.x & 63;
    int wid = threadIdx.x >> 6;
    int n = blockIdx.x * 4 + wid;
    if (n >= NN) return;
    float dv = dinv[n];
    float acc = hin[(size_t)n * GH + lane] * (dv * dv);  // self loop
    int i = rs[n], e1 = rs[n + 1];
    for (; i + 3 < e1; i += 4) {
        int4 p0 = *(const int4*)&ssrcw[i];       // edges i, i+1
        int4 p1 = *(const int4*)&ssrcw[i + 2];   // edges i+2, i+3
        float a0 = hin[(size_t)p0.x * GH + lane];
        float a1 = hin[(size_t)p0.z * GH + lane];
        float a2 = hin[(size_t)p1.x * GH + lane];
        float a3 = hin[(size_t)p1.z * GH + lane];
        acc += a0 * __int_as_float(p0.y) + a1 * __int_as_float(p0.w)
             + a2 * __int_as_float(p1.y) + a3 * __int_as_float(p1.w);
    }
    for (; i < e1; ++i) {
        int2 p = ssrcw[i];
        acc += hin[(size_t)p.x * GH + lane] * __int_as_float(p.y);
    }
    if (bias) acc += bias[lane];
    if (relu) acc = fmaxf(acc, 0.0f);
    hout[(size_t)n * GH + lane] = acc;
}

// ---------------- GCN layer 2 GEMM v2 (64 -> 128), register-tiled ----------------
__global__ __launch_bounds__(256) void gemm2_kernel(const float* __restrict__ a2,
                                                    const float* __restrict__ w2t,
                                                    const float* __restrict__ b2,
                                                    float* __restrict__ z2) {
    int m0 = blockIdx.x * 128, o0 = blockIdx.y * 64;
    __shared__ __align__(16) float xs[128][64];
    __shared__ __align__(16) float wt[64][64];
    __shared__ float bsh[64];
    int tid = threadIdx.x;
#pragma unroll
    for (int i = 0; i < 8; ++i) {            // stage a2 rows (swizzled)
        int idx = i * 256 + tid;
        int r = idx >> 4, c4 = idx & 15;
        int m = m0 + r;
        float4 v = (m < NN) ? *(const float4*)&a2[(size_t)m * GH + c4 * 4]
                            : make_float4(0.f, 0.f, 0.f, 0.f);
        *(float4*)&xs[r][(c4 ^ ((r >> 2) & 3)) * 4] = v;
    }
#pragma unroll
    for (int i = 0; i < 4; ++i) {            // stage w2t rows (swizzled)
        int idx = i * 256 + tid;
        int r = idx >> 4, c4 = idx & 15;
        float4 v = *(const float4*)&w2t[(size_t)(o0 + r) * GH + c4 * 4];
        *(float4*)&wt[r][(c4 ^ ((r >> 3) & 7)) * 4] = v;
    }
    if (tid < 64) bsh[tid] = b2[o0 + tid];
    __syncthreads();
    int mt = tid >> 3, ot = tid & 7;
    float acc[4][8];
#pragma unroll
    for (int mi = 0; mi < 4; ++mi)
#pragma unroll
        for (int oi = 0; oi < 8; ++oi) acc[mi][oi] = 0.0f;
    for (int k4 = 0; k4 < 16; ++k4) {
        int xc = (k4 ^ (mt & 3)) * 4;
        int wc = (k4 ^ (ot & 7)) * 4;
        float4 xv[4], wv[8];
#pragma unroll
        for (int mi = 0; mi < 4; ++mi) xv[mi] = *(const float4*)&xs[mt * 4 + mi][xc];
#pragma unroll
        for (int oi = 0; oi < 8; ++oi) wv[oi] = *(const float4*)&wt[ot * 8 + oi][wc];
#pragma unroll
        for (int mi = 0; mi < 4; ++mi)
#pragma unroll
            for (int oi = 0; oi < 8; ++oi)
                acc[mi][oi] += xv[mi].x * wv[oi].x + xv[mi].y * wv[oi].y
                             + xv[mi].z * wv[oi].z + xv[mi].w * wv[oi].w;
    }
#pragma unroll
    for (int mi = 0; mi < 4; ++mi) {
        int m = m0 + mt * 4 + mi;
        if (m >= NN) continue;
        int ob = ot * 8;
        float4 oa = make_float4(acc[mi][0] + bsh[ob + 0], acc[mi][1] + bsh[ob + 1],
                                acc[mi][2] + bsh[ob + 2], acc[mi][3] + bsh[ob + 3]);
        float4 obv = make_float4(acc[mi][4] + bsh[ob + 4], acc[mi][5] + bsh[ob + 5],
                                 acc[mi][6] + bsh[ob + 6], acc[mi][7] + bsh[ob + 7]);
        *(float4*)&z2[(size_t)m * EMB + o0 + ob] = oa;
        *(float4*)&z2[(size_t)m * EMB + o0 + ob + 4] = obv;
    }
}

// ---------------- pre-GEMM v4: gather fused into staging (se buffer removed) ----------------
__global__ __launch_bounds__(256) void pregemm_kernel(const float* __restrict__ z2,
                                                      const int* __restrict__ seq,
                                                      const float* __restrict__ w_ih_f,
                                                      const float* __restrict__ w_ih_b,
                                                      const float* __restrict__ b_ih_f,
                                                      const float* __restrict__ b_hh_f,
                                                      const float* __restrict__ b_ih_b,
                                                      const float* __restrict__ b_hh_b,
                                                      const int* __restrict__ lengths,
                                                      float* __restrict__ xpf,
                                                      float* __restrict__ xpb) {
    int dir = blockIdx.z;
    const float* w_ih = dir ? w_ih_b : w_ih_f;
    int o0 = blockIdx.y * PO;
    int m0 = blockIdx.x * PM;
    __shared__ __align__(16) float xs[PM][EMB];
    __shared__ __align__(16) float ws[PO][EMB];
    __shared__ float bsh[PO];
    int tid = threadIdx.x;
#pragma unroll
    for (int i = 0; i < 16; ++i) {          // stage W (swizzled)
        int idx = i * 256 + tid;
        int row = idx >> 5, c4 = idx & 31;
        float4 v = *(const float4*)&w_ih[(size_t)(o0 + row) * EMB + c4 * 4];
        *(float4*)&ws[row][(c4 ^ ((row >> 3) & 7)) * 4] = v;
    }
    if (tid < PO) bsh[tid] = dir ? (b_ih_b[o0 + tid] + b_hh_b[o0 + tid])
                                 : (b_ih_f[o0 + tid] + b_hh_f[o0 + tid]);
#pragma unroll
    for (int i = 0; i < 16; ++i) {          // stage x via fused gather (swizzled)
        int idx = i * 256 + tid;
        int r = idx >> 5, c4 = idx & 31;
        int m = m0 + r;
        int t = m >> 6, b = m & 63;
        int tsrc = t;
        if (dir) { int len = lengths[b]; tsrc = (t < len) ? (len - 1 - t) : t; }
        int node = seq[b * TT + tsrc];
        float4 v = *(const float4*)&z2[(size_t)node * EMB + c4 * 4];
        *(float4*)&xs[r][(c4 ^ ((r >> 3) & 3)) * 4] = v;
    }
    __syncthreads();
    int mt = tid >> 4, ot = tid & 15;
    int mswz = mt & 3, oswz = ot & 7;
    float acc[8][8];
#pragma unroll
    for (int mi = 0; mi < 8; ++mi)
#pragma unroll
        for (int oi = 0; oi < 8; ++oi) acc[mi][oi] = 0.0f;
    for (int k4 = 0; k4 < 32; ++k4) {
        int xk = (k4 ^ mswz) * 4;
        int wk = (k4 ^ oswz) * 4;
        float4 xv[8], wv[8];
#pragma unroll
        for (int mi = 0; mi < 8; ++mi) xv[mi] = *(const float4*)&xs[mt * 8 + mi][xk];
#pragma unroll
        for (int oi = 0; oi < 8; ++oi) wv[oi] = *(const float4*)&ws[ot * 8 + oi][wk];
#pragma unroll
        for (int mi = 0; mi < 8; ++mi)
#pragma unroll
            for (int oi = 0; oi < 8; ++oi)
                acc[mi][oi] += xv[mi].x * wv[oi].x + xv[mi].y * wv[oi].y
                             + xv[mi].z * wv[oi].z + xv[mi].w * wv[oi].w;
    }
    float* xp = dir ? xpb : xpf;
#pragma unroll
    for (int mi = 0; mi < 8; ++mi) {
        int m = m0 + mt * 8 + mi;
        int ob = ot * 8;
        float4 oa = make_float4(acc[mi][0] + bsh[ob + 0], acc[mi][1] + bsh[ob + 1],
                                acc[mi][2] + bsh[ob + 2], acc[mi][3] + bsh[ob + 3]);
        float4 obv = make_float4(acc[mi][4] + bsh[ob + 4], acc[mi][5] + bsh[ob + 5],
                                 acc[mi][6] + bsh[ob + 6], acc[mi][7] + bsh[ob + 7]);
        *(float4*)&xp[(size_t)m * G4 + o0 + ob] = oa;
        *(float4*)&xp[(size_t)m * G4 + o0 + ob + 4] = obv;
    }
}

// ---------------- LSTM recurrence v6 (structure Z + drain-free barriers) ----------------
// R8 insight: __syncthreads drains vmcnt(0); phase B issued the 4 xp L2-loads
// and the ho store right before barrier #2 -> every step paid a full L2
// round-trip (~600cyc) in the drain. v6 moves BOTH to the loop TOP (h store
// deferred one step via register), so they complete during the ~900cyc phase-A
// region and barrier #1's drain is free. Phase B is now global-op-free.
__global__ __launch_bounds__(1024, 4) void lstm_kernel(const float* __restrict__ xpf,
                                                       const float* __restrict__ xpb,
                                                       const float* __restrict__ w_hh_f,
                                                       const float* __restrict__ w_hh_b,
                                                       const int* __restrict__ lengths,
                                                       float* __restrict__ hfo,
                                                       float* __restrict__ hbo) {
    int chain = blockIdx.x;
    int dir = chain & 1, b = chain >> 1;
    const float* w_hh = dir ? w_hh_b : w_hh_f;
    const float* xp = dir ? xpb : xpf;
    float* ho = dir ? hbo : hfo;
    int tid = threadIdx.x;
    int u = tid & 127;
    int kq = tid >> 7;    // 0..7
    int len = lengths[b];

    float4 W[4][4];
#pragma unroll
    for (int g = 0; g < 4; ++g)
#pragma unroll
        for (int j4 = 0; j4 < 4; ++j4)
            W[g][j4] = *(const float4*)&w_hh[(size_t)(g * HH + u) * HH + kq * 16 + j4 * 4];

    __shared__ __align__(16) float hl[HH];
    __shared__ __align__(16) float part[HH][9][4];   // [u][kq(pad 9)][gate]
    if (tid < HH) hl[tid] = 0.0f;
    __syncthreads();

    float cst = 0.0f, hkeep = 0.0f;
    int tprev = -1;
    float x0 = 0.f, x1 = 0.f, x2 = 0.f, x3 = 0.f;
    const float* xpt = xp + (size_t)b * G4 + u;
    if (tid < HH && len > 0) {
        x0 = xpt[0]; x1 = xpt[HH]; x2 = xpt[2 * HH]; x3 = xpt[3 * HH];
    }
    for (int t = 0; t < len; ++t) {
        float n0 = 0.f, n1 = 0.f, n2 = 0.f, n3 = 0.f;
        if (tid < HH) {
            if (tprev >= 0) ho[((size_t)b * TT + tprev) * HH + u] = hkeep;  // store h(t-1)
            if (t + 1 < len) {                                             // prefetch x(t+1)
                const float* xn = xpt + (size_t)(t + 1) * (BB * G4);
                n0 = xn[0]; n1 = xn[HH]; n2 = xn[2 * HH]; n3 = xn[3 * HH];
            }
        }
        // phase A: all 16 waves; wave-uniform h broadcast reads
        const float4* h4 = (const float4*)&hl[kq * 16];
        float a0 = 0.f, a1 = 0.f, a2 = 0.f, a3 = 0.f;
#pragma unroll
        for (int j4 = 0; j4 < 4; ++j4) {
            float4 hv = h4[j4];
            a0 += W[0][j4].x * hv.x + W[0][j4].y * hv.y + W[0][j4].z * hv.z + W[0][j4].w * hv.w;
            a1 += W[1][j4].x * hv.x + W[1][j4].y * hv.y + W[1][j4].z * hv.z + W[1][j4].w * hv.w;
            a2 += W[2][j4].x * hv.x + W[2][j4].y * hv.y + W[2][j4].z * hv.z + W[2][j4].w * hv.w;
            a3 += W[3][j4].x * hv.x + W[3][j4].y * hv.y + W[3][j4].z * hv.z + W[3][j4].w * hv.w;
        }
        if (kq) *(float4*)&part[u][kq][0] = make_float4(a0, a1, a2, a3);
        __syncthreads();
        // phase B: 2 waves (kq=0 threads), no global ops
        if (tid < HH) {
            float s0 = x0 + a0, s1 = x1 + a1, s2 = x2 + a2, s3 = x3 + a3;
#pragma unroll
            for (int q = 1; q < 8; ++q) {
                float4 p = *(const float4*)&part[u][q][0];
                s0 += p.x; s1 += p.y; s2 += p.z; s3 += p.w;
            }
            float gi = sigf(s0), gf = sigf(s1), gg = tanhf_(s2), go = sigf(s3);
            cst = gf * cst + gi * gg;
            float h = go * tanhf_(cst);
            hl[u] = h;
            hkeep = h;
            tprev = dir ? (len - 1 - t) : t;
            x0 = n0; x1 = n1; x2 = n2; x3 = n3;
        }
        __syncthreads();
    }
    if (tid < HH && tprev >= 0) ho[((size_t)b * TT + tprev) * HH + u] = hkeep;
}

// ---------------- masked attention pooling ----------------
__global__ __launch_bounds__(256) void attn_kernel(const float* __restrict__ hf,
                                                   const float* __restrict__ hb,
                                                   const float* __restrict__ attn_w,
                                                   const float* __restrict__ attn_b,
                                                   const int* __restrict__ lengths,
                                                   float* __restrict__ ctx) {
    int b = blockIdx.x;
    int tid = threadIdx.x;
    int len = lengths[b];
    __shared__ __align__(16) float wl[256];
    __shared__ float pl[256];
    __shared__ float red[256];
    wl[tid] = attn_w[tid];
    __syncthreads();
    float sc = -3.0e38f;
    if (tid < len) {
        const float4* rf = (const float4*)(hf + ((size_t)b * TT + tid) * HH);
        const float4* rb = (const float4*)(hb + ((size_t)b * TT + tid) * HH);
        const float4* w4 = (const float4*)wl;
        float s = attn_b[0];
        for (int k4 = 0; k4 < 32; ++k4) {
            float4 a = rf[k4], ww = w4[k4];
            s += a.x * ww.x + a.y * ww.y + a.z * ww.z + a.w * ww.w;
        }
        for (int k4 = 0; k4 < 32; ++k4) {
            float4 a = rb[k4], ww = w4[32 + k4];
            s += a.x * ww.x + a.y * ww.y + a.z * ww.z + a.w * ww.w;
        }
        sc = s;
    }
    red[tid] = sc;
    __syncthreads();
    for (int off = 128; off > 0; off >>= 1) {
        if (tid < off) red[tid] = fmaxf(red[tid], red[tid + off]);
        __syncthreads();
    }
    float mx = red[0];
    __syncthreads();
    float e = (tid < len) ? __expf(sc - mx) : 0.0f;
    red[tid] = e;
    __syncthreads();
    for (int off = 128; off > 0; off >>= 1) {
        if (tid < off) red[tid] += red[tid + off];
        __syncthreads();
    }
    float inv = 1.0f / red[0];
    pl[tid] = e * inv;
    __syncthreads();
    float acc = 0.0f;
    const float* basep = (tid < HH) ? (hf + (size_t)b * TT * HH + tid)
                                    : (hb + (size_t)b * TT * HH + (tid - HH));
#pragma unroll 4
    for (int t = 0; t < len; ++t) acc += pl[t] * basep[(size_t)t * HH];
    ctx[(size_t)b * 256 + tid] = acc;
}

// ---------------- final FC v3: ctx via scalar (s_load) path, no LDS ----------------
// fc was LDS-issue-bound (16 broadcast b128/k4/wave). ctx reads are
// wave-uniform -> readfirstlane makes the address provably uniform so the
// compiler emits s_load on the idle scalar pipe. LDS staging + barrier gone.
__global__ __launch_bounds__(256) void fc_kernel(const float* __restrict__ ctx,
                                                 const float* __restrict__ fc_w,
                                                 const float* __restrict__ fc_b,
                                                 float* __restrict__ out) {
    int lane = threadIdx.x & 63;
    int bq = __builtin_amdgcn_readfirstlane(threadIdx.x >> 6);
    const float* cb = ctx + (size_t)bq * 16 * 256;
    int nb = blockIdx.x * 256 + lane;
    float acc[16][4];
#pragma unroll
    for (int i = 0; i < 16; ++i)
#pragma unroll
        for (int c = 0; c < 4; ++c) acc[i][c] = 0.0f;
    for (int k4 = 0; k4 < 64; ++k4) {
        int k = k4 * 4;
        float w[4][4];
#pragma unroll
        for (int j = 0; j < 4; ++j)
#pragma unroll
            for (int c = 0; c < 4; ++c) {
                int n = nb + c * 64;
                w[j][c] = (n < NN) ? fc_w[(size_t)(k + j) * NN + n] : 0.0f;
            }
#pragma unroll
        for (int i = 0; i < 16; ++i) {
            float4 cv = *(const float4*)&cb[i * 256 + k];   // uniform -> s_load_dwordx4
#pragma unroll
            for (int c = 0; c < 4; ++c)
                acc[i][c] += cv.x * w[0][c] + cv.y * w[1][c] + cv.z * w[2][c] + cv.w * w[3][c];
        }
    }
#pragma unroll
    for (int i = 0; i < 16; ++i)
#pragma unroll
        for (int c = 0; c < 4; ++c) {
            int n = nb + c * 64;
            if (n < NN) out[(size_t)(bq * 16 + i) * NN + n] = acc[i][c] + fc_b[n];
        }
}

// ---------------- host launcher ----------------
extern "C" void kernel_launch(void* const* d_in, const int* in_sizes, int n_in,
                              void* d_out, int out_size, void* d_ws, size_t ws_size,
                              hipStream_t stream) {
    const float* x_coords   = (const float*)d_in[0];
    const float* temporal   = (const float*)d_in[1];
    const int*   edge_index = (const int*)d_in[2];
    const float* edge_w     = (const float*)d_in[3];
    const int*   seq        = (const int*)d_in[4];
    const int*   lengths    = (const int*)d_in[5];
    const float* node_emb   = (const float*)d_in[6];
    const float* gcn1_w     = (const float*)d_in[7];
    const float* gcn1_b     = (const float*)d_in[8];
    const float* gcn2_w     = (const float*)d_in[9];
    const float* gcn2_b     = (const float*)d_in[10];
    const float* w_ih_f     = (const float*)d_in[11];
    const float* w_hh_f     = (const float*)d_in[12];
    const float* b_ih_f     = (const float*)d_in[13];
    const float* b_hh_f     = (const float*)d_in[14];
    const float* w_ih_b     = (const float*)d_in[15];
    const float* w_hh_b     = (const float*)d_in[16];
    const float* b_ih_b     = (const float*)d_in[17];
    const float* b_hh_b     = (const float*)d_in[18];
    const float* attn_w     = (const float*)d_in[19];
    const float* attn_b     = (const float*)d_in[20];
    const float* fc_w       = (const float*)d_in[21];
    const float* fc_b       = (const float*)d_in[22];
    float* out = (float*)d_out;

    char* base = (char*)d_ws;
    size_t off = 0;
    auto alloc = [&](size_t nbytes) -> void* {
        void* p = base + off;
        off = (off + nbytes + 255) & ~(size_t)255;
        return p;
    };
    int*   cnt     = (int*)alloc((size_t)2 * NN * 4);  // cnt + degw contiguous (one memset)
    float* degw    = (float*)(cnt + NN);
    float* dinv    = (float*)alloc((size_t)NN * 4);
    int*   rs      = (int*)alloc(((size_t)NN + 1) * 4);
    int*   cursor  = (int*)alloc((size_t)NN * 4);
    int*   partials= (int*)alloc(64 * 4);
    int2*  ssrcw   = (int2*)alloc((size_t)NE * 8);
    float* h1      = (float*)alloc((size_t)NN * GH * 4);
    float* z1      = (float*)alloc((size_t)NN * GH * 4);
    float* a2      = h1;  // h1 dead after agg1
    float* w1t     = (float*)alloc((size_t)64 * 136 * 4);
    float* w2t     = (float*)alloc((size_t)GH * EMB * 4);
    float* z2      = (float*)alloc((size_t)NN * EMB * 4);
    float* xpf     = (float*)alloc((size_t)TT * BB * G4 * 4);
    float* xpb     = (float*)alloc((size_t)TT * BB * G4 * 4);
    float* hfo     = (float*)alloc((size_t)BB * TT * HH * 4);
    float* hbo     = (float*)alloc((size_t)BB * TT * HH * 4);
    float* ctx     = (float*)alloc((size_t)BB * 256 * 4);
    (void)ws_size; (void)in_sizes; (void)n_in; (void)out_size;

    hipMemsetAsync(cnt, 0, (size_t)2 * NN * 4, stream);

    hist_kernel<<<(NE + 255) / 256, 256, 0, stream>>>(edge_index, edge_w, cnt, degw);
    const int nblk = (NN + 1023) / 1024;  // 49
    scan1_kernel<<<nblk, 1024, 0, stream>>>(cnt, degw, dinv, rs, partials);
    misc_kernel<<<67, 256, 0, stream>>>(partials, nblk, gcn1_w, w1t, gcn2_w, w2t);
    scan3_kernel<<<nblk, 1024, 0, stream>>>(partials, rs, cursor);
    fill_kernel<<<(NE + 255) / 256, 256, 0, stream>>>(edge_index, edge_w, dinv, cursor, ssrcw);

    gemm1_kernel<<<(NN + 127) / 128, 256, 0, stream>>>(x_coords, temporal, node_emb, w1t, h1);
    agg_kernel<<<(NN + 3) / 4, 256, 0, stream>>>(h1, rs, ssrcw, dinv, gcn1_b, 1, z1);
    agg_kernel<<<(NN + 3) / 4, 256, 0, stream>>>(z1, rs, ssrcw, dinv, (const float*)nullptr, 0, a2);
    gemm2_kernel<<<dim3((NN + 127) / 128, 2), 256, 0, stream>>>(a2, w2t, gcn2_b, z2);

    pregemm_kernel<<<dim3(TT * BB / PM, G4 / PO, 2), 256, 0, stream>>>(
        z2, seq, w_ih_f, w_ih_b, b_ih_f, b_hh_f, b_ih_b, b_hh_b, lengths, xpf, xpb);
    lstm_kernel<<<BB * 2, 1024, 0, stream>>>(xpf, xpb, w_hh_f, w_hh_b, lengths, hfo, hbo);
    attn_kernel<<<BB, 256, 0, stream>>>(hfo, hbo, attn_w, attn_b, lengths, ctx);
    fc_kernel<<<(NN + 255) / 256, 256, 0, stream>>>(ctx, fc_w, fc_b, out);
}

// Round 10
// 662.799 us; speedup vs baseline: 1.0577x; 1.0057x over previous
//
#include <hip/hip_runtime.h>
#include <math.h>

#define NN 50000
#define NE 800000
#define EMB 128
#define GH 64
#define BB 64
#define TT 200
#define HH 128
#define G4 512
#define IND 134
#define PM 128
#define PO 128

__device__ __forceinline__ float sigf(float x) { return 1.0f / (1.0f + __expf(-x)); }
__device__ __forceinline__ float tanhf_(float x) { return 1.0f - 2.0f / (__expf(2.0f * x) + 1.0f); }

// ---------------- CSR build ----------------
__global__ void hist_kernel(const int* __restrict__ ei, const float* __restrict__ ew,
                            int* __restrict__ cnt, float* __restrict__ degw) {
    int e = blockIdx.x * 256 + threadIdx.x;
    if (e >= NE) return;
    int d = ei[NE + e];
    atomicAdd(&cnt[d], 1);
    atomicAdd(&degw[d], ew[e]);
}

// scan1 + dinv fused (both depend only on hist)
__global__ __launch_bounds__(1024) void scan1_kernel(const int* __restrict__ cnt,
                                                     const float* __restrict__ degw,
                                                     float* __restrict__ dinv,
                                                     int* __restrict__ rs, int* __restrict__ partials) {
    __shared__ int s[1024];
    int gid = blockIdx.x * 1024 + threadIdx.x;
    int v = (gid < NN) ? cnt[gid] : 0;
    if (gid < NN) dinv[gid] = rsqrtf(degw[gid] + 1.0f);   // +1 self loop
    s[threadIdx.x] = v;
    __syncthreads();
    for (int off = 1; off < 1024; off <<= 1) {
        int add = (threadIdx.x >= (unsigned)off) ? s[threadIdx.x - off] : 0;
        __syncthreads();
        s[threadIdx.x] += add;
        __syncthreads();
    }
    if (gid < NN) rs[gid] = s[threadIdx.x] - v;  // exclusive
    if (threadIdx.x == 1023) partials[blockIdx.x] = s[1023];
}

// misc: block 0 = parallel scan of partials; blocks 1..34 = W1 transpose+reorder;
// blocks 35..66 = W2 transpose.
__global__ void misc_kernel(int* __restrict__ partials, int nblk,
                            const float* __restrict__ W1, float* __restrict__ w1t,
                            const float* __restrict__ W2, float* __restrict__ w2t) {
    int blk = blockIdx.x;
    int tid = threadIdx.x;
    if (blk == 0) {
        __shared__ int s[64];
        int v = (tid < nblk) ? partials[tid] : 0;
        s[tid] = v;
        __syncthreads();
        for (int off = 1; off < 64; off <<= 1) {
            int add = (tid >= off) ? s[tid - off] : 0;
            __syncthreads();
            s[tid] += add;
            __syncthreads();
        }
        if (tid < nblk) partials[tid] = s[tid] - v;  // exclusive
    } else if (blk <= 34) {
        int i = (blk - 1) * 256 + tid;
        if (i < 64 * 136) {
            int o = i / 136, j = i - o * 136;
            float v = 0.0f;
            if (j < 128) v = W1[(size_t)(j + 2) * GH + o];
            else if (j < 130) v = W1[(size_t)(j - 128) * GH + o];
            else if (j < 134) v = W1[(size_t)j * GH + o];
            w1t[i] = v;
        }
    } else {
        int i = (blk - 35) * 256 + tid;
        if (i < GH * EMB) {
            int o = i >> 6, k = i & 63;
            w2t[i] = W2[(size_t)k * EMB + o];
        }
    }
}

__global__ __launch_bounds__(1024) void scan3_kernel(const int* __restrict__ partials,
                                                     int* __restrict__ rs, int* __restrict__ cursor) {
    int gid = blockIdx.x * 1024 + threadIdx.x;
    if (gid < NN) {
        int v = rs[gid] + partials[gid >> 10];
        rs[gid] = v;
        cursor[gid] = v;
    }
    if (gid == 0) rs[NN] = NE;
}

// fill: (src, weight) packed into int2 -> ONE random 8B scatter instead of two 4B
__global__ void fill_kernel(const int* __restrict__ ei, const float* __restrict__ ew,
                            const float* __restrict__ dinv, int* __restrict__ cursor,
                            int2* __restrict__ ssrcw) {
    int e = blockIdx.x * 256 + threadIdx.x;
    if (e >= NE) return;
    int s = ei[e], d = ei[NE + e];
    int pos = atomicAdd(&cursor[d], 1);
    ssrcw[pos] = make_int2(s, __float_as_int(ew[e] * dinv[s] * dinv[d]));
}

// ---------------- GCN layer 1 GEMM v2 (134 -> 64), register-tiled ----------------
__global__ __launch_bounds__(256) void gemm1_kernel(const float* __restrict__ coords,
                                                    const float* __restrict__ temporal,
                                                    const float* __restrict__ emb,
                                                    const float* __restrict__ w1t,
                                                    float* __restrict__ h1) {
    __shared__ __align__(16) float xs[128][136];
    __shared__ __align__(16) float wt[64][136];
    int tid = threadIdx.x;
    int m0 = blockIdx.x * 128;
    for (int i = tid; i < 64 * 34; i += 256) {           // stage W^T (swizzled words 0..31)
        int rr = i / 34, w = i - rr * 34;
        float4 v = *(const float4*)&w1t[(size_t)rr * 136 + w * 4];
        int ws = (w < 32) ? (w ^ ((rr >> 3) & 7)) : w;
        *(float4*)&wt[rr][ws * 4] = v;
    }
    for (int i = tid; i < 128 * 32; i += 256) {          // stage emb words 0..31 (swizzled)
        int r = i >> 5, c4 = i & 31;
        int m = m0 + r;
        float4 v = make_float4(0.f, 0.f, 0.f, 0.f);
        if (m < NN) v = *(const float4*)&emb[(size_t)m * EMB + c4 * 4];
        *(float4*)&xs[r][(c4 ^ ((r >> 2) & 7)) * 4] = v;
    }
    for (int i = tid; i < 128 * 8; i += 256) {           // words 32..33: coords+temporal+pad
        int r = i >> 3, c = i & 7;
        int m = m0 + r;
        float v = 0.0f;
        if (m < NN) {
            if (c < 2) v = coords[2 * m + c];
            else if (c < 6) v = temporal[4 * m + (c - 2)];
        }
        xs[r][128 + c] = v;
    }
    __syncthreads();
    int mt = tid >> 3, ot = tid & 7;
    int xswz = mt & 7, wswz = ot & 7;
    float acc[4][8];
#pragma unroll
    for (int mi = 0; mi < 4; ++mi)
#pragma unroll
        for (int oi = 0; oi < 8; ++oi) acc[mi][oi] = 0.0f;
    for (int k4 = 0; k4 < 34; ++k4) {
        int xk = (k4 < 32) ? (k4 ^ xswz) : k4;
        int wk = (k4 < 32) ? (k4 ^ wswz) : k4;
        float4 xv[4], wv[8];
#pragma unroll
        for (int mi = 0; mi < 4; ++mi) xv[mi] = *(const float4*)&xs[mt * 4 + mi][xk * 4];
#pragma unroll
        for (int oi = 0; oi < 8; ++oi) wv[oi] = *(const float4*)&wt[ot * 8 + oi][wk * 4];
#pragma unroll
        for (int mi = 0; mi < 4; ++mi)
#pragma unroll
            for (int oi = 0; oi < 8; ++oi)
                acc[mi][oi] += xv[mi].x * wv[oi].x + xv[mi].y * wv[oi].y
                             + xv[mi].z * wv[oi].z + xv[mi].w * wv[oi].w;
    }
#pragma unroll
    for (int mi = 0; mi < 4; ++mi) {
        int m = m0 + mt * 4 + mi;
        if (m >= NN) continue;
        int ob = ot * 8;
        *(float4*)&h1[(size_t)m * GH + ob] = make_float4(acc[mi][0], acc[mi][1], acc[mi][2], acc[mi][3]);
        *(float4*)&h1[(size_t)m * GH + ob + 4] = make_float4(acc[mi][4], acc[mi][5], acc[mi][6], acc[mi][7]);
    }
}

// ---------------- symmetric-norm aggregation (64 features, CSR, int2 edges) ----------------
__global__ __launch_bounds__(256) void agg_kernel(const float* __restrict__ hin,
                                                  const int* __restrict__ rs,
                                                  const int2* __restrict__ ssrcw,
                                                  const float* __restrict__ dinv,
                                                  const float* __restrict__ bias, int relu,
                                                  float* __restrict__ hout) {
    int lane = threadIdx.x & 63;
    int wid = threadIdx.x >> 6;
    int n = blockIdx.x * 4 + wid;
    if (n >= NN) return;
    float dv = dinv[n];
    float acc = hin[(size_t)n * GH + lane] * (dv * dv);  // self loop
    int i = rs[n], e1 = rs[n + 1];
    for (; i + 3 < e1; i += 4) {
        int4 p0 = *(const int4*)&ssrcw[i];
        int4 p1 = *(const int4*)&ssrcw[i + 2];
        float a0 = hin[(size_t)p0.x * GH + lane];
        float a1 = hin[(size_t)p0.z * GH + lane];
        float a2 = hin[(size_t)p1.x * GH + lane];
        float a3 = hin[(size_t)p1.z * GH + lane];
        acc += a0 * __int_as_float(p0.y) + a1 * __int_as_float(p0.w)
             + a2 * __int_as_float(p1.y) + a3 * __int_as_float(p1.w);
    }
    for (; i < e1; ++i) {
        int2 p = ssrcw[i];
        acc += hin[(size_t)p.x * GH + lane] * __int_as_float(p.y);
    }
    if (bias) acc += bias[lane];
    if (relu) acc = fmaxf(acc, 0.0f);
    hout[(size_t)n * GH + lane] = acc;
}

// ---------------- GCN layer 2 GEMM v2 (64 -> 128), register-tiled ----------------
__global__ __launch_bounds__(256) void gemm2_kernel(const float* __restrict__ a2,
                                                    const float* __restrict__ w2t,
                                                    const float* __restrict__ b2,
                                                    float* __restrict__ z2) {
    int m0 = blockIdx.x * 128, o0 = blockIdx.y * 64;
    __shared__ __align__(16) float xs[128][64];
    __shared__ __align__(16) float wt[64][64];
    __shared__ float bsh[64];
    int tid = threadIdx.x;
#pragma unroll
    for (int i = 0; i < 8; ++i) {            // stage a2 rows (swizzled)
        int idx = i * 256 + tid;
        int r = idx >> 4, c4 = idx & 15;
        int m = m0 + r;
        float4 v = (m < NN) ? *(const float4*)&a2[(size_t)m * GH + c4 * 4]
                            : make_float4(0.f, 0.f, 0.f, 0.f);
        *(float4*)&xs[r][(c4 ^ ((r >> 2) & 3)) * 4] = v;
    }
#pragma unroll
    for (int i = 0; i < 4; ++i) {            // stage w2t rows (swizzled)
        int idx = i * 256 + tid;
        int r = idx >> 4, c4 = idx & 15;
        float4 v = *(const float4*)&w2t[(size_t)(o0 + r) * GH + c4 * 4];
        *(float4*)&wt[r][(c4 ^ ((r >> 3) & 7)) * 4] = v;
    }
    if (tid < 64) bsh[tid] = b2[o0 + tid];
    __syncthreads();
    int mt = tid >> 3, ot = tid & 7;
    float acc[4][8];
#pragma unroll
    for (int mi = 0; mi < 4; ++mi)
#pragma unroll
        for (int oi = 0; oi < 8; ++oi) acc[mi][oi] = 0.0f;
    for (int k4 = 0; k4 < 16; ++k4) {
        int xc = (k4 ^ (mt & 3)) * 4;
        int wc = (k4 ^ (ot & 7)) * 4;
        float4 xv[4], wv[8];
#pragma unroll
        for (int mi = 0; mi < 4; ++mi) xv[mi] = *(const float4*)&xs[mt * 4 + mi][xc];
#pragma unroll
        for (int oi = 0; oi < 8; ++oi) wv[oi] = *(const float4*)&wt[ot * 8 + oi][wc];
#pragma unroll
        for (int mi = 0; mi < 4; ++mi)
#pragma unroll
            for (int oi = 0; oi < 8; ++oi)
                acc[mi][oi] += xv[mi].x * wv[oi].x + xv[mi].y * wv[oi].y
                             + xv[mi].z * wv[oi].z + xv[mi].w * wv[oi].w;
    }
#pragma unroll
    for (int mi = 0; mi < 4; ++mi) {
        int m = m0 + mt * 4 + mi;
        if (m >= NN) continue;
        int ob = ot * 8;
        float4 oa = make_float4(acc[mi][0] + bsh[ob + 0], acc[mi][1] + bsh[ob + 1],
                                acc[mi][2] + bsh[ob + 2], acc[mi][3] + bsh[ob + 3]);
        float4 obv = make_float4(acc[mi][4] + bsh[ob + 4], acc[mi][5] + bsh[ob + 5],
                                 acc[mi][6] + bsh[ob + 6], acc[mi][7] + bsh[ob + 7]);
        *(float4*)&z2[(size_t)m * EMB + o0 + ob] = oa;
        *(float4*)&z2[(size_t)m * EMB + o0 + ob + 4] = obv;
    }
}

// ---------------- pre-GEMM v4: gather fused into staging ----------------
__global__ __launch_bounds__(256) void pregemm_kernel(const float* __restrict__ z2,
                                                      const int* __restrict__ seq,
                                                      const float* __restrict__ w_ih_f,
                                                      const float* __restrict__ w_ih_b,
                                                      const float* __restrict__ b_ih_f,
                                                      const float* __restrict__ b_hh_f,
                                                      const float* __restrict__ b_ih_b,
                                                      const float* __restrict__ b_hh_b,
                                                      const int* __restrict__ lengths,
                                                      float* __restrict__ xpf,
                                                      float* __restrict__ xpb) {
    int dir = blockIdx.z;
    const float* w_ih = dir ? w_ih_b : w_ih_f;
    int o0 = blockIdx.y * PO;
    int m0 = blockIdx.x * PM;
    __shared__ __align__(16) float xs[PM][EMB];
    __shared__ __align__(16) float ws[PO][EMB];
    __shared__ float bsh[PO];
    int tid = threadIdx.x;
#pragma unroll
    for (int i = 0; i < 16; ++i) {          // stage W (swizzled)
        int idx = i * 256 + tid;
        int row = idx >> 5, c4 = idx & 31;
        float4 v = *(const float4*)&w_ih[(size_t)(o0 + row) * EMB + c4 * 4];
        *(float4*)&ws[row][(c4 ^ ((row >> 3) & 7)) * 4] = v;
    }
    if (tid < PO) bsh[tid] = dir ? (b_ih_b[o0 + tid] + b_hh_b[o0 + tid])
                                 : (b_ih_f[o0 + tid] + b_hh_f[o0 + tid]);
#pragma unroll
    for (int i = 0; i < 16; ++i) {          // stage x via fused gather (swizzled)
        int idx = i * 256 + tid;
        int r = idx >> 5, c4 = idx & 31;
        int m = m0 + r;
        int t = m >> 6, b = m & 63;
        int tsrc = t;
        if (dir) { int len = lengths[b]; tsrc = (t < len) ? (len - 1 - t) : t; }
        int node = seq[b * TT + tsrc];
        float4 v = *(const float4*)&z2[(size_t)node * EMB + c4 * 4];
        *(float4*)&xs[r][(c4 ^ ((r >> 3) & 3)) * 4] = v;
    }
    __syncthreads();
    int mt = tid >> 4, ot = tid & 15;
    int mswz = mt & 3, oswz = ot & 7;
    float acc[8][8];
#pragma unroll
    for (int mi = 0; mi < 8; ++mi)
#pragma unroll
        for (int oi = 0; oi < 8; ++oi) acc[mi][oi] = 0.0f;
    for (int k4 = 0; k4 < 32; ++k4) {
        int xk = (k4 ^ mswz) * 4;
        int wk = (k4 ^ oswz) * 4;
        float4 xv[8], wv[8];
#pragma unroll
        for (int mi = 0; mi < 8; ++mi) xv[mi] = *(const float4*)&xs[mt * 8 + mi][xk];
#pragma unroll
        for (int oi = 0; oi < 8; ++oi) wv[oi] = *(const float4*)&ws[ot * 8 + oi][wk];
#pragma unroll
        for (int mi = 0; mi < 8; ++mi)
#pragma unroll
            for (int oi = 0; oi < 8; ++oi)
                acc[mi][oi] += xv[mi].x * wv[oi].x + xv[mi].y * wv[oi].y
                             + xv[mi].z * wv[oi].z + xv[mi].w * wv[oi].w;
    }
    float* xp = dir ? xpb : xpf;
#pragma unroll
    for (int mi = 0; mi < 8; ++mi) {
        int m = m0 + mt * 8 + mi;
        int ob = ot * 8;
        float4 oa = make_float4(acc[mi][0] + bsh[ob + 0], acc[mi][1] + bsh[ob + 1],
                                acc[mi][2] + bsh[ob + 2], acc[mi][3] + bsh[ob + 3]);
        float4 obv = make_float4(acc[mi][4] + bsh[ob + 4], acc[mi][5] + bsh[ob + 5],
                                 acc[mi][6] + bsh[ob + 6], acc[mi][7] + bsh[ob + 7]);
        *(float4*)&xp[(size_t)m * G4 + o0 + ob] = oa;
        *(float4*)&xp[(size_t)m * G4 + o0 + ob + 4] = obv;
    }
}

// ---------------- LSTM recurrence v7 (structure Z + conflict-free part layout) ----------------
// R9 audit: part[u][kq(9)][4] has 36-float row stride -> lanes u and u+8 hit
// the same bank (36*8 = 288 = 0 mod 32): the 14 part-writes AND the phase-B
// serial-path reads were ~8-way conflicted (~500 cyc/step unexplained).
// v7: part[kq][u][4] -> per-wave writes are 64x16B contiguous, phase-B reads
// contiguous per lane. Zero conflicts by construction.
__global__ __launch_bounds__(1024, 4) void lstm_kernel(const float* __restrict__ xpf,
                                                       const float* __restrict__ xpb,
                                                       const float* __restrict__ w_hh_f,
                                                       const float* __restrict__ w_hh_b,
                                                       const int* __restrict__ lengths,
                                                       float* __restrict__ hfo,
                                                       float* __restrict__ hbo) {
    int chain = blockIdx.x;
    int dir = chain & 1, b = chain >> 1;
    const float* w_hh = dir ? w_hh_b : w_hh_f;
    const float* xp = dir ? xpb : xpf;
    float* ho = dir ? hbo : hfo;
    int tid = threadIdx.x;
    int u = tid & 127;
    int kq = tid >> 7;    // 0..7
    int len = lengths[b];

    float4 W[4][4];
#pragma unroll
    for (int g = 0; g < 4; ++g)
#pragma unroll
        for (int j4 = 0; j4 < 4; ++j4)
            W[g][j4] = *(const float4*)&w_hh[(size_t)(g * HH + u) * HH + kq * 16 + j4 * 4];

    __shared__ __align__(16) float hl[HH];
    __shared__ __align__(16) float part[8][HH][4];   // [kq][u][gate] - conflict-free
    if (tid < HH) hl[tid] = 0.0f;
    __syncthreads();

    float cst = 0.0f, hkeep = 0.0f;
    int tprev = -1;
    float x0 = 0.f, x1 = 0.f, x2 = 0.f, x3 = 0.f;
    const float* xpt = xp + (size_t)b * G4 + u;
    if (tid < HH && len > 0) {
        x0 = xpt[0]; x1 = xpt[HH]; x2 = xpt[2 * HH]; x3 = xpt[3 * HH];
    }
    for (int t = 0; t < len; ++t) {
        float n0 = 0.f, n1 = 0.f, n2 = 0.f, n3 = 0.f;
        if (tid < HH) {
            if (tprev >= 0) ho[((size_t)b * TT + tprev) * HH + u] = hkeep;  // store h(t-1)
            if (t + 1 < len) {                                             // prefetch x(t+1)
                const float* xn = xpt + (size_t)(t + 1) * (BB * G4);
                n0 = xn[0]; n1 = xn[HH]; n2 = xn[2 * HH]; n3 = xn[3 * HH];
            }
        }
        // phase A: all 16 waves; wave-uniform h broadcast reads
        const float4* h4 = (const float4*)&hl[kq * 16];
        float a0 = 0.f, a1 = 0.f, a2 = 0.f, a3 = 0.f;
#pragma unroll
        for (int j4 = 0; j4 < 4; ++j4) {
            float4 hv = h4[j4];
            a0 += W[0][j4].x * hv.x + W[0][j4].y * hv.y + W[0][j4].z * hv.z + W[0][j4].w * hv.w;
            a1 += W[1][j4].x * hv.x + W[1][j4].y * hv.y + W[1][j4].z * hv.z + W[1][j4].w * hv.w;
            a2 += W[2][j4].x * hv.x + W[2][j4].y * hv.y + W[2][j4].z * hv.z + W[2][j4].w * hv.w;
            a3 += W[3][j4].x * hv.x + W[3][j4].y * hv.y + W[3][j4].z * hv.z + W[3][j4].w * hv.w;
        }
        if (kq) *(float4*)&part[kq][u][0] = make_float4(a0, a1, a2, a3);
        __syncthreads();
        // phase B: 2 waves (kq=0 threads), no global ops
        if (tid < HH) {
            float s0 = x0 + a0, s1 = x1 + a1, s2 = x2 + a2, s3 = x3 + a3;
#pragma unroll
            for (int q = 1; q < 8; ++q) {
                float4 p = *(const float4*)&part[q][u][0];
                s0 += p.x; s1 += p.y; s2 += p.z; s3 += p.w;
            }
            float gi = sigf(s0), gf = sigf(s1), gg = tanhf_(s2), go = sigf(s3);
            cst = gf * cst + gi * gg;
            float h = go * tanhf_(cst);
            hl[u] = h;
            hkeep = h;
            tprev = dir ? (len - 1 - t) : t;
            x0 = n0; x1 = n1; x2 = n2; x3 = n3;
        }
        __syncthreads();
    }
    if (tid < HH && tprev >= 0) ho[((size_t)b * TT + tprev) * HH + u] = hkeep;
}

// ---------------- masked attention pooling ----------------
__global__ __launch_bounds__(256) void attn_kernel(const float* __restrict__ hf,
                                                   const float* __restrict__ hb,
                                                   const float* __restrict__ attn_w,
                                                   const float* __restrict__ attn_b,
                                                   const int* __restrict__ lengths,
                                                   float* __restrict__ ctx) {
    int b = blockIdx.x;
    int tid = threadIdx.x;
    int len = lengths[b];
    __shared__ __align__(16) float wl[256];
    __shared__ float pl[256];
    __shared__ float red[256];
    wl[tid] = attn_w[tid];
    __syncthreads();
    float sc = -3.0e38f;
    if (tid < len) {
        const float4* rf = (const float4*)(hf + ((size_t)b * TT + tid) * HH);
        const float4* rb = (const float4*)(hb + ((size_t)b * TT + tid) * HH);
        const float4* w4 = (const float4*)wl;
        float s = attn_b[0];
        for (int k4 = 0; k4 < 32; ++k4) {
            float4 a = rf[k4], ww = w4[k4];
            s += a.x * ww.x + a.y * ww.y + a.z * ww.z + a.w * ww.w;
        }
        for (int k4 = 0; k4 < 32; ++k4) {
            float4 a = rb[k4], ww = w4[32 + k4];
            s += a.x * ww.x + a.y * ww.y + a.z * ww.z + a.w * ww.w;
        }
        sc = s;
    }
    red[tid] = sc;
    __syncthreads();
    for (int off = 128; off > 0; off >>= 1) {
        if (tid < off) red[tid] = fmaxf(red[tid], red[tid + off]);
        __syncthreads();
    }
    float mx = red[0];
    __syncthreads();
    float e = (tid < len) ? __expf(sc - mx) : 0.0f;
    red[tid] = e;
    __syncthreads();
    for (int off = 128; off > 0; off >>= 1) {
        if (tid < off) red[tid] += red[tid + off];
        __syncthreads();
    }
    float inv = 1.0f / red[0];
    pl[tid] = e * inv;
    __syncthreads();
    float acc = 0.0f;
    const float* basep = (tid < HH) ? (hf + (size_t)b * TT * HH + tid)
                                    : (hb + (size_t)b * TT * HH + (tid - HH));
#pragma unroll 4
    for (int t = 0; t < len; ++t) acc += pl[t] * basep[(size_t)t * HH];
    ctx[(size_t)b * 256 + tid] = acc;
}

// ---------------- final FC v2 (reverted from R8's scalar-path experiment) ----------------
// R8's readfirstlane/s_load variant is the prime suspect for the R6->R9 +25us
// total regression (if the compiler kept vector loads: 1024 redundant 16B
// global loads/thread). This LDS-staged register-tiled version is the
// known-good model: thread = 4 n-cols x 16 b-rows, fc_w read exactly once.
__global__ __launch_bounds__(256) void fc_kernel(const float* __restrict__ ctx,
                                                 const float* __restrict__ fc_w,
                                                 const float* __restrict__ fc_b,
                                                 float* __restrict__ out) {
    __shared__ __align__(16) float cl[64][256];
    for (int i = threadIdx.x; i < 64 * 256 / 4; i += 256)
        ((float4*)cl)[i] = ((const float4*)ctx)[i];
    __syncthreads();
    int lane = threadIdx.x & 63;
    int bq = threadIdx.x >> 6;
    int nb = blockIdx.x * 256 + lane;
    float acc[16][4];
#pragma unroll
    for (int i = 0; i < 16; ++i)
#pragma unroll
        for (int c = 0; c < 4; ++c) acc[i][c] = 0.0f;
    for (int k4 = 0; k4 < 64; ++k4) {
        int k = k4 * 4;
        float w[4][4];
#pragma unroll
        for (int j = 0; j < 4; ++j)
#pragma unroll
            for (int c = 0; c < 4; ++c) {
                int n = nb + c * 64;
                w[j][c] = (n < NN) ? fc_w[(size_t)(k + j) * NN + n] : 0.0f;
            }
#pragma unroll
        for (int i = 0; i < 16; ++i) {
            float4 cv = *(const float4*)&cl[bq * 16 + i][k];
#pragma unroll
            for (int c = 0; c < 4; ++c)
                acc[i][c] += cv.x * w[0][c] + cv.y * w[1][c] + cv.z * w[2][c] + cv.w * w[3][c];
        }
    }
#pragma unroll
    for (int i = 0; i < 16; ++i)
#pragma unroll
        for (int c = 0; c < 4; ++c) {
            int n = nb + c * 64;
            if (n < NN) out[(size_t)(bq * 16 + i) * NN + n] = acc[i][c] + fc_b[n];
        }
}

// ---------------- host launcher ----------------
extern "C" void kernel_launch(void* const* d_in, const int* in_sizes, int n_in,
                              void* d_out, int out_size, void* d_ws, size_t ws_size,
                              hipStream_t stream) {
    const float* x_coords   = (const float*)d_in[0];
    const float* temporal   = (const float*)d_in[1];
    const int*   edge_index = (const int*)d_in[2];
    const float* edge_w     = (const float*)d_in[3];
    const int*   seq        = (const int*)d_in[4];
    const int*   lengths    = (const int*)d_in[5];
    const float* node_emb   = (const float*)d_in[6];
    const float* gcn1_w     = (const float*)d_in[7];
    const float* gcn1_b     = (const float*)d_in[8];
    const float* gcn2_w     = (const float*)d_in[9];
    const float* gcn2_b     = (const float*)d_in[10];
    const float* w_ih_f     = (const float*)d_in[11];
    const float* w_hh_f     = (const float*)d_in[12];
    const float* b_ih_f     = (const float*)d_in[13];
    const float* b_hh_f     = (const float*)d_in[14];
    const float* w_ih_b     = (const float*)d_in[15];
    const float* w_hh_b     = (const float*)d_in[16];
    const float* b_ih_b     = (const float*)d_in[17];
    const float* b_hh_b     = (const float*)d_in[18];
    const float* attn_w     = (const float*)d_in[19];
    const float* attn_b     = (const float*)d_in[20];
    const float* fc_w       = (const float*)d_in[21];
    const float* fc_b       = (const float*)d_in[22];
    float* out = (float*)d_out;

    char* base = (char*)d_ws;
    size_t off = 0;
    auto alloc = [&](size_t nbytes) -> void* {
        void* p = base + off;
        off = (off + nbytes + 255) & ~(size_t)255;
        return p;
    };
    int*   cnt     = (int*)alloc((size_t)2 * NN * 4);  // cnt + degw contiguous (one memset)
    float* degw    = (float*)(cnt + NN);
    float* dinv    = (float*)alloc((size_t)NN * 4);
    int*   rs      = (int*)alloc(((size_t)NN + 1) * 4);
    int*   cursor  = (int*)alloc((size_t)NN * 4);
    int*   partials= (int*)alloc(64 * 4);
    int2*  ssrcw   = (int2*)alloc((size_t)NE * 8);
    float* h1      = (float*)alloc((size_t)NN * GH * 4);
    float* z1      = (float*)alloc((size_t)NN * GH * 4);
    float* a2      = h1;  // h1 dead after agg1
    float* w1t     = (float*)alloc((size_t)64 * 136 * 4);
    float* w2t     = (float*)alloc((size_t)GH * EMB * 4);
    float* z2      = (float*)alloc((size_t)NN * EMB * 4);
    float* xpf     = (float*)alloc((size_t)TT * BB * G4 * 4);
    float* xpb     = (float*)alloc((size_t)TT * BB * G4 * 4);
    float* hfo     = (float*)alloc((size_t)BB * TT * HH * 4);
    float* hbo     = (float*)alloc((size_t)BB * TT * HH * 4);
    float* ctx     = (float*)alloc((size_t)BB * 256 * 4);
    (void)ws_size; (void)in_sizes; (void)n_in; (void)out_size;

    hipMemsetAsync(cnt, 0, (size_t)2 * NN * 4, stream);

    hist_kernel<<<(NE + 255) / 256, 256, 0, stream>>>(edge_index, edge_w, cnt, degw);
    const int nblk = (NN + 1023) / 1024;  // 49
    scan1_kernel<<<nblk, 1024, 0, stream>>>(cnt, degw, dinv, rs, partials);
    misc_kernel<<<67, 256, 0, stream>>>(partials, nblk, gcn1_w, w1t, gcn2_w, w2t);
    scan3_kernel<<<nblk, 1024, 0, stream>>>(partials, rs, cursor);
    fill_kernel<<<(NE + 255) / 256, 256, 0, stream>>>(edge_index, edge_w, dinv, cursor, ssrcw);

    gemm1_kernel<<<(NN + 127) / 128, 256, 0, stream>>>(x_coords, temporal, node_emb, w1t, h1);
    agg_kernel<<<(NN + 3) / 4, 256, 0, stream>>>(h1, rs, ssrcw, dinv, gcn1_b, 1, z1);
    agg_kernel<<<(NN + 3) / 4, 256, 0, stream>>>(z1, rs, ssrcw, dinv, (const float*)nullptr, 0, a2);
    gemm2_kernel<<<dim3((NN + 127) / 128, 2), 256, 0, stream>>>(a2, w2t, gcn2_b, z2);

    pregemm_kernel<<<dim3(TT * BB / PM, G4 / PO, 2), 256, 0, stream>>>(
        z2, seq, w_ih_f, w_ih_b, b_ih_f, b_hh_f, b_ih_b, b_hh_b, lengths, xpf, xpb);
    lstm_kernel<<<BB * 2, 1024, 0, stream>>>(xpf, xpb, w_hh_f, w_hh_b, lengths, hfo, hbo);
    attn_kernel<<<BB, 256, 0, stream>>>(hfo, hbo, attn_w, attn_b, lengths, ctx);
    fc_kernel<<<(NN + 255) / 256, 256, 0, stream>>>(ctx, fc_w, fc_b, out);
}

// Round 11
// 660.954 us; speedup vs baseline: 1.0606x; 1.0028x over previous
//
#include <hip/hip_runtime.h>
#include <math.h>

#define NN 50000
#define NE 800000
#define EMB 128
#define GH 64
#define BB 64
#define TT 200
#define HH 128
#define G4 512
#define IND 134
#define PM 128
#define PO 128

__device__ __forceinline__ float sigf(float x) { return 1.0f / (1.0f + __expf(-x)); }
__device__ __forceinline__ float tanhf_(float x) { return 1.0f - 2.0f / (__expf(2.0f * x) + 1.0f); }
// barrier WITHOUT the vmcnt(0) drain that __syncthreads emits: LDS ordering
// is enforced explicitly (lgkmcnt), global loads/stores float across the
// barrier and are waited at their use point (guide T4: never vmcnt(0) at a
// barrier in a hot loop).
__device__ __forceinline__ void barrier_nodrain() {
    asm volatile("s_waitcnt lgkmcnt(0)" ::: "memory");
    __builtin_amdgcn_s_barrier();
}

// ---------------- CSR build ----------------
__global__ void hist_kernel(const int* __restrict__ ei, const float* __restrict__ ew,
                            int* __restrict__ cnt, float* __restrict__ degw) {
    int e = blockIdx.x * 256 + threadIdx.x;
    if (e >= NE) return;
    int d = ei[NE + e];
    atomicAdd(&cnt[d], 1);
    atomicAdd(&degw[d], ew[e]);
}

// scan1 + dinv fused (both depend only on hist)
__global__ __launch_bounds__(1024) void scan1_kernel(const int* __restrict__ cnt,
                                                     const float* __restrict__ degw,
                                                     float* __restrict__ dinv,
                                                     int* __restrict__ rs, int* __restrict__ partials) {
    __shared__ int s[1024];
    int gid = blockIdx.x * 1024 + threadIdx.x;
    int v = (gid < NN) ? cnt[gid] : 0;
    if (gid < NN) dinv[gid] = rsqrtf(degw[gid] + 1.0f);   // +1 self loop
    s[threadIdx.x] = v;
    __syncthreads();
    for (int off = 1; off < 1024; off <<= 1) {
        int add = (threadIdx.x >= (unsigned)off) ? s[threadIdx.x - off] : 0;
        __syncthreads();
        s[threadIdx.x] += add;
        __syncthreads();
    }
    if (gid < NN) rs[gid] = s[threadIdx.x] - v;  // exclusive
    if (threadIdx.x == 1023) partials[blockIdx.x] = s[1023];
}

// misc: block 0 = parallel scan of partials; blocks 1..34 = W1 transpose+reorder;
// blocks 35..66 = W2 transpose.
__global__ void misc_kernel(int* __restrict__ partials, int nblk,
                            const float* __restrict__ W1, float* __restrict__ w1t,
                            const float* __restrict__ W2, float* __restrict__ w2t) {
    int blk = blockIdx.x;
    int tid = threadIdx.x;
    if (blk == 0) {
        __shared__ int s[64];
        int v = (tid < nblk) ? partials[tid] : 0;
        s[tid] = v;
        __syncthreads();
        for (int off = 1; off < 64; off <<= 1) {
            int add = (tid >= off) ? s[tid - off] : 0;
            __syncthreads();
            s[tid] += add;
            __syncthreads();
        }
        if (tid < nblk) partials[tid] = s[tid] - v;  // exclusive
    } else if (blk <= 34) {
        int i = (blk - 1) * 256 + tid;
        if (i < 64 * 136) {
            int o = i / 136, j = i - o * 136;
            float v = 0.0f;
            if (j < 128) v = W1[(size_t)(j + 2) * GH + o];
            else if (j < 130) v = W1[(size_t)(j - 128) * GH + o];
            else if (j < 134) v = W1[(size_t)j * GH + o];
            w1t[i] = v;
        }
    } else {
        int i = (blk - 35) * 256 + tid;
        if (i < GH * EMB) {
            int o = i >> 6, k = i & 63;
            w2t[i] = W2[(size_t)k * EMB + o];
        }
    }
}

__global__ __launch_bounds__(1024) void scan3_kernel(const int* __restrict__ partials,
                                                     int* __restrict__ rs, int* __restrict__ cursor) {
    int gid = blockIdx.x * 1024 + threadIdx.x;
    if (gid < NN) {
        int v = rs[gid] + partials[gid >> 10];
        rs[gid] = v;
        cursor[gid] = v;
    }
    if (gid == 0) rs[NN] = NE;
}

// fill: (src, weight) packed into int2 -> ONE random 8B scatter instead of two 4B
__global__ void fill_kernel(const int* __restrict__ ei, const float* __restrict__ ew,
                            const float* __restrict__ dinv, int* __restrict__ cursor,
                            int2* __restrict__ ssrcw) {
    int e = blockIdx.x * 256 + threadIdx.x;
    if (e >= NE) return;
    int s = ei[e], d = ei[NE + e];
    int pos = atomicAdd(&cursor[d], 1);
    ssrcw[pos] = make_int2(s, __float_as_int(ew[e] * dinv[s] * dinv[d]));
}

// ---------------- GCN layer 1 GEMM v2 (134 -> 64), register-tiled ----------------
__global__ __launch_bounds__(256) void gemm1_kernel(const float* __restrict__ coords,
                                                    const float* __restrict__ temporal,
                                                    const float* __restrict__ emb,
                                                    const float* __restrict__ w1t,
                                                    float* __restrict__ h1) {
    __shared__ __align__(16) float xs[128][136];
    __shared__ __align__(16) float wt[64][136];
    int tid = threadIdx.x;
    int m0 = blockIdx.x * 128;
    for (int i = tid; i < 64 * 34; i += 256) {           // stage W^T (swizzled words 0..31)
        int rr = i / 34, w = i - rr * 34;
        float4 v = *(const float4*)&w1t[(size_t)rr * 136 + w * 4];
        int ws = (w < 32) ? (w ^ ((rr >> 3) & 7)) : w;
        *(float4*)&wt[rr][ws * 4] = v;
    }
    for (int i = tid; i < 128 * 32; i += 256) {          // stage emb words 0..31 (swizzled)
        int r = i >> 5, c4 = i & 31;
        int m = m0 + r;
        float4 v = make_float4(0.f, 0.f, 0.f, 0.f);
        if (m < NN) v = *(const float4*)&emb[(size_t)m * EMB + c4 * 4];
        *(float4*)&xs[r][(c4 ^ ((r >> 2) & 7)) * 4] = v;
    }
    for (int i = tid; i < 128 * 8; i += 256) {           // words 32..33: coords+temporal+pad
        int r = i >> 3, c = i & 7;
        int m = m0 + r;
        float v = 0.0f;
        if (m < NN) {
            if (c < 2) v = coords[2 * m + c];
            else if (c < 6) v = temporal[4 * m + (c - 2)];
        }
        xs[r][128 + c] = v;
    }
    __syncthreads();
    int mt = tid >> 3, ot = tid & 7;
    int xswz = mt & 7, wswz = ot & 7;
    float acc[4][8];
#pragma unroll
    for (int mi = 0; mi < 4; ++mi)
#pragma unroll
        for (int oi = 0; oi < 8; ++oi) acc[mi][oi] = 0.0f;
    for (int k4 = 0; k4 < 34; ++k4) {
        int xk = (k4 < 32) ? (k4 ^ xswz) : k4;
        int wk = (k4 < 32) ? (k4 ^ wswz) : k4;
        float4 xv[4], wv[8];
#pragma unroll
        for (int mi = 0; mi < 4; ++mi) xv[mi] = *(const float4*)&xs[mt * 4 + mi][xk * 4];
#pragma unroll
        for (int oi = 0; oi < 8; ++oi) wv[oi] = *(const float4*)&wt[ot * 8 + oi][wk * 4];
#pragma unroll
        for (int mi = 0; mi < 4; ++mi)
#pragma unroll
            for (int oi = 0; oi < 8; ++oi)
                acc[mi][oi] += xv[mi].x * wv[oi].x + xv[mi].y * wv[oi].y
                             + xv[mi].z * wv[oi].z + xv[mi].w * wv[oi].w;
    }
#pragma unroll
    for (int mi = 0; mi < 4; ++mi) {
        int m = m0 + mt * 4 + mi;
        if (m >= NN) continue;
        int ob = ot * 8;
        *(float4*)&h1[(size_t)m * GH + ob] = make_float4(acc[mi][0], acc[mi][1], acc[mi][2], acc[mi][3]);
        *(float4*)&h1[(size_t)m * GH + ob + 4] = make_float4(acc[mi][4], acc[mi][5], acc[mi][6], acc[mi][7]);
    }
}

// ---------------- symmetric-norm aggregation (CSR, int2 edges, 8-deep MLP) ----------------
// Latency-bound L3 gather: unroll 8 to double outstanding row loads.
__global__ __launch_bounds__(256) void agg_kernel(const float* __restrict__ hin,
                                                  const int* __restrict__ rs,
                                                  const int2* __restrict__ ssrcw,
                                                  const float* __restrict__ dinv,
                                                  const float* __restrict__ bias, int relu,
                                                  float* __restrict__ hout) {
    int lane = threadIdx.x & 63;
    int wid = threadIdx.x >> 6;
    int n = blockIdx.x * 4 + wid;
    if (n >= NN) return;
    float dv = dinv[n];
    float acc = hin[(size_t)n * GH + lane] * (dv * dv);  // self loop
    int i = rs[n], e1 = rs[n + 1];
    for (; i + 7 < e1; i += 8) {
        int4 p0 = *(const int4*)&ssrcw[i];
        int4 p1 = *(const int4*)&ssrcw[i + 2];
        int4 p2 = *(const int4*)&ssrcw[i + 4];
        int4 p3 = *(const int4*)&ssrcw[i + 6];
        float a0 = hin[(size_t)p0.x * GH + lane];
        float a1 = hin[(size_t)p0.z * GH + lane];
        float a2 = hin[(size_t)p1.x * GH + lane];
        float a3 = hin[(size_t)p1.z * GH + lane];
        float a4 = hin[(size_t)p2.x * GH + lane];
        float a5 = hin[(size_t)p2.z * GH + lane];
        float a6 = hin[(size_t)p3.x * GH + lane];
        float a7 = hin[(size_t)p3.z * GH + lane];
        acc += a0 * __int_as_float(p0.y) + a1 * __int_as_float(p0.w)
             + a2 * __int_as_float(p1.y) + a3 * __int_as_float(p1.w)
             + a4 * __int_as_float(p2.y) + a5 * __int_as_float(p2.w)
             + a6 * __int_as_float(p3.y) + a7 * __int_as_float(p3.w);
    }
    for (; i + 3 < e1; i += 4) {
        int4 p0 = *(const int4*)&ssrcw[i];
        int4 p1 = *(const int4*)&ssrcw[i + 2];
        float a0 = hin[(size_t)p0.x * GH + lane];
        float a1 = hin[(size_t)p0.z * GH + lane];
        float a2 = hin[(size_t)p1.x * GH + lane];
        float a3 = hin[(size_t)p1.z * GH + lane];
        acc += a0 * __int_as_float(p0.y) + a1 * __int_as_float(p0.w)
             + a2 * __int_as_float(p1.y) + a3 * __int_as_float(p1.w);
    }
    for (; i < e1; ++i) {
        int2 p = ssrcw[i];
        acc += hin[(size_t)p.x * GH + lane] * __int_as_float(p.y);
    }
    if (bias) acc += bias[lane];
    if (relu) acc = fmaxf(acc, 0.0f);
    hout[(size_t)n * GH + lane] = acc;
}

// ---------------- GCN layer 2 GEMM v2 (64 -> 128), register-tiled ----------------
__global__ __launch_bounds__(256) void gemm2_kernel(const float* __restrict__ a2,
                                                    const float* __restrict__ w2t,
                                                    const float* __restrict__ b2,
                                                    float* __restrict__ z2) {
    int m0 = blockIdx.x * 128, o0 = blockIdx.y * 64;
    __shared__ __align__(16) float xs[128][64];
    __shared__ __align__(16) float wt[64][64];
    __shared__ float bsh[64];
    int tid = threadIdx.x;
#pragma unroll
    for (int i = 0; i < 8; ++i) {            // stage a2 rows (swizzled)
        int idx = i * 256 + tid;
        int r = idx >> 4, c4 = idx & 15;
        int m = m0 + r;
        float4 v = (m < NN) ? *(const float4*)&a2[(size_t)m * GH + c4 * 4]
                            : make_float4(0.f, 0.f, 0.f, 0.f);
        *(float4*)&xs[r][(c4 ^ ((r >> 2) & 3)) * 4] = v;
    }
#pragma unroll
    for (int i = 0; i < 4; ++i) {            // stage w2t rows (swizzled)
        int idx = i * 256 + tid;
        int r = idx >> 4, c4 = idx & 15;
        float4 v = *(const float4*)&w2t[(size_t)(o0 + r) * GH + c4 * 4];
        *(float4*)&wt[r][(c4 ^ ((r >> 3) & 7)) * 4] = v;
    }
    if (tid < 64) bsh[tid] = b2[o0 + tid];
    __syncthreads();
    int mt = tid >> 3, ot = tid & 7;
    float acc[4][8];
#pragma unroll
    for (int mi = 0; mi < 4; ++mi)
#pragma unroll
        for (int oi = 0; oi < 8; ++oi) acc[mi][oi] = 0.0f;
    for (int k4 = 0; k4 < 16; ++k4) {
        int xc = (k4 ^ (mt & 3)) * 4;
        int wc = (k4 ^ (ot & 7)) * 4;
        float4 xv[4], wv[8];
#pragma unroll
        for (int mi = 0; mi < 4; ++mi) xv[mi] = *(const float4*)&xs[mt * 4 + mi][xc];
#pragma unroll
        for (int oi = 0; oi < 8; ++oi) wv[oi] = *(const float4*)&wt[ot * 8 + oi][wc];
#pragma unroll
        for (int mi = 0; mi < 4; ++mi)
#pragma unroll
            for (int oi = 0; oi < 8; ++oi)
                acc[mi][oi] += xv[mi].x * wv[oi].x + xv[mi].y * wv[oi].y
                             + xv[mi].z * wv[oi].z + xv[mi].w * wv[oi].w;
    }
#pragma unroll
    for (int mi = 0; mi < 4; ++mi) {
        int m = m0 + mt * 4 + mi;
        if (m >= NN) continue;
        int ob = ot * 8;
        float4 oa = make_float4(acc[mi][0] + bsh[ob + 0], acc[mi][1] + bsh[ob + 1],
                                acc[mi][2] + bsh[ob + 2], acc[mi][3] + bsh[ob + 3]);
        float4 obv = make_float4(acc[mi][4] + bsh[ob + 4], acc[mi][5] + bsh[ob + 5],
                                 acc[mi][6] + bsh[ob + 6], acc[mi][7] + bsh[ob + 7]);
        *(float4*)&z2[(size_t)m * EMB + o0 + ob] = oa;
        *(float4*)&z2[(size_t)m * EMB + o0 + ob + 4] = obv;
    }
}

// ---------------- pre-GEMM v4: gather fused into staging ----------------
__global__ __launch_bounds__(256) void pregemm_kernel(const float* __restrict__ z2,
                                                      const int* __restrict__ seq,
                                                      const float* __restrict__ w_ih_f,
                                                      const float* __restrict__ w_ih_b,
                                                      const float* __restrict__ b_ih_f,
                                                      const float* __restrict__ b_hh_f,
                                                      const float* __restrict__ b_ih_b,
                                                      const float* __restrict__ b_hh_b,
                                                      const int* __restrict__ lengths,
                                                      float* __restrict__ xpf,
                                                      float* __restrict__ xpb) {
    int dir = blockIdx.z;
    const float* w_ih = dir ? w_ih_b : w_ih_f;
    int o0 = blockIdx.y * PO;
    int m0 = blockIdx.x * PM;
    __shared__ __align__(16) float xs[PM][EMB];
    __shared__ __align__(16) float ws[PO][EMB];
    __shared__ float bsh[PO];
    int tid = threadIdx.x;
#pragma unroll
    for (int i = 0; i < 16; ++i) {          // stage W (swizzled)
        int idx = i * 256 + tid;
        int row = idx >> 5, c4 = idx & 31;
        float4 v = *(const float4*)&w_ih[(size_t)(o0 + row) * EMB + c4 * 4];
        *(float4*)&ws[row][(c4 ^ ((row >> 3) & 7)) * 4] = v;
    }
    if (tid < PO) bsh[tid] = dir ? (b_ih_b[o0 + tid] + b_hh_b[o0 + tid])
                                 : (b_ih_f[o0 + tid] + b_hh_f[o0 + tid]);
#pragma unroll
    for (int i = 0; i < 16; ++i) {          // stage x via fused gather (swizzled)
        int idx = i * 256 + tid;
        int r = idx >> 5, c4 = idx & 31;
        int m = m0 + r;
        int t = m >> 6, b = m & 63;
        int tsrc = t;
        if (dir) { int len = lengths[b]; tsrc = (t < len) ? (len - 1 - t) : t; }
        int node = seq[b * TT + tsrc];
        float4 v = *(const float4*)&z2[(size_t)node * EMB + c4 * 4];
        *(float4*)&xs[r][(c4 ^ ((r >> 3) & 3)) * 4] = v;
    }
    __syncthreads();
    int mt = tid >> 4, ot = tid & 15;
    int mswz = mt & 3, oswz = ot & 7;
    float acc[8][8];
#pragma unroll
    for (int mi = 0; mi < 8; ++mi)
#pragma unroll
        for (int oi = 0; oi < 8; ++oi) acc[mi][oi] = 0.0f;
    for (int k4 = 0; k4 < 32; ++k4) {
        int xk = (k4 ^ mswz) * 4;
        int wk = (k4 ^ oswz) * 4;
        float4 xv[8], wv[8];
#pragma unroll
        for (int mi = 0; mi < 8; ++mi) xv[mi] = *(const float4*)&xs[mt * 8 + mi][xk];
#pragma unroll
        for (int oi = 0; oi < 8; ++oi) wv[oi] = *(const float4*)&ws[ot * 8 + oi][wk];
#pragma unroll
        for (int mi = 0; mi < 8; ++mi)
#pragma unroll
            for (int oi = 0; oi < 8; ++oi)
                acc[mi][oi] += xv[mi].x * wv[oi].x + xv[mi].y * wv[oi].y
                             + xv[mi].z * wv[oi].z + xv[mi].w * wv[oi].w;
    }
    float* xp = dir ? xpb : xpf;
#pragma unroll
    for (int mi = 0; mi < 8; ++mi) {
        int m = m0 + mt * 8 + mi;
        int ob = ot * 8;
        float4 oa = make_float4(acc[mi][0] + bsh[ob + 0], acc[mi][1] + bsh[ob + 1],
                                acc[mi][2] + bsh[ob + 2], acc[mi][3] + bsh[ob + 3]);
        float4 obv = make_float4(acc[mi][4] + bsh[ob + 4], acc[mi][5] + bsh[ob + 5],
                                 acc[mi][6] + bsh[ob + 6], acc[mi][7] + bsh[ob + 7]);
        *(float4*)&xp[(size_t)m * G4 + o0 + ob] = oa;
        *(float4*)&xp[(size_t)m * G4 + o0 + ob + 4] = obv;
    }
}

// ---------------- LSTM recurrence v8 (structure Z + NO-DRAIN barriers) ----------------
// R10 falsified the conflict theory (part transpose = flat). Remaining gap
// (~1000cyc/step) pinned on __syncthreads' s_waitcnt vmcnt(0) drain: the xp
// prefetch is a COLD HBM read (~900cyc) with only phase-A (~600cyc) of cover
// before barrier #1 forced it complete. v8 uses raw s_barrier with explicit
// lgkmcnt(0) only (LDS ordering preserved); global loads float across
// barriers and are waited at their use point -> full-step (~2000cyc) cover.
__global__ __launch_bounds__(1024, 4) void lstm_kernel(const float* __restrict__ xpf,
                                                       const float* __restrict__ xpb,
                                                       const float* __restrict__ w_hh_f,
                                                       const float* __restrict__ w_hh_b,
                                                       const int* __restrict__ lengths,
                                                       float* __restrict__ hfo,
                                                       float* __restrict__ hbo) {
    int chain = blockIdx.x;
    int dir = chain & 1, b = chain >> 1;
    const float* w_hh = dir ? w_hh_b : w_hh_f;
    const float* xp = dir ? xpb : xpf;
    float* ho = dir ? hbo : hfo;
    int tid = threadIdx.x;
    int u = tid & 127;
    int kq = tid >> 7;    // 0..7
    int len = lengths[b];

    float4 W[4][4];
#pragma unroll
    for (int g = 0; g < 4; ++g)
#pragma unroll
        for (int j4 = 0; j4 < 4; ++j4)
            W[g][j4] = *(const float4*)&w_hh[(size_t)(g * HH + u) * HH + kq * 16 + j4 * 4];

    __shared__ __align__(16) float hl[HH];
    __shared__ __align__(16) float part[8][HH][4];   // [kq][u][gate] - conflict-free
    if (tid < HH) hl[tid] = 0.0f;
    __syncthreads();

    float cst = 0.0f, hkeep = 0.0f;
    int tprev = -1;
    float x0 = 0.f, x1 = 0.f, x2 = 0.f, x3 = 0.f;
    const float* xpt = xp + (size_t)b * G4 + u;
    if (tid < HH && len > 0) {
        x0 = xpt[0]; x1 = xpt[HH]; x2 = xpt[2 * HH]; x3 = xpt[3 * HH];
    }
    for (int t = 0; t < len; ++t) {
        float n0 = 0.f, n1 = 0.f, n2 = 0.f, n3 = 0.f;
        if (tid < HH) {
            if (tprev >= 0) ho[((size_t)b * TT + tprev) * HH + u] = hkeep;  // store h(t-1)
            if (t + 1 < len) {                                             // prefetch x(t+1)
                const float* xn = xpt + (size_t)(t + 1) * (BB * G4);
                n0 = xn[0]; n1 = xn[HH]; n2 = xn[2 * HH]; n3 = xn[3 * HH];
            }
        }
        // phase A: all 16 waves; wave-uniform h broadcast reads
        const float4* h4 = (const float4*)&hl[kq * 16];
        float a0 = 0.f, a1 = 0.f, a2 = 0.f, a3 = 0.f;
#pragma unroll
        for (int j4 = 0; j4 < 4; ++j4) {
            float4 hv = h4[j4];
            a0 += W[0][j4].x * hv.x + W[0][j4].y * hv.y + W[0][j4].z * hv.z + W[0][j4].w * hv.w;
            a1 += W[1][j4].x * hv.x + W[1][j4].y * hv.y + W[1][j4].z * hv.z + W[1][j4].w * hv.w;
            a2 += W[2][j4].x * hv.x + W[2][j4].y * hv.y + W[2][j4].z * hv.z + W[2][j4].w * hv.w;
            a3 += W[3][j4].x * hv.x + W[3][j4].y * hv.y + W[3][j4].z * hv.z + W[3][j4].w * hv.w;
        }
        if (kq) *(float4*)&part[kq][u][0] = make_float4(a0, a1, a2, a3);
        barrier_nodrain();
        // phase B: 2 waves (kq=0 threads), no global ops on the drain path
        if (tid < HH) {
            float s0 = x0 + a0, s1 = x1 + a1, s2 = x2 + a2, s3 = x3 + a3;
#pragma unroll
            for (int q = 1; q < 8; ++q) {
                float4 p = *(const float4*)&part[q][u][0];
                s0 += p.x; s1 += p.y; s2 += p.z; s3 += p.w;
            }
            float gi = sigf(s0), gf = sigf(s1), gg = tanhf_(s2), go = sigf(s3);
            cst = gf * cst + gi * gg;
            float h = go * tanhf_(cst);
            hl[u] = h;
            hkeep = h;
            tprev = dir ? (len - 1 - t) : t;
            x0 = n0; x1 = n1; x2 = n2; x3 = n3;
        }
        barrier_nodrain();
    }
    if (tid < HH && tprev >= 0) ho[((size_t)b * TT + tprev) * HH + u] = hkeep;
}

// ---------------- masked attention pooling ----------------
__global__ __launch_bounds__(256) void attn_kernel(const float* __restrict__ hf,
                                                   const float* __restrict__ hb,
                                                   const float* __restrict__ attn_w,
                                                   const float* __restrict__ attn_b,
                                                   const int* __restrict__ lengths,
                                                   float* __restrict__ ctx) {
    int b = blockIdx.x;
    int tid = threadIdx.x;
    int len = lengths[b];
    __shared__ __align__(16) float wl[256];
    __shared__ float pl[256];
    __shared__ float red[256];
    wl[tid] = attn_w[tid];
    __syncthreads();
    float sc = -3.0e38f;
    if (tid < len) {
        const float4* rf = (const float4*)(hf + ((size_t)b * TT + tid) * HH);
        const float4* rb = (const float4*)(hb + ((size_t)b * TT + tid) * HH);
        const float4* w4 = (const float4*)wl;
        float s = attn_b[0];
        for (int k4 = 0; k4 < 32; ++k4) {
            float4 a = rf[k4], ww = w4[k4];
            s += a.x * ww.x + a.y * ww.y + a.z * ww.z + a.w * ww.w;
        }
        for (int k4 = 0; k4 < 32; ++k4) {
            float4 a = rb[k4], ww = w4[32 + k4];
            s += a.x * ww.x + a.y * ww.y + a.z * ww.z + a.w * ww.w;
        }
        sc = s;
    }
    red[tid] = sc;
    __syncthreads();
    for (int off = 128; off > 0; off >>= 1) {
        if (tid < off) red[tid] = fmaxf(red[tid], red[tid + off]);
        __syncthreads();
    }
    float mx = red[0];
    __syncthreads();
    float e = (tid < len) ? __expf(sc - mx) : 0.0f;
    red[tid] = e;
    __syncthreads();
    for (int off = 128; off > 0; off >>= 1) {
        if (tid < off) red[tid] += red[tid + off];
        __syncthreads();
    }
    float inv = 1.0f / red[0];
    pl[tid] = e * inv;
    __syncthreads();
    float acc = 0.0f;
    const float* basep = (tid < HH) ? (hf + (size_t)b * TT * HH + tid)
                                    : (hb + (size_t)b * TT * HH + (tid - HH));
#pragma unroll 4
    for (int t = 0; t < len; ++t) acc += pl[t] * basep[(size_t)t * HH];
    ctx[(size_t)b * 256 + tid] = acc;
}

// ---------------- final FC v2: thread = 4 n-cols x 16 b-rows ----------------
__global__ __launch_bounds__(256) void fc_kernel(const float* __restrict__ ctx,
                                                 const float* __restrict__ fc_w,
                                                 const float* __restrict__ fc_b,
                                                 float* __restrict__ out) {
    __shared__ __align__(16) float cl[64][256];
    for (int i = threadIdx.x; i < 64 * 256 / 4; i += 256)
        ((float4*)cl)[i] = ((const float4*)ctx)[i];
    __syncthreads();
    int lane = threadIdx.x & 63;
    int bq = threadIdx.x >> 6;
    int nb = blockIdx.x * 256 + lane;
    float acc[16][4];
#pragma unroll
    for (int i = 0; i < 16; ++i)
#pragma unroll
        for (int c = 0; c < 4; ++c) acc[i][c] = 0.0f;
    for (int k4 = 0; k4 < 64; ++k4) {
        int k = k4 * 4;
        float w[4][4];
#pragma unroll
        for (int j = 0; j < 4; ++j)
#pragma unroll
            for (int c = 0; c < 4; ++c) {
                int n = nb + c * 64;
                w[j][c] = (n < NN) ? fc_w[(size_t)(k + j) * NN + n] : 0.0f;
            }
#pragma unroll
        for (int i = 0; i < 16; ++i) {
            float4 cv = *(const float4*)&cl[bq * 16 + i][k];
#pragma unroll
            for (int c = 0; c < 4; ++c)
                acc[i][c] += cv.x * w[0][c] + cv.y * w[1][c] + cv.z * w[2][c] + cv.w * w[3][c];
        }
    }
#pragma unroll
    for (int i = 0; i < 16; ++i)
#pragma unroll
        for (int c = 0; c < 4; ++c) {
            int n = nb + c * 64;
            if (n < NN) out[(size_t)(bq * 16 + i) * NN + n] = acc[i][c] + fc_b[n];
        }
}

// ---------------- host launcher ----------------
extern "C" void kernel_launch(void* const* d_in, const int* in_sizes, int n_in,
                              void* d_out, int out_size, void* d_ws, size_t ws_size,
                              hipStream_t stream) {
    const float* x_coords   = (const float*)d_in[0];
    const float* temporal   = (const float*)d_in[1];
    const int*   edge_index = (const int*)d_in[2];
    const float* edge_w     = (const float*)d_in[3];
    const int*   seq        = (const int*)d_in[4];
    const int*   lengths    = (const int*)d_in[5];
    const float* node_emb   = (const float*)d_in[6];
    const float* gcn1_w     = (const float*)d_in[7];
    const float* gcn1_b     = (const float*)d_in[8];
    const float* gcn2_w     = (const float*)d_in[9];
    const float* gcn2_b     = (const float*)d_in[10];
    const float* w_ih_f     = (const float*)d_in[11];
    const float* w_hh_f     = (const float*)d_in[12];
    const float* b_ih_f     = (const float*)d_in[13];
    const float* b_hh_f     = (const float*)d_in[14];
    const float* w_ih_b     = (const float*)d_in[15];
    const float* w_hh_b     = (const float*)d_in[16];
    const float* b_ih_b     = (const float*)d_in[17];
    const float* b_hh_b     = (const float*)d_in[18];
    const float* attn_w     = (const float*)d_in[19];
    const float* attn_b     = (const float*)d_in[20];
    const float* fc_w       = (const float*)d_in[21];
    const float* fc_b       = (const float*)d_in[22];
    float* out = (float*)d_out;

    char* base = (char*)d_ws;
    size_t off = 0;
    auto alloc = [&](size_t nbytes) -> void* {
        void* p = base + off;
        off = (off + nbytes + 255) & ~(size_t)255;
        return p;
    };
    int*   cnt     = (int*)alloc((size_t)2 * NN * 4);  // cnt + degw contiguous (one memset)
    float* degw    = (float*)(cnt + NN);
    float* dinv    = (float*)alloc((size_t)NN * 4);
    int*   rs      = (int*)alloc(((size_t)NN + 1) * 4);
    int*   cursor  = (int*)alloc((size_t)NN * 4);
    int*   partials= (int*)alloc(64 * 4);
    int2*  ssrcw   = (int2*)alloc((size_t)NE * 8);
    float* h1      = (float*)alloc((size_t)NN * GH * 4);
    float* z1      = (float*)alloc((size_t)NN * GH * 4);
    float* a2      = h1;  // h1 dead after agg1
    float* w1t     = (float*)alloc((size_t)64 * 136 * 4);
    float* w2t     = (float*)alloc((size_t)GH * EMB * 4);
    float* z2      = (float*)alloc((size_t)NN * EMB * 4);
    float* xpf     = (float*)alloc((size_t)TT * BB * G4 * 4);
    float* xpb     = (float*)alloc((size_t)TT * BB * G4 * 4);
    float* hfo     = (float*)alloc((size_t)BB * TT * HH * 4);
    float* hbo     = (float*)alloc((size_t)BB * TT * HH * 4);
    float* ctx     = (float*)alloc((size_t)BB * 256 * 4);
    (void)ws_size; (void)in_sizes; (void)n_in; (void)out_size;

    hipMemsetAsync(cnt, 0, (size_t)2 * NN * 4, stream);

    hist_kernel<<<(NE + 255) / 256, 256, 0, stream>>>(edge_index, edge_w, cnt, degw);
    const int nblk = (NN + 1023) / 1024;  // 49
    scan1_kernel<<<nblk, 1024, 0, stream>>>(cnt, degw, dinv, rs, partials);
    misc_kernel<<<67, 256, 0, stream>>>(partials, nblk, gcn1_w, w1t, gcn2_w, w2t);
    scan3_kernel<<<nblk, 1024, 0, stream>>>(partials, rs, cursor);
    fill_kernel<<<(NE + 255) / 256, 256, 0, stream>>>(edge_index, edge_w, dinv, cursor, ssrcw);

    gemm1_kernel<<<(NN + 127) / 128, 256, 0, stream>>>(x_coords, temporal, node_emb, w1t, h1);
    agg_kernel<<<(NN + 3) / 4, 256, 0, stream>>>(h1, rs, ssrcw, dinv, gcn1_b, 1, z1);
    agg_kernel<<<(NN + 3) / 4, 256, 0, stream>>>(z1, rs, ssrcw, dinv, (const float*)nullptr, 0, a2);
    gemm2_kernel<<<dim3((NN + 127) / 128, 2), 256, 0, stream>>>(a2, w2t, gcn2_b, z2);

    pregemm_kernel<<<dim3(TT * BB / PM, G4 / PO, 2), 256, 0, stream>>>(
        z2, seq, w_ih_f, w_ih_b, b_ih_f, b_hh_f, b_ih_b, b_hh_b, lengths, xpf, xpb);
    lstm_kernel<<<BB * 2, 1024, 0, stream>>>(xpf, xpb, w_hh_f, w_hh_b, lengths, hfo, hbo);
    attn_kernel<<<BB, 256, 0, stream>>>(hfo, hbo, attn_w, attn_b, lengths, ctx);
    fc_kernel<<<(NN + 255) / 256, 256, 0, stream>>>(ctx, fc_w, fc_b, out);
}

// Round 12
// 645.801 us; speedup vs baseline: 1.0855x; 1.0235x over previous
//
#include <hip/hip_runtime.h>
#include <math.h>

#define NN 50000
#define NE 800000
#define EMB 128
#define GH 64
#define BB 64
#define TT 200
#define HH 128
#define G4 512
#define IND 134
#define PM 128
#define PO 128

__device__ __forceinline__ float sigf(float x) { return 1.0f / (1.0f + __expf(-x)); }
__device__ __forceinline__ float tanhf_(float x) { return 1.0f - 2.0f / (__expf(2.0f * x) + 1.0f); }

// ---------------- CSR build ----------------
__global__ void hist_kernel(const int* __restrict__ ei, const float* __restrict__ ew,
                            int* __restrict__ cnt, float* __restrict__ degw) {
    int e = blockIdx.x * 256 + threadIdx.x;
    if (e >= NE) return;
    int d = ei[NE + e];
    atomicAdd(&cnt[d], 1);
    atomicAdd(&degw[d], ew[e]);
}

// scan1 + dinv fused (both depend only on hist)
__global__ __launch_bounds__(1024) void scan1_kernel(const int* __restrict__ cnt,
                                                     const float* __restrict__ degw,
                                                     float* __restrict__ dinv,
                                                     int* __restrict__ rs, int* __restrict__ partials) {
    __shared__ int s[1024];
    int gid = blockIdx.x * 1024 + threadIdx.x;
    int v = (gid < NN) ? cnt[gid] : 0;
    if (gid < NN) dinv[gid] = rsqrtf(degw[gid] + 1.0f);   // +1 self loop
    s[threadIdx.x] = v;
    __syncthreads();
    for (int off = 1; off < 1024; off <<= 1) {
        int add = (threadIdx.x >= (unsigned)off) ? s[threadIdx.x - off] : 0;
        __syncthreads();
        s[threadIdx.x] += add;
        __syncthreads();
    }
    if (gid < NN) rs[gid] = s[threadIdx.x] - v;  // exclusive
    if (threadIdx.x == 1023) partials[blockIdx.x] = s[1023];
}

// misc: block 0 = parallel scan of partials; blocks 1..34 = W1 transpose+reorder;
// blocks 35..66 = W2 transpose.
__global__ void misc_kernel(int* __restrict__ partials, int nblk,
                            const float* __restrict__ W1, float* __restrict__ w1t,
                            const float* __restrict__ W2, float* __restrict__ w2t) {
    int blk = blockIdx.x;
    int tid = threadIdx.x;
    if (blk == 0) {
        __shared__ int s[64];
        int v = (tid < nblk) ? partials[tid] : 0;
        s[tid] = v;
        __syncthreads();
        for (int off = 1; off < 64; off <<= 1) {
            int add = (tid >= off) ? s[tid - off] : 0;
            __syncthreads();
            s[tid] += add;
            __syncthreads();
        }
        if (tid < nblk) partials[tid] = s[tid] - v;  // exclusive
    } else if (blk <= 34) {
        int i = (blk - 1) * 256 + tid;
        if (i < 64 * 136) {
            int o = i / 136, j = i - o * 136;
            float v = 0.0f;
            if (j < 128) v = W1[(size_t)(j + 2) * GH + o];
            else if (j < 130) v = W1[(size_t)(j - 128) * GH + o];
            else if (j < 134) v = W1[(size_t)j * GH + o];
            w1t[i] = v;
        }
    } else {
        int i = (blk - 35) * 256 + tid;
        if (i < GH * EMB) {
            int o = i >> 6, k = i & 63;
            w2t[i] = W2[(size_t)k * EMB + o];
        }
    }
}

__global__ __launch_bounds__(1024) void scan3_kernel(const int* __restrict__ partials,
                                                     int* __restrict__ rs, int* __restrict__ cursor) {
    int gid = blockIdx.x * 1024 + threadIdx.x;
    if (gid < NN) {
        int v = rs[gid] + partials[gid >> 10];
        rs[gid] = v;
        cursor[gid] = v;
    }
    if (gid == 0) rs[NN] = NE;
}

// fill: (src, weight) packed into int2 -> ONE random 8B scatter instead of two 4B
__global__ void fill_kernel(const int* __restrict__ ei, const float* __restrict__ ew,
                            const float* __restrict__ dinv, int* __restrict__ cursor,
                            int2* __restrict__ ssrcw) {
    int e = blockIdx.x * 256 + threadIdx.x;
    if (e >= NE) return;
    int s = ei[e], d = ei[NE + e];
    int pos = atomicAdd(&cursor[d], 1);
    ssrcw[pos] = make_int2(s, __float_as_int(ew[e] * dinv[s] * dinv[d]));
}

// ---------------- GCN layer 1 GEMM v2 (134 -> 64), register-tiled ----------------
__global__ __launch_bounds__(256) void gemm1_kernel(const float* __restrict__ coords,
                                                    const float* __restrict__ temporal,
                                                    const float* __restrict__ emb,
                                                    const float* __restrict__ w1t,
                                                    float* __restrict__ h1) {
    __shared__ __align__(16) float xs[128][136];
    __shared__ __align__(16) float wt[64][136];
    int tid = threadIdx.x;
    int m0 = blockIdx.x * 128;
    for (int i = tid; i < 64 * 34; i += 256) {           // stage W^T (swizzled words 0..31)
        int rr = i / 34, w = i - rr * 34;
        float4 v = *(const float4*)&w1t[(size_t)rr * 136 + w * 4];
        int ws = (w < 32) ? (w ^ ((rr >> 3) & 7)) : w;
        *(float4*)&wt[rr][ws * 4] = v;
    }
    for (int i = tid; i < 128 * 32; i += 256) {          // stage emb words 0..31 (swizzled)
        int r = i >> 5, c4 = i & 31;
        int m = m0 + r;
        float4 v = make_float4(0.f, 0.f, 0.f, 0.f);
        if (m < NN) v = *(const float4*)&emb[(size_t)m * EMB + c4 * 4];
        *(float4*)&xs[r][(c4 ^ ((r >> 2) & 7)) * 4] = v;
    }
    for (int i = tid; i < 128 * 8; i += 256) {           // words 32..33: coords+temporal+pad
        int r = i >> 3, c = i & 7;
        int m = m0 + r;
        float v = 0.0f;
        if (m < NN) {
            if (c < 2) v = coords[2 * m + c];
            else if (c < 6) v = temporal[4 * m + (c - 2)];
        }
        xs[r][128 + c] = v;
    }
    __syncthreads();
    int mt = tid >> 3, ot = tid & 7;
    int xswz = mt & 7, wswz = ot & 7;
    float acc[4][8];
#pragma unroll
    for (int mi = 0; mi < 4; ++mi)
#pragma unroll
        for (int oi = 0; oi < 8; ++oi) acc[mi][oi] = 0.0f;
    for (int k4 = 0; k4 < 34; ++k4) {
        int xk = (k4 < 32) ? (k4 ^ xswz) : k4;
        int wk = (k4 < 32) ? (k4 ^ wswz) : k4;
        float4 xv[4], wv[8];
#pragma unroll
        for (int mi = 0; mi < 4; ++mi) xv[mi] = *(const float4*)&xs[mt * 4 + mi][xk * 4];
#pragma unroll
        for (int oi = 0; oi < 8; ++oi) wv[oi] = *(const float4*)&wt[ot * 8 + oi][wk * 4];
#pragma unroll
        for (int mi = 0; mi < 4; ++mi)
#pragma unroll
            for (int oi = 0; oi < 8; ++oi)
                acc[mi][oi] += xv[mi].x * wv[oi].x + xv[mi].y * wv[oi].y
                             + xv[mi].z * wv[oi].z + xv[mi].w * wv[oi].w;
    }
#pragma unroll
    for (int mi = 0; mi < 4; ++mi) {
        int m = m0 + mt * 4 + mi;
        if (m >= NN) continue;
        int ob = ot * 8;
        *(float4*)&h1[(size_t)m * GH + ob] = make_float4(acc[mi][0], acc[mi][1], acc[mi][2], acc[mi][3]);
        *(float4*)&h1[(size_t)m * GH + ob + 4] = make_float4(acc[mi][4], acc[mi][5], acc[mi][6], acc[mi][7]);
    }
}

// ---------------- symmetric-norm aggregation (CSR, int2 edges, 8-deep MLP) ----------------
__global__ __launch_bounds__(256) void agg_kernel(const float* __restrict__ hin,
                                                  const int* __restrict__ rs,
                                                  const int2* __restrict__ ssrcw,
                                                  const float* __restrict__ dinv,
                                                  const float* __restrict__ bias, int relu,
                                                  float* __restrict__ hout) {
    int lane = threadIdx.x & 63;
    int wid = threadIdx.x >> 6;
    int n = blockIdx.x * 4 + wid;
    if (n >= NN) return;
    float dv = dinv[n];
    float acc = hin[(size_t)n * GH + lane] * (dv * dv);  // self loop
    int i = rs[n], e1 = rs[n + 1];
    for (; i + 7 < e1; i += 8) {
        int4 p0 = *(const int4*)&ssrcw[i];
        int4 p1 = *(const int4*)&ssrcw[i + 2];
        int4 p2 = *(const int4*)&ssrcw[i + 4];
        int4 p3 = *(const int4*)&ssrcw[i + 6];
        float a0 = hin[(size_t)p0.x * GH + lane];
        float a1 = hin[(size_t)p0.z * GH + lane];
        float a2 = hin[(size_t)p1.x * GH + lane];
        float a3 = hin[(size_t)p1.z * GH + lane];
        float a4 = hin[(size_t)p2.x * GH + lane];
        float a5 = hin[(size_t)p2.z * GH + lane];
        float a6 = hin[(size_t)p3.x * GH + lane];
        float a7 = hin[(size_t)p3.z * GH + lane];
        acc += a0 * __int_as_float(p0.y) + a1 * __int_as_float(p0.w)
             + a2 * __int_as_float(p1.y) + a3 * __int_as_float(p1.w)
             + a4 * __int_as_float(p2.y) + a5 * __int_as_float(p2.w)
             + a6 * __int_as_float(p3.y) + a7 * __int_as_float(p3.w);
    }
    for (; i + 3 < e1; i += 4) {
        int4 p0 = *(const int4*)&ssrcw[i];
        int4 p1 = *(const int4*)&ssrcw[i + 2];
        float a0 = hin[(size_t)p0.x * GH + lane];
        float a1 = hin[(size_t)p0.z * GH + lane];
        float a2 = hin[(size_t)p1.x * GH + lane];
        float a3 = hin[(size_t)p1.z * GH + lane];
        acc += a0 * __int_as_float(p0.y) + a1 * __int_as_float(p0.w)
             + a2 * __int_as_float(p1.y) + a3 * __int_as_float(p1.w);
    }
    for (; i < e1; ++i) {
        int2 p = ssrcw[i];
        acc += hin[(size_t)p.x * GH + lane] * __int_as_float(p.y);
    }
    if (bias) acc += bias[lane];
    if (relu) acc = fmaxf(acc, 0.0f);
    hout[(size_t)n * GH + lane] = acc;
}

// ---------------- GCN layer 2 GEMM v2 (64 -> 128), register-tiled ----------------
__global__ __launch_bounds__(256) void gemm2_kernel(const float* __restrict__ a2,
                                                    const float* __restrict__ w2t,
                                                    const float* __restrict__ b2,
                                                    float* __restrict__ z2) {
    int m0 = blockIdx.x * 128, o0 = blockIdx.y * 64;
    __shared__ __align__(16) float xs[128][64];
    __shared__ __align__(16) float wt[64][64];
    __shared__ float bsh[64];
    int tid = threadIdx.x;
#pragma unroll
    for (int i = 0; i < 8; ++i) {            // stage a2 rows (swizzled)
        int idx = i * 256 + tid;
        int r = idx >> 4, c4 = idx & 15;
        int m = m0 + r;
        float4 v = (m < NN) ? *(const float4*)&a2[(size_t)m * GH + c4 * 4]
                            : make_float4(0.f, 0.f, 0.f, 0.f);
        *(float4*)&xs[r][(c4 ^ ((r >> 2) & 3)) * 4] = v;
    }
#pragma unroll
    for (int i = 0; i < 4; ++i) {            // stage w2t rows (swizzled)
        int idx = i * 256 + tid;
        int r = idx >> 4, c4 = idx & 15;
        float4 v = *(const float4*)&w2t[(size_t)(o0 + r) * GH + c4 * 4];
        *(float4*)&wt[r][(c4 ^ ((r >> 3) & 7)) * 4] = v;
    }
    if (tid < 64) bsh[tid] = b2[o0 + tid];
    __syncthreads();
    int mt = tid >> 3, ot = tid & 7;
    float acc[4][8];
#pragma unroll
    for (int mi = 0; mi < 4; ++mi)
#pragma unroll
        for (int oi = 0; oi < 8; ++oi) acc[mi][oi] = 0.0f;
    for (int k4 = 0; k4 < 16; ++k4) {
        int xc = (k4 ^ (mt & 3)) * 4;
        int wc = (k4 ^ (ot & 7)) * 4;
        float4 xv[4], wv[8];
#pragma unroll
        for (int mi = 0; mi < 4; ++mi) xv[mi] = *(const float4*)&xs[mt * 4 + mi][xc];
#pragma unroll
        for (int oi = 0; oi < 8; ++oi) wv[oi] = *(const float4*)&wt[ot * 8 + oi][wc];
#pragma unroll
        for (int mi = 0; mi < 4; ++mi)
#pragma unroll
            for (int oi = 0; oi < 8; ++oi)
                acc[mi][oi] += xv[mi].x * wv[oi].x + xv[mi].y * wv[oi].y
                             + xv[mi].z * wv[oi].z + xv[mi].w * wv[oi].w;
    }
#pragma unroll
    for (int mi = 0; mi < 4; ++mi) {
        int m = m0 + mt * 4 + mi;
        if (m >= NN) continue;
        int ob = ot * 8;
        float4 oa = make_float4(acc[mi][0] + bsh[ob + 0], acc[mi][1] + bsh[ob + 1],
                                acc[mi][2] + bsh[ob + 2], acc[mi][3] + bsh[ob + 3]);
        float4 obv = make_float4(acc[mi][4] + bsh[ob + 4], acc[mi][5] + bsh[ob + 5],
                                 acc[mi][6] + bsh[ob + 6], acc[mi][7] + bsh[ob + 7]);
        *(float4*)&z2[(size_t)m * EMB + o0 + ob] = oa;
        *(float4*)&z2[(size_t)m * EMB + o0 + ob + 4] = obv;
    }
}

// ---------------- pre-GEMM v4: gather fused into staging ----------------
__global__ __launch_bounds__(256) void pregemm_kernel(const float* __restrict__ z2,
                                                      const int* __restrict__ seq,
                                                      const float* __restrict__ w_ih_f,
                                                      const float* __restrict__ w_ih_b,
                                                      const float* __restrict__ b_ih_f,
                                                      const float* __restrict__ b_hh_f,
                                                      const float* __restrict__ b_ih_b,
                                                      const float* __restrict__ b_hh_b,
                                                      const int* __restrict__ lengths,
                                                      float* __restrict__ xpf,
                                                      float* __restrict__ xpb) {
    int dir = blockIdx.z;
    const float* w_ih = dir ? w_ih_b : w_ih_f;
    int o0 = blockIdx.y * PO;
    int m0 = blockIdx.x * PM;
    __shared__ __align__(16) float xs[PM][EMB];
    __shared__ __align__(16) float ws[PO][EMB];
    __shared__ float bsh[PO];
    int tid = threadIdx.x;
#pragma unroll
    for (int i = 0; i < 16; ++i) {          // stage W (swizzled)
        int idx = i * 256 + tid;
        int row = idx >> 5, c4 = idx & 31;
        float4 v = *(const float4*)&w_ih[(size_t)(o0 + row) * EMB + c4 * 4];
        *(float4*)&ws[row][(c4 ^ ((row >> 3) & 7)) * 4] = v;
    }
    if (tid < PO) bsh[tid] = dir ? (b_ih_b[o0 + tid] + b_hh_b[o0 + tid])
                                 : (b_ih_f[o0 + tid] + b_hh_f[o0 + tid]);
#pragma unroll
    for (int i = 0; i < 16; ++i) {          // stage x via fused gather (swizzled)
        int idx = i * 256 + tid;
        int r = idx >> 5, c4 = idx & 31;
        int m = m0 + r;
        int t = m >> 6, b = m & 63;
        int tsrc = t;
        if (dir) { int len = lengths[b]; tsrc = (t < len) ? (len - 1 - t) : t; }
        int node = seq[b * TT + tsrc];
        float4 v = *(const float4*)&z2[(size_t)node * EMB + c4 * 4];
        *(float4*)&xs[r][(c4 ^ ((r >> 3) & 3)) * 4] = v;
    }
    __syncthreads();
    int mt = tid >> 4, ot = tid & 15;
    int mswz = mt & 3, oswz = ot & 7;
    float acc[8][8];
#pragma unroll
    for (int mi = 0; mi < 8; ++mi)
#pragma unroll
        for (int oi = 0; oi < 8; ++oi) acc[mi][oi] = 0.0f;
    for (int k4 = 0; k4 < 32; ++k4) {
        int xk = (k4 ^ mswz) * 4;
        int wk = (k4 ^ oswz) * 4;
        float4 xv[8], wv[8];
#pragma unroll
        for (int mi = 0; mi < 8; ++mi) xv[mi] = *(const float4*)&xs[mt * 8 + mi][xk];
#pragma unroll
        for (int oi = 0; oi < 8; ++oi) wv[oi] = *(const float4*)&ws[ot * 8 + oi][wk];
#pragma unroll
        for (int mi = 0; mi < 8; ++mi)
#pragma unroll
            for (int oi = 0; oi < 8; ++oi)
                acc[mi][oi] += xv[mi].x * wv[oi].x + xv[mi].y * wv[oi].y
                             + xv[mi].z * wv[oi].z + xv[mi].w * wv[oi].w;
    }
    float* xp = dir ? xpb : xpf;
#pragma unroll
    for (int mi = 0; mi < 8; ++mi) {
        int m = m0 + mt * 8 + mi;
        int ob = ot * 8;
        float4 oa = make_float4(acc[mi][0] + bsh[ob + 0], acc[mi][1] + bsh[ob + 1],
                                acc[mi][2] + bsh[ob + 2], acc[mi][3] + bsh[ob + 3]);
        float4 obv = make_float4(acc[mi][4] + bsh[ob + 4], acc[mi][5] + bsh[ob + 5],
                                 acc[mi][6] + bsh[ob + 6], acc[mi][7] + bsh[ob + 7]);
        *(float4*)&xp[(size_t)m * G4 + o0 + ob] = oa;
        *(float4*)&xp[(size_t)m * G4 + o0 + ob + 4] = obv;
    }
}

// ---------------- LSTM recurrence v9 (structure Z + PINNED weights) ----------------
// R11 post-mortem: VGPR_Count=56 < 64 declared W floats => the compiler has
// been REMATERIALIZING the W loads inside the t-loop since R5 (same bug as
// R1/R2): 16 waves x 16 global_load_dwordx4 = 256 L2 reloads per step per CU
// (~1000 cyc vmem issue+latency) - the unexplained half of the 2100cyc step.
// Fix: empty-asm "+v" pin after each load makes the value opaque ->
// rematerialization impossible; launch_bounds(1024,4) caps VGPR at 128 and
// 64 W + ~45 live fits. Verification signal: VGPR_Count should jump to >~105.
#define PIN4(v) asm volatile("" : "+v"(v.x), "+v"(v.y), "+v"(v.z), "+v"(v.w))
__global__ __launch_bounds__(1024, 4) void lstm_kernel(const float* __restrict__ xpf,
                                                       const float* __restrict__ xpb,
                                                       const float* __restrict__ w_hh_f,
                                                       const float* __restrict__ w_hh_b,
                                                       const int* __restrict__ lengths,
                                                       float* __restrict__ hfo,
                                                       float* __restrict__ hbo) {
    int chain = blockIdx.x;
    int dir = chain & 1, b = chain >> 1;
    const float* w_hh = dir ? w_hh_b : w_hh_f;
    const float* xp = dir ? xpb : xpf;
    float* ho = dir ? hbo : hfo;
    int tid = threadIdx.x;
    int u = tid & 127;
    int kq = tid >> 7;    // 0..7
    int len = lengths[b];

    float4 W[4][4];
#pragma unroll
    for (int g = 0; g < 4; ++g)
#pragma unroll
        for (int j4 = 0; j4 < 4; ++j4) {
            W[g][j4] = *(const float4*)&w_hh[(size_t)(g * HH + u) * HH + kq * 16 + j4 * 4];
            PIN4(W[g][j4]);
        }

    __shared__ __align__(16) float hl[HH];
    __shared__ __align__(16) float part[8][HH][4];   // [kq][u][gate]
    if (tid < HH) hl[tid] = 0.0f;
    __syncthreads();

    float cst = 0.0f, hkeep = 0.0f;
    int tprev = -1;
    float x0 = 0.f, x1 = 0.f, x2 = 0.f, x3 = 0.f;
    const float* xpt = xp + (size_t)b * G4 + u;
    if (tid < HH && len > 0) {
        x0 = xpt[0]; x1 = xpt[HH]; x2 = xpt[2 * HH]; x3 = xpt[3 * HH];
    }
    for (int t = 0; t < len; ++t) {
        float n0 = 0.f, n1 = 0.f, n2 = 0.f, n3 = 0.f;
        if (tid < HH) {
            if (tprev >= 0) ho[((size_t)b * TT + tprev) * HH + u] = hkeep;  // store h(t-1)
            if (t + 1 < len) {                                             // prefetch x(t+1)
                const float* xn = xpt + (size_t)(t + 1) * (BB * G4);
                n0 = xn[0]; n1 = xn[HH]; n2 = xn[2 * HH]; n3 = xn[3 * HH];
            }
        }
        // phase A: all 16 waves; wave-uniform h broadcast reads
        const float4* h4 = (const float4*)&hl[kq * 16];
        float a0 = 0.f, a1 = 0.f, a2 = 0.f, a3 = 0.f;
#pragma unroll
        for (int j4 = 0; j4 < 4; ++j4) {
            float4 hv = h4[j4];
            a0 += W[0][j4].x * hv.x + W[0][j4].y * hv.y + W[0][j4].z * hv.z + W[0][j4].w * hv.w;
            a1 += W[1][j4].x * hv.x + W[1][j4].y * hv.y + W[1][j4].z * hv.z + W[1][j4].w * hv.w;
            a2 += W[2][j4].x * hv.x + W[2][j4].y * hv.y + W[2][j4].z * hv.z + W[2][j4].w * hv.w;
            a3 += W[3][j4].x * hv.x + W[3][j4].y * hv.y + W[3][j4].z * hv.z + W[3][j4].w * hv.w;
        }
        if (kq) *(float4*)&part[kq][u][0] = make_float4(a0, a1, a2, a3);
        __syncthreads();
        // phase B: 2 waves (kq=0 threads)
        if (tid < HH) {
            float s0 = x0 + a0, s1 = x1 + a1, s2 = x2 + a2, s3 = x3 + a3;
#pragma unroll
            for (int q = 1; q < 8; ++q) {
                float4 p = *(const float4*)&part[q][u][0];
                s0 += p.x; s1 += p.y; s2 += p.z; s3 += p.w;
            }
            float gi = sigf(s0), gf = sigf(s1), gg = tanhf_(s2), go = sigf(s3);
            cst = gf * cst + gi * gg;
            float h = go * tanhf_(cst);
            hl[u] = h;
            hkeep = h;
            tprev = dir ? (len - 1 - t) : t;
            x0 = n0; x1 = n1; x2 = n2; x3 = n3;
        }
        __syncthreads();
    }
    if (tid < HH && tprev >= 0) ho[((size_t)b * TT + tprev) * HH + u] = hkeep;
}

// ---------------- masked attention pooling ----------------
__global__ __launch_bounds__(256) void attn_kernel(const float* __restrict__ hf,
                                                   const float* __restrict__ hb,
                                                   const float* __restrict__ attn_w,
                                                   const float* __restrict__ attn_b,
                                                   const int* __restrict__ lengths,
                                                   float* __restrict__ ctx) {
    int b = blockIdx.x;
    int tid = threadIdx.x;
    int len = lengths[b];
    __shared__ __align__(16) float wl[256];
    __shared__ float pl[256];
    __shared__ float red[256];
    wl[tid] = attn_w[tid];
    __syncthreads();
    float sc = -3.0e38f;
    if (tid < len) {
        const float4* rf = (const float4*)(hf + ((size_t)b * TT + tid) * HH);
        const float4* rb = (const float4*)(hb + ((size_t)b * TT + tid) * HH);
        const float4* w4 = (const float4*)wl;
        float s = attn_b[0];
        for (int k4 = 0; k4 < 32; ++k4) {
            float4 a = rf[k4], ww = w4[k4];
            s += a.x * ww.x + a.y * ww.y + a.z * ww.z + a.w * ww.w;
        }
        for (int k4 = 0; k4 < 32; ++k4) {
            float4 a = rb[k4], ww = w4[32 + k4];
            s += a.x * ww.x + a.y * ww.y + a.z * ww.z + a.w * ww.w;
        }
        sc = s;
    }
    red[tid] = sc;
    __syncthreads();
    for (int off = 128; off > 0; off >>= 1) {
        if (tid < off) red[tid] = fmaxf(red[tid], red[tid + off]);
        __syncthreads();
    }
    float mx = red[0];
    __syncthreads();
    float e = (tid < len) ? __expf(sc - mx) : 0.0f;
    red[tid] = e;
    __syncthreads();
    for (int off = 128; off > 0; off >>= 1) {
        if (tid < off) red[tid] += red[tid + off];
        __syncthreads();
    }
    float inv = 1.0f / red[0];
    pl[tid] = e * inv;
    __syncthreads();
    float acc = 0.0f;
    const float* basep = (tid < HH) ? (hf + (size_t)b * TT * HH + tid)
                                    : (hb + (size_t)b * TT * HH + (tid - HH));
#pragma unroll 4
    for (int t = 0; t < len; ++t) acc += pl[t] * basep[(size_t)t * HH];
    ctx[(size_t)b * 256 + tid] = acc;
}

// ---------------- final FC v2: thread = 4 n-cols x 16 b-rows ----------------
__global__ __launch_bounds__(256) void fc_kernel(const float* __restrict__ ctx,
                                                 const float* __restrict__ fc_w,
                                                 const float* __restrict__ fc_b,
                                                 float* __restrict__ out) {
    __shared__ __align__(16) float cl[64][256];
    for (int i = threadIdx.x; i < 64 * 256 / 4; i += 256)
        ((float4*)cl)[i] = ((const float4*)ctx)[i];
    __syncthreads();
    int lane = threadIdx.x & 63;
    int bq = threadIdx.x >> 6;
    int nb = blockIdx.x * 256 + lane;
    float acc[16][4];
#pragma unroll
    for (int i = 0; i < 16; ++i)
#pragma unroll
        for (int c = 0; c < 4; ++c) acc[i][c] = 0.0f;
    for (int k4 = 0; k4 < 64; ++k4) {
        int k = k4 * 4;
        float w[4][4];
#pragma unroll
        for (int j = 0; j < 4; ++j)
#pragma unroll
            for (int c = 0; c < 4; ++c) {
                int n = nb + c * 64;
                w[j][c] = (n < NN) ? fc_w[(size_t)(k + j) * NN + n] : 0.0f;
            }
#pragma unroll
        for (int i = 0; i < 16; ++i) {
            float4 cv = *(const float4*)&cl[bq * 16 + i][k];
#pragma unroll
            for (int c = 0; c < 4; ++c)
                acc[i][c] += cv.x * w[0][c] + cv.y * w[1][c] + cv.z * w[2][c] + cv.w * w[3][c];
        }
    }
#pragma unroll
    for (int i = 0; i < 16; ++i)
#pragma unroll
        for (int c = 0; c < 4; ++c) {
            int n = nb + c * 64;
            if (n < NN) out[(size_t)(bq * 16 + i) * NN + n] = acc[i][c] + fc_b[n];
        }
}

// ---------------- host launcher ----------------
extern "C" void kernel_launch(void* const* d_in, const int* in_sizes, int n_in,
                              void* d_out, int out_size, void* d_ws, size_t ws_size,
                              hipStream_t stream) {
    const float* x_coords   = (const float*)d_in[0];
    const float* temporal   = (const float*)d_in[1];
    const int*   edge_index = (const int*)d_in[2];
    const float* edge_w     = (const float*)d_in[3];
    const int*   seq        = (const int*)d_in[4];
    const int*   lengths    = (const int*)d_in[5];
    const float* node_emb   = (const float*)d_in[6];
    const float* gcn1_w     = (const float*)d_in[7];
    const float* gcn1_b     = (const float*)d_in[8];
    const float* gcn2_w     = (const float*)d_in[9];
    const float* gcn2_b     = (const float*)d_in[10];
    const float* w_ih_f     = (const float*)d_in[11];
    const float* w_hh_f     = (const float*)d_in[12];
    const float* b_ih_f     = (const float*)d_in[13];
    const float* b_hh_f     = (const float*)d_in[14];
    const float* w_ih_b     = (const float*)d_in[15];
    const float* w_hh_b     = (const float*)d_in[16];
    const float* b_ih_b     = (const float*)d_in[17];
    const float* b_hh_b     = (const float*)d_in[18];
    const float* attn_w     = (const float*)d_in[19];
    const float* attn_b     = (const float*)d_in[20];
    const float* fc_w       = (const float*)d_in[21];
    const float* fc_b       = (const float*)d_in[22];
    float* out = (float*)d_out;

    char* base = (char*)d_ws;
    size_t off = 0;
    auto alloc = [&](size_t nbytes) -> void* {
        void* p = base + off;
        off = (off + nbytes + 255) & ~(size_t)255;
        return p;
    };
    int*   cnt     = (int*)alloc((size_t)2 * NN * 4);  // cnt + degw contiguous (one memset)
    float* degw    = (float*)(cnt + NN);
    float* dinv    = (float*)alloc((size_t)NN * 4);
    int*   rs      = (int*)alloc(((size_t)NN + 1) * 4);
    int*   cursor  = (int*)alloc((size_t)NN * 4);
    int*   partials= (int*)alloc(64 * 4);
    int2*  ssrcw   = (int2*)alloc((size_t)NE * 8);
    float* h1      = (float*)alloc((size_t)NN * GH * 4);
    float* z1      = (float*)alloc((size_t)NN * GH * 4);
    float* a2      = h1;  // h1 dead after agg1
    float* w1t     = (float*)alloc((size_t)64 * 136 * 4);
    float* w2t     = (float*)alloc((size_t)GH * EMB * 4);
    float* z2      = (float*)alloc((size_t)NN * EMB * 4);
    float* xpf     = (float*)alloc((size_t)TT * BB * G4 * 4);
    float* xpb     = (float*)alloc((size_t)TT * BB * G4 * 4);
    float* hfo     = (float*)alloc((size_t)BB * TT * HH * 4);
    float* hbo     = (float*)alloc((size_t)BB * TT * HH * 4);
    float* ctx     = (float*)alloc((size_t)BB * 256 * 4);
    (void)ws_size; (void)in_sizes; (void)n_in; (void)out_size;

    hipMemsetAsync(cnt, 0, (size_t)2 * NN * 4, stream);

    hist_kernel<<<(NE + 255) / 256, 256, 0, stream>>>(edge_index, edge_w, cnt, degw);
    const int nblk = (NN + 1023) / 1024;  // 49
    scan1_kernel<<<nblk, 1024, 0, stream>>>(cnt, degw, dinv, rs, partials);
    misc_kernel<<<67, 256, 0, stream>>>(partials, nblk, gcn1_w, w1t, gcn2_w, w2t);
    scan3_kernel<<<nblk, 1024, 0, stream>>>(partials, rs, cursor);
    fill_kernel<<<(NE + 255) / 256, 256, 0, stream>>>(edge_index, edge_w, dinv, cursor, ssrcw);

    gemm1_kernel<<<(NN + 127) / 128, 256, 0, stream>>>(x_coords, temporal, node_emb, w1t, h1);
    agg_kernel<<<(NN + 3) / 4, 256, 0, stream>>>(h1, rs, ssrcw, dinv, gcn1_b, 1, z1);
    agg_kernel<<<(NN + 3) / 4, 256, 0, stream>>>(z1, rs, ssrcw, dinv, (const float*)nullptr, 0, a2);
    gemm2_kernel<<<dim3((NN + 127) / 128, 2), 256, 0, stream>>>(a2, w2t, gcn2_b, z2);

    pregemm_kernel<<<dim3(TT * BB / PM, G4 / PO, 2), 256, 0, stream>>>(
        z2, seq, w_ih_f, w_ih_b, b_ih_f, b_hh_f, b_ih_b, b_hh_b, lengths, xpf, xpb);
    lstm_kernel<<<BB * 2, 1024, 0, stream>>>(xpf, xpb, w_hh_f, w_hh_b, lengths, hfo, hbo);
    attn_kernel<<<BB, 256, 0, stream>>>(hfo, hbo, attn_w, attn_b, lengths, ctx);
    fc_kernel<<<(NN + 255) / 256, 256, 0, stream>>>(ctx, fc_w, fc_b, out);
}

// Round 13
// 566.267 us; speedup vs baseline: 1.2380x; 1.1405x over previous
//
#include <hip/hip_runtime.h>
#include <math.h>

#define NN 50000
#define NE 800000
#define EMB 128
#define GH 64
#define BB 64
#define TT 200
#define HH 128
#define G4 512
#define IND 134
#define PM 128
#define PO 128

__device__ __forceinline__ float sigf(float x) { return 1.0f / (1.0f + __expf(-x)); }
__device__ __forceinline__ float tanhf_(float x) { return 1.0f - 2.0f / (__expf(2.0f * x) + 1.0f); }

// ---------------- CSR build ----------------
__global__ void hist_kernel(const int* __restrict__ ei, const float* __restrict__ ew,
                            int* __restrict__ cnt, float* __restrict__ degw) {
    int e = blockIdx.x * 256 + threadIdx.x;
    if (e >= NE) return;
    int d = ei[NE + e];
    atomicAdd(&cnt[d], 1);
    atomicAdd(&degw[d], ew[e]);
}

// scan1 + dinv fused (both depend only on hist)
__global__ __launch_bounds__(1024) void scan1_kernel(const int* __restrict__ cnt,
                                                     const float* __restrict__ degw,
                                                     float* __restrict__ dinv,
                                                     int* __restrict__ rs, int* __restrict__ partials) {
    __shared__ int s[1024];
    int gid = blockIdx.x * 1024 + threadIdx.x;
    int v = (gid < NN) ? cnt[gid] : 0;
    if (gid < NN) dinv[gid] = rsqrtf(degw[gid] + 1.0f);   // +1 self loop
    s[threadIdx.x] = v;
    __syncthreads();
    for (int off = 1; off < 1024; off <<= 1) {
        int add = (threadIdx.x >= (unsigned)off) ? s[threadIdx.x - off] : 0;
        __syncthreads();
        s[threadIdx.x] += add;
        __syncthreads();
    }
    if (gid < NN) rs[gid] = s[threadIdx.x] - v;  // exclusive
    if (threadIdx.x == 1023) partials[blockIdx.x] = s[1023];
}

// misc: block 0 = parallel scan of partials; blocks 1..34 = W1 transpose+reorder.
__global__ void misc_kernel(int* __restrict__ partials, int nblk,
                            const float* __restrict__ W1, float* __restrict__ w1t) {
    int blk = blockIdx.x;
    int tid = threadIdx.x;
    if (blk == 0) {
        __shared__ int s[64];
        int v = (tid < nblk) ? partials[tid] : 0;
        s[tid] = v;
        __syncthreads();
        for (int off = 1; off < 64; off <<= 1) {
            int add = (tid >= off) ? s[tid - off] : 0;
            __syncthreads();
            s[tid] += add;
            __syncthreads();
        }
        if (tid < nblk) partials[tid] = s[tid] - v;  // exclusive
    } else {
        int i = (blk - 1) * 256 + tid;
        if (i < 64 * 136) {
            int o = i / 136, j = i - o * 136;
            float v = 0.0f;
            if (j < 128) v = W1[(size_t)(j + 2) * GH + o];
            else if (j < 130) v = W1[(size_t)(j - 128) * GH + o];
            else if (j < 134) v = W1[(size_t)j * GH + o];
            w1t[i] = v;
        }
    }
}

// wcomb: fold gemm2 into pregemm via associativity. z2 = a2@W2 feeds ONLY the
// seq gather -> xp = a2[node] @ (W2@W_ih^T). wcomb[dir][o][k] =
// sum_e W2[k][e]*W_ih[o][e]; bcomb[dir][o] = b_ih+b_hh + dot(W_ih[o], b2).
// Kills the gemm2 kernel + 51MB of z2 HBM traffic; halves pregemm K.
__global__ __launch_bounds__(256) void wcomb_kernel(const float* __restrict__ w_ih_f,
                                                    const float* __restrict__ w_ih_b,
                                                    const float* __restrict__ W2,
                                                    const float* __restrict__ b2,
                                                    const float* __restrict__ b_ih_f,
                                                    const float* __restrict__ b_hh_f,
                                                    const float* __restrict__ b_ih_b,
                                                    const float* __restrict__ b_hh_b,
                                                    float* __restrict__ wcomb,
                                                    float* __restrict__ bcomb) {
    int bx = blockIdx.x, tid = threadIdx.x;
    int dir = bx >> 7, o0 = (bx & 127) * 4;
    const float* w_ih = dir ? w_ih_b : w_ih_f;
    __shared__ __align__(16) float w2s[GH][EMB];    // 32KB, [k][e]
    __shared__ __align__(16) float wihs[4][EMB];    // 2KB, [oo][e]
    __shared__ __align__(16) float b2s[EMB];
    for (int i = tid; i < GH * EMB / 4; i += 256)
        ((float4*)w2s)[i] = ((const float4*)W2)[i];
    for (int i = tid; i < 4 * EMB / 4; i += 256) {
        int oo = i >> 5, e4 = i & 31;
        ((float4*)wihs)[i] = *(const float4*)&w_ih[(size_t)(o0 + oo) * EMB + e4 * 4];
    }
    if (tid < 32) ((float4*)b2s)[tid] = ((const float4*)b2)[tid];
    __syncthreads();
    int oo = tid >> 6, k = tid & 63;
    float acc = 0.0f;
#pragma unroll 8
    for (int e4 = 0; e4 < 32; ++e4) {
        float4 a = *(const float4*)&wihs[oo][e4 * 4];
        float4 w = *(const float4*)&w2s[k][e4 * 4];
        acc += a.x * w.x + a.y * w.y + a.z * w.z + a.w * w.w;
    }
    wcomb[((size_t)dir * G4 + o0 + oo) * GH + k] = acc;
    if (tid < 4) {
        int o = o0 + tid;
        float s = dir ? (b_ih_b[o] + b_hh_b[o]) : (b_ih_f[o] + b_hh_f[o]);
        for (int e = 0; e < EMB; ++e) s += wihs[tid][e] * b2s[e];
        bcomb[dir * G4 + o] = s;
    }
}

__global__ __launch_bounds__(1024) void scan3_kernel(const int* __restrict__ partials,
                                                     int* __restrict__ rs, int* __restrict__ cursor) {
    int gid = blockIdx.x * 1024 + threadIdx.x;
    if (gid < NN) {
        int v = rs[gid] + partials[gid >> 10];
        rs[gid] = v;
        cursor[gid] = v;
    }
    if (gid == 0) rs[NN] = NE;
}

// fill: (src, weight) packed into int2 -> ONE random 8B scatter instead of two 4B
__global__ void fill_kernel(const int* __restrict__ ei, const float* __restrict__ ew,
                            const float* __restrict__ dinv, int* __restrict__ cursor,
                            int2* __restrict__ ssrcw) {
    int e = blockIdx.x * 256 + threadIdx.x;
    if (e >= NE) return;
    int s = ei[e], d = ei[NE + e];
    int pos = atomicAdd(&cursor[d], 1);
    ssrcw[pos] = make_int2(s, __float_as_int(ew[e] * dinv[s] * dinv[d]));
}

// ---------------- GCN layer 1 GEMM v2 (134 -> 64), register-tiled ----------------
__global__ __launch_bounds__(256) void gemm1_kernel(const float* __restrict__ coords,
                                                    const float* __restrict__ temporal,
                                                    const float* __restrict__ emb,
                                                    const float* __restrict__ w1t,
                                                    float* __restrict__ h1) {
    __shared__ __align__(16) float xs[128][136];
    __shared__ __align__(16) float wt[64][136];
    int tid = threadIdx.x;
    int m0 = blockIdx.x * 128;
    for (int i = tid; i < 64 * 34; i += 256) {           // stage W^T (swizzled words 0..31)
        int rr = i / 34, w = i - rr * 34;
        float4 v = *(const float4*)&w1t[(size_t)rr * 136 + w * 4];
        int ws = (w < 32) ? (w ^ ((rr >> 3) & 7)) : w;
        *(float4*)&wt[rr][ws * 4] = v;
    }
    for (int i = tid; i < 128 * 32; i += 256) {          // stage emb words 0..31 (swizzled)
        int r = i >> 5, c4 = i & 31;
        int m = m0 + r;
        float4 v = make_float4(0.f, 0.f, 0.f, 0.f);
        if (m < NN) v = *(const float4*)&emb[(size_t)m * EMB + c4 * 4];
        *(float4*)&xs[r][(c4 ^ ((r >> 2) & 7)) * 4] = v;
    }
    for (int i = tid; i < 128 * 8; i += 256) {           // words 32..33: coords+temporal+pad
        int r = i >> 3, c = i & 7;
        int m = m0 + r;
        float v = 0.0f;
        if (m < NN) {
            if (c < 2) v = coords[2 * m + c];
            else if (c < 6) v = temporal[4 * m + (c - 2)];
        }
        xs[r][128 + c] = v;
    }
    __syncthreads();
    int mt = tid >> 3, ot = tid & 7;
    int xswz = mt & 7, wswz = ot & 7;
    float acc[4][8];
#pragma unroll
    for (int mi = 0; mi < 4; ++mi)
#pragma unroll
        for (int oi = 0; oi < 8; ++oi) acc[mi][oi] = 0.0f;
    for (int k4 = 0; k4 < 34; ++k4) {
        int xk = (k4 < 32) ? (k4 ^ xswz) : k4;
        int wk = (k4 < 32) ? (k4 ^ wswz) : k4;
        float4 xv[4], wv[8];
#pragma unroll
        for (int mi = 0; mi < 4; ++mi) xv[mi] = *(const float4*)&xs[mt * 4 + mi][xk * 4];
#pragma unroll
        for (int oi = 0; oi < 8; ++oi) wv[oi] = *(const float4*)&wt[ot * 8 + oi][wk * 4];
#pragma unroll
        for (int mi = 0; mi < 4; ++mi)
#pragma unroll
            for (int oi = 0; oi < 8; ++oi)
                acc[mi][oi] += xv[mi].x * wv[oi].x + xv[mi].y * wv[oi].y
                             + xv[mi].z * wv[oi].z + xv[mi].w * wv[oi].w;
    }
#pragma unroll
    for (int mi = 0; mi < 4; ++mi) {
        int m = m0 + mt * 4 + mi;
        if (m >= NN) continue;
        int ob = ot * 8;
        *(float4*)&h1[(size_t)m * GH + ob] = make_float4(acc[mi][0], acc[mi][1], acc[mi][2], acc[mi][3]);
        *(float4*)&h1[(size_t)m * GH + ob + 4] = make_float4(acc[mi][4], acc[mi][5], acc[mi][6], acc[mi][7]);
    }
}

// ---------------- symmetric-norm aggregation (CSR, int2 edges) ----------------
__global__ __launch_bounds__(256) void agg_kernel(const float* __restrict__ hin,
                                                  const int* __restrict__ rs,
                                                  const int2* __restrict__ ssrcw,
                                                  const float* __restrict__ dinv,
                                                  const float* __restrict__ bias, int relu,
                                                  float* __restrict__ hout) {
    int lane = threadIdx.x & 63;
    int wid = threadIdx.x >> 6;
    int n = blockIdx.x * 4 + wid;
    if (n >= NN) return;
    float dv = dinv[n];
    float acc = hin[(size_t)n * GH + lane] * (dv * dv);  // self loop
    int2 range = *(const int2*)&rs[n];                   // rs[n], rs[n+1] in one load
    int i = range.x, e1 = range.y;
    for (; i + 7 < e1; i += 8) {
        int4 p0 = *(const int4*)&ssrcw[i];
        int4 p1 = *(const int4*)&ssrcw[i + 2];
        int4 p2 = *(const int4*)&ssrcw[i + 4];
        int4 p3 = *(const int4*)&ssrcw[i + 6];
        float a0 = hin[(size_t)p0.x * GH + lane];
        float a1 = hin[(size_t)p0.z * GH + lane];
        float a2 = hin[(size_t)p1.x * GH + lane];
        float a3 = hin[(size_t)p1.z * GH + lane];
        float a4 = hin[(size_t)p2.x * GH + lane];
        float a5 = hin[(size_t)p2.z * GH + lane];
        float a6 = hin[(size_t)p3.x * GH + lane];
        float a7 = hin[(size_t)p3.z * GH + lane];
        acc += a0 * __int_as_float(p0.y) + a1 * __int_as_float(p0.w)
             + a2 * __int_as_float(p1.y) + a3 * __int_as_float(p1.w)
             + a4 * __int_as_float(p2.y) + a5 * __int_as_float(p2.w)
             + a6 * __int_as_float(p3.y) + a7 * __int_as_float(p3.w);
    }
    for (; i + 3 < e1; i += 4) {
        int4 p0 = *(const int4*)&ssrcw[i];
        int4 p1 = *(const int4*)&ssrcw[i + 2];
        float a0 = hin[(size_t)p0.x * GH + lane];
        float a1 = hin[(size_t)p0.z * GH + lane];
        float a2 = hin[(size_t)p1.x * GH + lane];
        float a3 = hin[(size_t)p1.z * GH + lane];
        acc += a0 * __int_as_float(p0.y) + a1 * __int_as_float(p0.w)
             + a2 * __int_as_float(p1.y) + a3 * __int_as_float(p1.w);
    }
    for (; i < e1; ++i) {
        int2 p = ssrcw[i];
        acc += hin[(size_t)p.x * GH + lane] * __int_as_float(p.y);
    }
    if (bias) acc += bias[lane];
    if (relu) acc = fmaxf(acc, 0.0f);
    hout[(size_t)n * GH + lane] = acc;
}

// ---------------- pre-GEMM v5: K=64 via Wcomb, gather fused, 64.5KB LDS ----------------
// xp[m] = a2[node[m]] @ wcomb[dir] + bcomb[dir]. Half the K, half the LDS-pipe
// reads (was LDS-issue-bound), half the gather bytes, 2 blocks/CU (was 1).
__global__ __launch_bounds__(256) void pregemm_kernel(const float* __restrict__ a2,
                                                      const int* __restrict__ seq,
                                                      const float* __restrict__ wcomb,
                                                      const float* __restrict__ bcomb,
                                                      const int* __restrict__ lengths,
                                                      float* __restrict__ xpf,
                                                      float* __restrict__ xpb) {
    int dir = blockIdx.z;
    int o0 = blockIdx.y * PO;
    int m0 = blockIdx.x * PM;
    const float* wc = wcomb + (size_t)dir * G4 * GH;
    __shared__ __align__(16) float xs[PM][GH];   // 32KB
    __shared__ __align__(16) float ws[PO][GH];   // 32KB
    __shared__ float bsh[PO];
    int tid = threadIdx.x;
#pragma unroll
    for (int i = 0; i < 8; ++i) {          // stage Wcomb rows (swizzled)
        int idx = i * 256 + tid;
        int row = idx >> 4, c4 = idx & 15;
        float4 v = *(const float4*)&wc[(size_t)(o0 + row) * GH + c4 * 4];
        *(float4*)&ws[row][(c4 ^ ((row >> 3) & 7)) * 4] = v;
    }
    if (tid < PO) bsh[tid] = bcomb[dir * G4 + o0 + tid];
#pragma unroll
    for (int i = 0; i < 8; ++i) {          // stage a2 via fused gather (swizzled)
        int idx = i * 256 + tid;
        int r = idx >> 4, c4 = idx & 15;
        int m = m0 + r;
        int t = m >> 6, b = m & 63;
        int tsrc = t;
        if (dir) { int len = lengths[b]; tsrc = (t < len) ? (len - 1 - t) : t; }
        int node = seq[b * TT + tsrc];
        float4 v = *(const float4*)&a2[(size_t)node * GH + c4 * 4];
        *(float4*)&xs[r][(c4 ^ ((r >> 3) & 3)) * 4] = v;
    }
    __syncthreads();
    int mt = tid >> 4, ot = tid & 15;
    int mswz = mt & 3, oswz = ot & 7;
    float acc[8][8];
#pragma unroll
    for (int mi = 0; mi < 8; ++mi)
#pragma unroll
        for (int oi = 0; oi < 8; ++oi) acc[mi][oi] = 0.0f;
    for (int k4 = 0; k4 < 16; ++k4) {
        int xk = (k4 ^ mswz) * 4;
        int wk = (k4 ^ oswz) * 4;
        float4 xv[8], wv[8];
#pragma unroll
        for (int mi = 0; mi < 8; ++mi) xv[mi] = *(const float4*)&xs[mt * 8 + mi][xk];
#pragma unroll
        for (int oi = 0; oi < 8; ++oi) wv[oi] = *(const float4*)&ws[ot * 8 + oi][wk];
#pragma unroll
        for (int mi = 0; mi < 8; ++mi)
#pragma unroll
            for (int oi = 0; oi < 8; ++oi)
                acc[mi][oi] += xv[mi].x * wv[oi].x + xv[mi].y * wv[oi].y
                             + xv[mi].z * wv[oi].z + xv[mi].w * wv[oi].w;
    }
    float* xp = dir ? xpb : xpf;
#pragma unroll
    for (int mi = 0; mi < 8; ++mi) {
        int m = m0 + mt * 8 + mi;
        int ob = ot * 8;
        float4 oa = make_float4(acc[mi][0] + bsh[ob + 0], acc[mi][1] + bsh[ob + 1],
                                acc[mi][2] + bsh[ob + 2], acc[mi][3] + bsh[ob + 3]);
        float4 obv = make_float4(acc[mi][4] + bsh[ob + 4], acc[mi][5] + bsh[ob + 5],
                                 acc[mi][6] + bsh[ob + 6], acc[mi][7] + bsh[ob + 7]);
        *(float4*)&xp[(size_t)m * G4 + o0 + ob] = oa;
        *(float4*)&xp[(size_t)m * G4 + o0 + ob + 4] = obv;
    }
}

// ---------------- LSTM recurrence v9 (structure Z; latency-bound floor ~175us) ----------------
#define PIN4(v) asm volatile("" : "+v"(v.x), "+v"(v.y), "+v"(v.z), "+v"(v.w))
__global__ __launch_bounds__(1024, 4) void lstm_kernel(const float* __restrict__ xpf,
                                                       const float* __restrict__ xpb,
                                                       const float* __restrict__ w_hh_f,
                                                       const float* __restrict__ w_hh_b,
                                                       const int* __restrict__ lengths,
                                                       float* __restrict__ hfo,
                                                       float* __restrict__ hbo) {
    int chain = blockIdx.x;
    int dir = chain & 1, b = chain >> 1;
    const float* w_hh = dir ? w_hh_b : w_hh_f;
    const float* xp = dir ? xpb : xpf;
    float* ho = dir ? hbo : hfo;
    int tid = threadIdx.x;
    int u = tid & 127;
    int kq = tid >> 7;    // 0..7
    int len = lengths[b];

    float4 W[4][4];
#pragma unroll
    for (int g = 0; g < 4; ++g)
#pragma unroll
        for (int j4 = 0; j4 < 4; ++j4) {
            W[g][j4] = *(const float4*)&w_hh[(size_t)(g * HH + u) * HH + kq * 16 + j4 * 4];
            PIN4(W[g][j4]);
        }

    __shared__ __align__(16) float hl[HH];
    __shared__ __align__(16) float part[8][HH][4];   // [kq][u][gate]
    if (tid < HH) hl[tid] = 0.0f;
    __syncthreads();

    float cst = 0.0f, hkeep = 0.0f;
    int tprev = -1;
    float x0 = 0.f, x1 = 0.f, x2 = 0.f, x3 = 0.f;
    const float* xpt = xp + (size_t)b * G4 + u;
    if (tid < HH && len > 0) {
        x0 = xpt[0]; x1 = xpt[HH]; x2 = xpt[2 * HH]; x3 = xpt[3 * HH];
    }
    for (int t = 0; t < len; ++t) {
        float n0 = 0.f, n1 = 0.f, n2 = 0.f, n3 = 0.f;
        if (tid < HH) {
            if (tprev >= 0) ho[((size_t)b * TT + tprev) * HH + u] = hkeep;  // store h(t-1)
            if (t + 1 < len) {                                             // prefetch x(t+1)
                const float* xn = xpt + (size_t)(t + 1) * (BB * G4);
                n0 = xn[0]; n1 = xn[HH]; n2 = xn[2 * HH]; n3 = xn[3 * HH];
            }
        }
        // phase A: all 16 waves; wave-uniform h broadcast reads
        const float4* h4 = (const float4*)&hl[kq * 16];
        float a0 = 0.f, a1 = 0.f, a2 = 0.f, a3 = 0.f;
#pragma unroll
        for (int j4 = 0; j4 < 4; ++j4) {
            float4 hv = h4[j4];
            a0 += W[0][j4].x * hv.x + W[0][j4].y * hv.y + W[0][j4].z * hv.z + W[0][j4].w * hv.w;
            a1 += W[1][j4].x * hv.x + W[1][j4].y * hv.y + W[1][j4].z * hv.z + W[1][j4].w * hv.w;
            a2 += W[2][j4].x * hv.x + W[2][j4].y * hv.y + W[2][j4].z * hv.z + W[2][j4].w * hv.w;
            a3 += W[3][j4].x * hv.x + W[3][j4].y * hv.y + W[3][j4].z * hv.z + W[3][j4].w * hv.w;
        }
        if (kq) *(float4*)&part[kq][u][0] = make_float4(a0, a1, a2, a3);
        __syncthreads();
        // phase B: 2 waves (kq=0 threads)
        if (tid < HH) {
            float s0 = x0 + a0, s1 = x1 + a1, s2 = x2 + a2, s3 = x3 + a3;
#pragma unroll
            for (int q = 1; q < 8; ++q) {
                float4 p = *(const float4*)&part[q][u][0];
                s0 += p.x; s1 += p.y; s2 += p.z; s3 += p.w;
            }
            float gi = sigf(s0), gf = sigf(s1), gg = tanhf_(s2), go = sigf(s3);
            cst = gf * cst + gi * gg;
            float h = go * tanhf_(cst);
            hl[u] = h;
            hkeep = h;
            tprev = dir ? (len - 1 - t) : t;
            x0 = n0; x1 = n1; x2 = n2; x3 = n3;
        }
        __syncthreads();
    }
    if (tid < HH && tprev >= 0) ho[((size_t)b * TT + tprev) * HH + u] = hkeep;
}

// ---------------- masked attention pooling ----------------
__global__ __launch_bounds__(256) void attn_kernel(const float* __restrict__ hf,
                                                   const float* __restrict__ hb,
                                                   const float* __restrict__ attn_w,
                                                   const float* __restrict__ attn_b,
                                                   const int* __restrict__ lengths,
                                                   float* __restrict__ ctx) {
    int b = blockIdx.x;
    int tid = threadIdx.x;
    int len = lengths[b];
    __shared__ __align__(16) float wl[256];
    __shared__ float pl[256];
    __shared__ float red[256];
    wl[tid] = attn_w[tid];
    __syncthreads();
    float sc = -3.0e38f;
    if (tid < len) {
        const float4* rf = (const float4*)(hf + ((size_t)b * TT + tid) * HH);
        const float4* rb = (const float4*)(hb + ((size_t)b * TT + tid) * HH);
        const float4* w4 = (const float4*)wl;
        float s = attn_b[0];
        for (int k4 = 0; k4 < 32; ++k4) {
            float4 a = rf[k4], ww = w4[k4];
            s += a.x * ww.x + a.y * ww.y + a.z * ww.z + a.w * ww.w;
        }
        for (int k4 = 0; k4 < 32; ++k4) {
            float4 a = rb[k4], ww = w4[32 + k4];
            s += a.x * ww.x + a.y * ww.y + a.z * ww.z + a.w * ww.w;
        }
        sc = s;
    }
    red[tid] = sc;
    __syncthreads();
    for (int off = 128; off > 0; off >>= 1) {
        if (tid < off) red[tid] = fmaxf(red[tid], red[tid + off]);
        __syncthreads();
    }
    float mx = red[0];
    __syncthreads();
    float e = (tid < len) ? __expf(sc - mx) : 0.0f;
    red[tid] = e;
    __syncthreads();
    for (int off = 128; off > 0; off >>= 1) {
        if (tid < off) red[tid] += red[tid + off];
        __syncthreads();
    }
    float inv = 1.0f / red[0];
    pl[tid] = e * inv;
    __syncthreads();
    float acc = 0.0f;
    const float* basep = (tid < HH) ? (hf + (size_t)b * TT * HH + tid)
                                    : (hb + (size_t)b * TT * HH + (tid - HH));
#pragma unroll 4
    for (int t = 0; t < len; ++t) acc += pl[t] * basep[(size_t)t * HH];
    ctx[(size_t)b * 256 + tid] = acc;
}

// ---------------- final FC v2: thread = 4 n-cols x 16 b-rows ----------------
__global__ __launch_bounds__(256) void fc_kernel(const float* __restrict__ ctx,
                                                 const float* __restrict__ fc_w,
                                                 const float* __restrict__ fc_b,
                                                 float* __restrict__ out) {
    __shared__ __align__(16) float cl[64][256];
    for (int i = threadIdx.x; i < 64 * 256 / 4; i += 256)
        ((float4*)cl)[i] = ((const float4*)ctx)[i];
    __syncthreads();
    int lane = threadIdx.x & 63;
    int bq = threadIdx.x >> 6;
    int nb = blockIdx.x * 256 + lane;
    float acc[16][4];
#pragma unroll
    for (int i = 0; i < 16; ++i)
#pragma unroll
        for (int c = 0; c < 4; ++c) acc[i][c] = 0.0f;
    for (int k4 = 0; k4 < 64; ++k4) {
        int k = k4 * 4;
        float w[4][4];
#pragma unroll
        for (int j = 0; j < 4; ++j)
#pragma unroll
            for (int c = 0; c < 4; ++c) {
                int n = nb + c * 64;
                w[j][c] = (n < NN) ? fc_w[(size_t)(k + j) * NN + n] : 0.0f;
            }
#pragma unroll
        for (int i = 0; i < 16; ++i) {
            float4 cv = *(const float4*)&cl[bq * 16 + i][k];
#pragma unroll
            for (int c = 0; c < 4; ++c)
                acc[i][c] += cv.x * w[0][c] + cv.y * w[1][c] + cv.z * w[2][c] + cv.w * w[3][c];
        }
    }
#pragma unroll
    for (int i = 0; i < 16; ++i)
#pragma unroll
        for (int c = 0; c < 4; ++c) {
            int n = nb + c * 64;
            if (n < NN) out[(size_t)(bq * 16 + i) * NN + n] = acc[i][c] + fc_b[n];
        }
}

// ---------------- host launcher ----------------
extern "C" void kernel_launch(void* const* d_in, const int* in_sizes, int n_in,
                              void* d_out, int out_size, void* d_ws, size_t ws_size,
                              hipStream_t stream) {
    const float* x_coords   = (const float*)d_in[0];
    const float* temporal   = (const float*)d_in[1];
    const int*   edge_index = (const int*)d_in[2];
    const float* edge_w     = (const float*)d_in[3];
    const int*   seq        = (const int*)d_in[4];
    const int*   lengths    = (const int*)d_in[5];
    const float* node_emb   = (const float*)d_in[6];
    const float* gcn1_w     = (const float*)d_in[7];
    const float* gcn1_b     = (const float*)d_in[8];
    const float* gcn2_w     = (const float*)d_in[9];
    const float* gcn2_b     = (const float*)d_in[10];
    const float* w_ih_f     = (const float*)d_in[11];
    const float* w_hh_f     = (const float*)d_in[12];
    const float* b_ih_f     = (const float*)d_in[13];
    const float* b_hh_f     = (const float*)d_in[14];
    const float* w_ih_b     = (const float*)d_in[15];
    const float* w_hh_b     = (const float*)d_in[16];
    const float* b_ih_b     = (const float*)d_in[17];
    const float* b_hh_b     = (const float*)d_in[18];
    const float* attn_w     = (const float*)d_in[19];
    const float* attn_b     = (const float*)d_in[20];
    const float* fc_w       = (const float*)d_in[21];
    const float* fc_b       = (const float*)d_in[22];
    float* out = (float*)d_out;

    char* base = (char*)d_ws;
    size_t off = 0;
    auto alloc = [&](size_t nbytes) -> void* {
        void* p = base + off;
        off = (off + nbytes + 255) & ~(size_t)255;
        return p;
    };
    int*   cnt     = (int*)alloc((size_t)2 * NN * 4);  // cnt + degw contiguous (one memset)
    float* degw    = (float*)(cnt + NN);
    float* dinv    = (float*)alloc((size_t)NN * 4);
    int*   rs      = (int*)alloc(((size_t)NN + 1) * 4);
    int*   cursor  = (int*)alloc((size_t)NN * 4);
    int*   partials= (int*)alloc(64 * 4);
    int2*  ssrcw   = (int2*)alloc((size_t)NE * 8);
    float* h1      = (float*)alloc((size_t)NN * GH * 4);
    float* z1      = (float*)alloc((size_t)NN * GH * 4);
    float* a2      = h1;  // h1 dead after agg1
    float* w1t     = (float*)alloc((size_t)64 * 136 * 4);
    float* wcomb   = (float*)alloc((size_t)2 * G4 * GH * 4);
    float* bcomb   = (float*)alloc((size_t)2 * G4 * 4);
    float* xpf     = (float*)alloc((size_t)TT * BB * G4 * 4);
    float* xpb     = (float*)alloc((size_t)TT * BB * G4 * 4);
    float* hfo     = (float*)alloc((size_t)BB * TT * HH * 4);
    float* hbo     = (float*)alloc((size_t)BB * TT * HH * 4);
    float* ctx     = (float*)alloc((size_t)BB * 256 * 4);
    (void)ws_size; (void)in_sizes; (void)n_in; (void)out_size;

    hipMemsetAsync(cnt, 0, (size_t)2 * NN * 4, stream);

    hist_kernel<<<(NE + 255) / 256, 256, 0, stream>>>(edge_index, edge_w, cnt, degw);
    const int nblk = (NN + 1023) / 1024;  // 49
    scan1_kernel<<<nblk, 1024, 0, stream>>>(cnt, degw, dinv, rs, partials);
    misc_kernel<<<35, 256, 0, stream>>>(partials, nblk, gcn1_w, w1t);
    wcomb_kernel<<<256, 256, 0, stream>>>(w_ih_f, w_ih_b, gcn2_w, gcn2_b,
                                          b_ih_f, b_hh_f, b_ih_b, b_hh_b, wcomb, bcomb);
    scan3_kernel<<<nblk, 1024, 0, stream>>>(partials, rs, cursor);
    fill_kernel<<<(NE + 255) / 256, 256, 0, stream>>>(edge_index, edge_w, dinv, cursor, ssrcw);

    gemm1_kernel<<<(NN + 127) / 128, 256, 0, stream>>>(x_coords, temporal, node_emb, w1t, h1);
    agg_kernel<<<(NN + 3) / 4, 256, 0, stream>>>(h1, rs, ssrcw, dinv, gcn1_b, 1, z1);
    agg_kernel<<<(NN + 3) / 4, 256, 0, stream>>>(z1, rs, ssrcw, dinv, (const float*)nullptr, 0, a2);

    pregemm_kernel<<<dim3(TT * BB / PM, G4 / PO, 2), 256, 0, stream>>>(
        a2, seq, wcomb, bcomb, lengths, xpf, xpb);
    lstm_kernel<<<BB * 2, 1024, 0, stream>>>(xpf, xpb, w_hh_f, w_hh_b, lengths, hfo, hbo);
    attn_kernel<<<BB, 256, 0, stream>>>(hfo, hbo, attn_w, attn_b, lengths, ctx);
    fc_kernel<<<(NN + 255) / 256, 256, 0, stream>>>(ctx, fc_w, fc_b, out);
}